// Round 6
// baseline (1179.884 us; speedup 1.0000x reference)
//
#include <hip/hip_runtime.h>
#include <stdint.h>

typedef unsigned short u16;
typedef __attribute__((ext_vector_type(8))) short short8;
typedef __attribute__((ext_vector_type(4))) float f32x4;

#define DEVI __device__ __forceinline__

// problem constants
#define BB   256
#define LL   100
#define CC   55
#define DD   512
#define HH   8
#define DKK  64
#define MM   (BB * LL)   // 25600 tokens
#define KEMB 192         // 3 * 64 (c padded 55->64)
#define NSEG 17

DEVI float bf2f(u16 s) { union { unsigned int u; float f; } x; x.u = ((unsigned int)s) << 16; return x.f; }
DEVI u16 f2bf(float f) {
  union { float f; unsigned int u; } x; x.f = f;
  unsigned int u = x.u;
  return (u16)((u + 0x7FFFu + ((u >> 16) & 1u)) >> 16);
}

DEVI void async_lds16(const u16* gp, u16* lp) {
  __builtin_amdgcn_global_load_lds((const __attribute__((address_space(1))) void*)gp,
                                   (__attribute__((address_space(3))) void*)lp, 16, 0, 0);
}

DEVI void wave_lds_fence() {   // wave-local LDS RAW/WAR fence (no cross-wave sync)
  asm volatile("s_waitcnt lgkmcnt(0)" ::: "memory");
  __builtin_amdgcn_wave_barrier();
}

// ---------------- dtype detect + canonicalize ----------------
__global__ void detect_dtype(const u16* __restrict__ x, int* __restrict__ flag) {
  __shared__ int cnt[256];
  int tid = threadIdx.x;
  u16 u = x[2 * tid];
  int e = (u >> 7) & 0xFF;
  cnt[tid] = (e >= 0x5F && e <= 0x90) ? 1 : 0;   // |v| in [2^-32, 2^17]
  __syncthreads();
  for (int s = 128; s > 0; s >>= 1) { if (tid < s) cnt[tid] += cnt[tid + s]; __syncthreads(); }
  if (tid == 0) *flag = (cnt[0] >= 160) ? 0 : 1;
}

struct Segs { const void* src[NSEG]; int off[NSEG + 1]; };

__global__ void convert_all(Segs s, const int* __restrict__ flag, u16* __restrict__ dst) {
  int i = blockIdx.x * 256 + threadIdx.x;
  if (i >= s.off[NSEG]) return;
  int sidx = 0;
#pragma unroll
  for (int k = 1; k < NSEG; k++) if (i >= s.off[k]) sidx = k;
  int j = i - s.off[sidx];
  u16 v;
  if (*flag) v = f2bf(((const float*)s.src[sidx])[j]);
  else       v = ((const u16*)s.src[sidx])[j];
  dst[i] = v;
}

// ---------------- repack kernels (embedding conv -> GEMM) ----------------
__global__ void repack_w(const u16* __restrict__ tokw, u16* __restrict__ Wg) {
  int idx = blockIdx.x * 256 + threadIdx.x;   // 512*192
  if (idx >= 512 * KEMB) return;
  int d = idx / KEMB, j = idx % KEMB, k = j >> 6, c = j & 63;
  Wg[idx] = (c < CC) ? tokw[d * (CC * 3) + c * 3 + k] : (u16)0;
}

__global__ void repack_x(const u16* __restrict__ x, u16* __restrict__ Xg) {
  int idx = blockIdx.x * 256 + threadIdx.x;   // 25600*192
  if (idx >= MM * KEMB) return;
  int m = idx / KEMB, j = idx % KEMB, k = j >> 6, c = j & 63;
  int b = m / LL, l = m % LL;
  int l2 = l + k - 1; l2 = (l2 + LL) % LL;    // circular pad
  Xg[idx] = (c < CC) ? x[(size_t)(b * LL + l2) * CC + c] : (u16)0;
}

// ---------------- bf16 MFMA GEMM: out = A[M,K] @ W[N,K]^T (+epilogue) ----------------
// BK=32 (verified-free LDS banking). 256 threads = 4 waves as 2x2.
// QKV: BM=256, grid.y spans 3 concatenated weight sets (sel by n0>>9).
// MRD: fp32 master READ prefetched BEFORE the K-loop (latency hidden behind staging).
// bf16 tile store via per-wave-exclusive 16-row LDS slab (wave-local fences).
struct GemmW { const u16* W[3]; const u16* bias[3]; void* out[3]; };

template<int BM, int BN, int TAG, bool QKV, bool DIRECT, bool MRD>
__global__ __launch_bounds__(256)
void gemm_bt(const u16* __restrict__ A, int K, GemmW w,
             const u16* __restrict__ pe,     // if non-null: add pe[(m%100)*512+col]
             float* __restrict__ master,     // if non-null: (MRD? +=) write fp32 master [M,512]
             int dogelu,
             int ldo, int nvalid,
             const int* __restrict__ dtf)    // DIRECT only: *dtf==1 -> fp32 store
{
  constexpr int BK = 32;
  constexpr int MI = BM / 32;                 // 16-row tiles per wave (rows = BM/2 per wave)
  constexpr int CW = BN / 2, NT = CW / 16;    // cols per wave
  constexpr int SW = CW + 4;                  // slab stride (u16)
  constexpr int STAGE_U16 = (BM + BN) * BK;
  __shared__ alignas(16) u16 smem[STAGE_U16];
  u16* As = smem;
  u16* Bs = smem + BM * BK;

  const int tid = threadIdx.x;
  const int lane = tid & 63;
  const int wv = __builtin_amdgcn_readfirstlane(tid >> 6);
  const int wm = wv & 1, wn = wv >> 1;
  const int l15 = lane & 15, qd = lane >> 4;
  const int m0 = blockIdx.x * BM;
  int n0 = blockIdx.y * BN;
  int sel = 0, n0l = n0;
  if (QKV) { sel = n0 >> 9; n0l = n0 & 511; }
  const u16* W = w.W[sel];
  const u16* bias = w.bias[sel];
  void* outp = w.out[sel];

  // ---- master fp32 prefetch (independent of K-loop; drains with first staging) ----
  float mv[MRD ? MI : 1][MRD ? NT : 1][4];
  if (MRD) {
#pragma unroll
    for (int mi = 0; mi < MI; mi++) {
      const int lr = wm * (BM / 2) + mi * 16 + qd * 4;
#pragma unroll
      for (int ni = 0; ni < NT; ni++) {
        int col = n0l + wn * CW + ni * 16 + l15;
#pragma unroll
        for (int r = 0; r < 4; r++)
          mv[mi][ni][r] = master[(size_t)(m0 + lr + r) * DD + col];
      }
    }
  }

  const f32x4 zf = {0.f, 0.f, 0.f, 0.f};
  f32x4 acc[MI][NT];
#pragma unroll
  for (int i = 0; i < MI; i++)
#pragma unroll
    for (int j = 0; j < NT; j++) acc[i][j] = zf;

  for (int k0 = 0; k0 < K; k0 += BK) {
    __syncthreads();
#pragma unroll
    for (int i = 0; i < BM / 64; i++) {               // A tile: BMx32, 16B chunks
      int base = i * 256 + wv * 64;
      int idx = base + lane;
      int row = idx >> 2, c8 = (idx & 3) * 8;
      async_lds16(A + (size_t)(m0 + row) * K + k0 + c8, As + base * 8);
    }
#pragma unroll
    for (int i = 0; i < BN / 64; i++) {               // B rows, clamped tail
      int base = i * 256 + wv * 64;
      int idx = base + lane;
      int row = idx >> 2, c8 = (idx & 3) * 8;
      int gr = n0l + row; if (gr >= nvalid) gr = nvalid - 1;
      async_lds16(W + (size_t)gr * K + k0 + c8, Bs + base * 8);
    }
    __syncthreads();

    short8 af[MI], bfr[NT];
#pragma unroll
    for (int mi = 0; mi < MI; mi++)
      af[mi] = *(const short8*)&As[(wm * (BM / 2) + mi * 16 + l15) * BK + qd * 8];
#pragma unroll
    for (int ni = 0; ni < NT; ni++)
      bfr[ni] = *(const short8*)&Bs[(wn * CW + ni * 16 + l15) * BK + qd * 8];
#pragma unroll
    for (int mi = 0; mi < MI; mi++)
#pragma unroll
      for (int ni = 0; ni < NT; ni++)
        acc[mi][ni] = __builtin_amdgcn_mfma_f32_16x16x32_bf16(af[mi], bfr[ni], acc[mi][ni], 0, 0, 0);
  }

  // C/D layout: col=lane&15, row=(lane>>4)*4+reg [verified m89/m91]
  if (DIRECT) {
    const int sf = (dtf != nullptr) ? *dtf : 0;
#pragma unroll
    for (int mi = 0; mi < MI; mi++)
#pragma unroll
      for (int ni = 0; ni < NT; ni++) {
        int gcol = n0l + wn * CW + ni * 16 + l15;
        float bv = (bias && gcol < nvalid) ? bf2f(bias[gcol]) : 0.f;
#pragma unroll
        for (int r = 0; r < 4; r++) {
          int grow = m0 + wm * (BM / 2) + mi * 16 + qd * 4 + r;
          if (gcol < nvalid) {
            float v = acc[mi][ni][r] + bv;
            if (sf) ((float*)outp)[(size_t)grow * ldo + gcol] = v;
            else    ((u16*)outp)[(size_t)grow * ldo + gcol] = f2bf(v);
          }
        }
      }
    return;
  }

  __syncthreads();                                    // retire staging reads; reuse smem
  u16* slab = smem + wv * 16 * SW;                    // per-wave exclusive, 16 rows
#pragma unroll
  for (int mi = 0; mi < MI; mi++) {
    const int lr = wm * (BM / 2) + mi * 16 + qd * 4;  // local row base (frag layout)
    float v[NT][4];
#pragma unroll
    for (int ni = 0; ni < NT; ni++) {
      const int lc = wn * CW + ni * 16 + l15;
      float bv = bias ? bf2f(bias[n0l + lc]) : 0.f;
#pragma unroll
      for (int r = 0; r < 4; r++) {
        float x = acc[mi][ni][r] + bv;
        if (MRD) x += mv[mi][ni][r];
        if (!QKV && pe) x += bf2f(pe[((m0 + lr + r) % LL) * DD + n0l + lc]);
        if (!QKV && master) master[(size_t)(m0 + lr + r) * DD + n0l + lc] = x;
        if (!QKV && dogelu) x = 0.5f * x * (1.f + erff(x * 0.70710678118654752f));
        v[ni][r] = x;
      }
    }
    // bf16 out via wave-local slab transpose -> full-line stores
#pragma unroll
    for (int ni = 0; ni < NT; ni++)
#pragma unroll
      for (int r = 0; r < 4; r++)
        slab[(qd * 4 + r) * SW + ni * 16 + l15] = f2bf(v[ni][r]);
    wave_lds_fence();
    if (BN == 128) {                                  // 4 lanes x 32B per row = 128B lines
      int r2 = lane >> 2, c2 = (lane & 3) * 16;
      int grow = m0 + wm * (BM / 2) + mi * 16 + r2;
      u16* op = (u16*)outp + (size_t)grow * ldo + n0l + wn * CW + c2;
      *(short8*)&op[0] = *(const short8*)&slab[r2 * SW + c2];
      *(short8*)&op[8] = *(const short8*)&slab[r2 * SW + c2 + 8];
    } else {                                          // BN=64: 2 lanes x 32B per row
      if (lane < 32) {
        int r2 = lane >> 1, c2 = (lane & 1) * 16;
        int grow = m0 + wm * (BM / 2) + mi * 16 + r2;
        u16* op = (u16*)outp + (size_t)grow * ldo + n0l + wn * CW + c2;
        *(short8*)&op[0] = *(const short8*)&slab[r2 * SW + c2];
        *(short8*)&op[8] = *(const short8*)&slab[r2 * SW + c2 + 8];
      }
    }
    wave_lds_fence();                                 // WAR guard before next mi
  }
}

// ---------------- fused attention: one block per (b,h) ----------------
__global__ __launch_bounds__(256)
void attn(const u16* __restrict__ qg, const u16* __restrict__ kg,
          const u16* __restrict__ vg, u16* __restrict__ og)
{
  constexpr int LP = 128;
  __shared__ alignas(16) u16 Ks[LP * DKK];   // 16 KB
  __shared__ alignas(16) u16 Vt[DKK * LP];   // 16 KB  V transposed [d][j]
  __shared__ alignas(16) u16 Ps[LP * LP];    // 32 KB  probs; reused for O staging

  const int bh = blockIdx.x;
  const int b = bh >> 3, h = bh & 7;
  const size_t base = (size_t)b * LL * DD + (size_t)h * DKK;
  const int tid = threadIdx.x, lane = tid & 63, wv = tid >> 6;
  const int l15 = lane & 15, qd = lane >> 4;
  const short8 z8 = {0, 0, 0, 0, 0, 0, 0, 0};

  for (int i = tid; i < LP * 8; i += 256) {            // K rows, zero-padded
    int row = i >> 3, e8 = (i & 7) * 8;
    short8 val = z8;
    if (row < LL) val = *(const short8*)(kg + base + (size_t)row * DD + e8);
    *(short8*)&Ks[row * DKK + e8] = val;
  }
  for (int i = tid; i < LP * 8; i += 256) {            // V transposed
    int j = i & 127, d0 = (i >> 7) * 8;
    short8 val = z8;
    if (j < LL) val = *(const short8*)(vg + base + (size_t)j * DD + d0);
#pragma unroll
    for (int u = 0; u < 8; u++) Vt[(d0 + u) * LP + j] = (u16)val[u];
  }
  __syncthreads();

  const f32x4 zf = {0.f, 0.f, 0.f, 0.f};
  f32x4 sc[2][8];
#pragma unroll
  for (int it = 0; it < 2; it++)
#pragma unroll
    for (int jt = 0; jt < 8; jt++) sc[it][jt] = zf;

  short8 af[2][2];
#pragma unroll
  for (int it = 0; it < 2; it++) {
    int row = (2 * wv + it) * 16 + l15;
#pragma unroll
    for (int ks = 0; ks < 2; ks++) {
      short8 val = z8;
      if (row < LL) val = *(const short8*)(qg + base + (size_t)row * DD + ks * 32 + qd * 8);
      af[it][ks] = val;
    }
  }
#pragma unroll
  for (int jt = 0; jt < 8; jt++) {
    short8 b0 = *(const short8*)&Ks[(jt * 16 + l15) * DKK + qd * 8];
    short8 b1 = *(const short8*)&Ks[(jt * 16 + l15) * DKK + 32 + qd * 8];
#pragma unroll
    for (int it = 0; it < 2; it++) {
      sc[it][jt] = __builtin_amdgcn_mfma_f32_16x16x32_bf16(af[it][0], b0, sc[it][jt], 0, 0, 0);
      sc[it][jt] = __builtin_amdgcn_mfma_f32_16x16x32_bf16(af[it][1], b1, sc[it][jt], 0, 0, 0);
    }
  }

  constexpr float scale = 0.125f;   // 1/sqrt(64)
#pragma unroll
  for (int it = 0; it < 2; it++) {
    int rb = (2 * wv + it) * 16 + qd * 4;
#pragma unroll
    for (int r = 0; r < 4; r++) {
      float vals[8];
      float mx = -1e30f;
#pragma unroll
      for (int jt = 0; jt < 8; jt++) {
        int col = jt * 16 + l15;
        float vv = sc[it][jt][r] * scale;
        if (col >= LL) vv = -1e30f;
        vals[jt] = vv;
        mx = fmaxf(mx, vv);
      }
#pragma unroll
      for (int off = 1; off < 16; off <<= 1) mx = fmaxf(mx, __shfl_xor(mx, off, 64));
      float s = 0.f;
#pragma unroll
      for (int jt = 0; jt < 8; jt++) { float p = __expf(vals[jt] - mx); vals[jt] = p; s += p; }
#pragma unroll
      for (int off = 1; off < 16; off <<= 1) s += __shfl_xor(s, off, 64);
      float inv = 1.f / s;
      int rowp = rb + r;
#pragma unroll
      for (int jt = 0; jt < 8; jt++) Ps[rowp * LP + jt * 16 + l15] = f2bf(vals[jt] * inv);
    }
  }
  __syncthreads();

  f32x4 oc[2][4];
#pragma unroll
  for (int it = 0; it < 2; it++)
#pragma unroll
    for (int dt = 0; dt < 4; dt++) oc[it][dt] = zf;
#pragma unroll
  for (int ks = 0; ks < 4; ks++) {
    short8 ap[2];
#pragma unroll
    for (int it = 0; it < 2; it++)
      ap[it] = *(const short8*)&Ps[((2 * wv + it) * 16 + l15) * LP + ks * 32 + qd * 8];
#pragma unroll
    for (int dt = 0; dt < 4; dt++) {
      short8 bv = *(const short8*)&Vt[(dt * 16 + l15) * LP + ks * 32 + qd * 8];
#pragma unroll
      for (int it = 0; it < 2; it++)
        oc[it][dt] = __builtin_amdgcn_mfma_f32_16x16x32_bf16(ap[it], bv, oc[it][dt], 0, 0, 0);
    }
  }

  // O staging -> vectorized store (reuse Ps as [128][64] bf16)
  __syncthreads();
  u16* Os = Ps;
#pragma unroll
  for (int it = 0; it < 2; it++) {
    int rb = (2 * wv + it) * 16 + qd * 4;
#pragma unroll
    for (int dt = 0; dt < 4; dt++)
#pragma unroll
      for (int r = 0; r < 4; r++)
        Os[(rb + r) * DKK + dt * 16 + l15] = f2bf(oc[it][dt][r]);
  }
  __syncthreads();
  {
    int row = tid >> 1, c0 = (tid & 1) * 32;
    if (row < LL) {
      u16* op = og + base + (size_t)row * DD + c0;
#pragma unroll
      for (int c = 0; c < 32; c += 8)
        *(short8*)&op[c] = *(const short8*)&Os[row * DKK + c0 + c];
    }
  }
}

// ---------------- launch ----------------
extern "C" void kernel_launch(void* const* d_in, const int* in_sizes, int n_in,
                              void* d_out, int out_size, void* d_ws, size_t ws_size,
                              hipStream_t stream)
{
  (void)in_sizes; (void)n_in; (void)out_size; (void)ws_size;

  char* ws = (char*)d_ws;
  size_t off = 0;
  auto alloc = [&](size_t bytes) { char* p = ws + off; off += (bytes + 255) & ~(size_t)255; return p; };
  int* dflag = (int*)alloc(256);
  static const int seg_sizes[NSEG] = {
    MM * CC, DD * CC * 3, LL * DD,
    3 * DD * DD, 3 * DD, 3 * DD * DD, 3 * DD, 3 * DD * DD, 3 * DD,
    3 * DD * DD, 3 * DD, 3 * 64 * DD, 3 * 64, 3 * DD * 64, 3 * DD,
    CC * DD, CC
  };
  static const int seg_input[NSEG] = {0, 1, 2, 3, 4, 5, 6, 7, 8, 11, 12, 13, 14, 15, 16, 17, 18};
  int total = 0, segoff[NSEG + 1];
  for (int i = 0; i < NSEG; i++) { segoff[i] = total; total += seg_sizes[i]; }
  segoff[NSEG] = total;
  u16* canon = (u16*)alloc((size_t)total * 2);

  float* h32 = (float*)alloc((size_t)MM * DD * 4);
  u16* hbf = (u16*)alloc((size_t)MM * DD * 2);
  u16* qb  = (u16*)alloc((size_t)MM * DD * 2);
  u16* kb  = (u16*)alloc((size_t)MM * DD * 2);
  u16* vb  = (u16*)alloc((size_t)MM * DD * 2);
  u16* ob  = (u16*)alloc((size_t)MM * DD * 2);
  u16* yb  = (u16*)alloc((size_t)MM * 64 * 2);
  u16* Wg  = (u16*)alloc((size_t)512 * KEMB * 2);
  u16* Xg  = qb;   // alias: Xg dead before qb first written (stream-serialized)

  const u16* xc  = canon + segoff[0];
  const u16* twc = canon + segoff[1];
  const u16* pec = canon + segoff[2];
  const u16* Wqc = canon + segoff[3];  const u16* bqc = canon + segoff[4];
  const u16* Wkc = canon + segoff[5];  const u16* bkc = canon + segoff[6];
  const u16* Wvc = canon + segoff[7];  const u16* bvc = canon + segoff[8];
  const u16* Woc = canon + segoff[9];  const u16* boc = canon + segoff[10];
  const u16* W1c = canon + segoff[11]; const u16* b1c = canon + segoff[12];
  const u16* W2c = canon + segoff[13]; const u16* b2c = canon + segoff[14];
  const u16* pwc = canon + segoff[15]; const u16* pbc = canon + segoff[16];

  Segs sg;
  for (int i = 0; i < NSEG; i++) { sg.src[i] = d_in[seg_input[i]]; sg.off[i] = segoff[i]; }
  sg.off[NSEG] = total;

  dim3 blk(256);
  detect_dtype<<<dim3(1), blk, 0, stream>>>((const u16*)d_in[0], dflag);
  convert_all<<<dim3((total + 255) / 256), blk, 0, stream>>>(sg, dflag, canon);
  repack_w<<<dim3((512 * KEMB + 255) / 256), blk, 0, stream>>>(twc, Wg);
  repack_x<<<dim3((MM * KEMB + 255) / 256), blk, 0, stream>>>(xc, Xg);

  auto W1of = [&](const u16* p) { GemmW g{}; g.W[0] = g.W[1] = g.W[2] = p; return g; };

  // embedding GEMM: h = Xg @ Wg^T + pe -> h32 (write), hbf   [TAG 0]
  { GemmW g = W1of(Wg); g.out[0] = hbf;
    gemm_bt<128, 128, 0, false, false, false><<<dim3(MM / 128, 4), blk, 0, stream>>>(Xg, KEMB, g, pec, h32, 0, DD, DD, nullptr); }

  for (int l = 0; l < 3; l++) {
    const u16* Wq_l = Wqc + (size_t)l * DD * DD; const u16* bq_l = bqc + l * DD;
    const u16* Wk_l = Wkc + (size_t)l * DD * DD; const u16* bk_l = bkc + l * DD;
    const u16* Wv_l = Wvc + (size_t)l * DD * DD; const u16* bv_l = bvc + l * DD;
    const u16* Wo_l = Woc + (size_t)l * DD * DD; const u16* bo_l = boc + l * DD;
    const u16* W1_l = W1c + (size_t)l * 64 * DD; const u16* b1_l = b1c + l * 64;
    const u16* W2_l = W2c + (size_t)l * DD * 64; const u16* b2_l = b2c + l * DD;

    // fused QKV: BM=256, grid (100, 12), block-uniform sel by n0>>9   [TAG 1]
    { GemmW g{}; g.W[0] = Wq_l; g.W[1] = Wk_l; g.W[2] = Wv_l;
      g.bias[0] = bq_l; g.bias[1] = bk_l; g.bias[2] = bv_l;
      g.out[0] = qb; g.out[1] = kb; g.out[2] = vb;
      gemm_bt<256, 128, 1, true, false, false><<<dim3(MM / 256, 12), blk, 0, stream>>>(hbf, DD, g, nullptr, nullptr, 0, DD, DD, nullptr); }

    attn<<<dim3(BB * HH), blk, 0, stream>>>(qb, kb, vb, ob);

    // h += o @ Wo^T + bo   [TAG 2]  (master read prefetched)
    { GemmW g = W1of(Wo_l); g.bias[0] = g.bias[1] = g.bias[2] = bo_l; g.out[0] = g.out[1] = g.out[2] = hbf;
      gemm_bt<128, 128, 2, false, false, true><<<dim3(MM / 128, 4), blk, 0, stream>>>(ob, DD, g, nullptr, h32, 0, DD, DD, nullptr); }
    // y = gelu(h @ W1^T + b1)   [TAG 3]
    { GemmW g = W1of(W1_l); g.bias[0] = b1_l; g.out[0] = yb;
      gemm_bt<64, 64, 3, false, false, false><<<dim3(MM / 64, 1), blk, 0, stream>>>(hbf, DD, g, nullptr, nullptr, 1, 64, 64, nullptr); }
    // h += y @ W2^T + b2   [TAG 4]  (master read prefetched)
    { GemmW g = W1of(W2_l); g.bias[0] = g.bias[1] = g.bias[2] = b2_l; g.out[0] = g.out[1] = g.out[2] = hbf;
      gemm_bt<128, 128, 4, false, false, true><<<dim3(MM / 128, 4), blk, 0, stream>>>(yb, 64, g, nullptr, h32, 0, DD, DD, nullptr); }
  }
  // out = h @ proj_w^T + proj_b (N=55, direct masked stores; dtype per flag)   [TAG 5]
  { GemmW g = W1of(pwc); g.bias[0] = pbc; g.out[0] = d_out;
    gemm_bt<64, 64, 5, false, true, false><<<dim3(MM / 64, 1), blk, 0, stream>>>(hbf, DD, g, nullptr, nullptr, 0, CC, CC, dflag); }
}

// Round 7
// 807.071 us; speedup vs baseline: 1.4619x; 1.4619x over previous
//
#include <hip/hip_runtime.h>
#include <stdint.h>

typedef unsigned short u16;
typedef __attribute__((ext_vector_type(8))) short short8;
typedef __attribute__((ext_vector_type(4))) float f32x4;

#define DEVI __device__ __forceinline__

// problem constants
#define BB   256
#define LL   100
#define CC   55
#define DD   512
#define HH   8
#define DKK  64
#define MM   (BB * LL)   // 25600 tokens
#define KEMB 192         // 3 * 64 (c padded 55->64)
#define NSEG 17

DEVI float bf2f(u16 s) { union { unsigned int u; float f; } x; x.u = ((unsigned int)s) << 16; return x.f; }
DEVI u16 f2bf(float f) {
  union { float f; unsigned int u; } x; x.f = f;
  unsigned int u = x.u;
  return (u16)((u + 0x7FFFu + ((u >> 16) & 1u)) >> 16);
}

DEVI void async_lds16(const u16* gp, u16* lp) {
  __builtin_amdgcn_global_load_lds((const __attribute__((address_space(1))) void*)gp,
                                   (__attribute__((address_space(3))) void*)lp, 16, 0, 0);
}

DEVI void wave_lds_fence() {   // wave-local LDS RAW/WAR fence (no cross-wave sync)
  asm volatile("s_waitcnt lgkmcnt(0)" ::: "memory");
  __builtin_amdgcn_wave_barrier();
}

// ---------------- dtype detect + canonicalize ----------------
__global__ void detect_dtype(const u16* __restrict__ x, int* __restrict__ flag) {
  __shared__ int cnt[256];
  int tid = threadIdx.x;
  u16 u = x[2 * tid];
  int e = (u >> 7) & 0xFF;
  cnt[tid] = (e >= 0x5F && e <= 0x90) ? 1 : 0;   // |v| in [2^-32, 2^17]
  __syncthreads();
  for (int s = 128; s > 0; s >>= 1) { if (tid < s) cnt[tid] += cnt[tid + s]; __syncthreads(); }
  if (tid == 0) *flag = (cnt[0] >= 160) ? 0 : 1;
}

struct Segs { const void* src[NSEG]; int off[NSEG + 1]; };

__global__ void convert_all(Segs s, const int* __restrict__ flag, u16* __restrict__ dst) {
  int i = blockIdx.x * 256 + threadIdx.x;
  if (i >= s.off[NSEG]) return;
  int sidx = 0;
#pragma unroll
  for (int k = 1; k < NSEG; k++) if (i >= s.off[k]) sidx = k;
  int j = i - s.off[sidx];
  u16 v;
  if (*flag) v = f2bf(((const float*)s.src[sidx])[j]);
  else       v = ((const u16*)s.src[sidx])[j];
  dst[i] = v;
}

// ---------------- repack kernels (embedding conv -> GEMM) ----------------
__global__ void repack_w(const u16* __restrict__ tokw, u16* __restrict__ Wg) {
  int idx = blockIdx.x * 256 + threadIdx.x;   // 512*192
  if (idx >= 512 * KEMB) return;
  int d = idx / KEMB, j = idx % KEMB, k = j >> 6, c = j & 63;
  Wg[idx] = (c < CC) ? tokw[d * (CC * 3) + c * 3 + k] : (u16)0;
}

__global__ void repack_x(const u16* __restrict__ x, u16* __restrict__ Xg) {
  int idx = blockIdx.x * 256 + threadIdx.x;   // 25600*192
  if (idx >= MM * KEMB) return;
  int m = idx / KEMB, j = idx % KEMB, k = j >> 6, c = j & 63;
  int b = m / LL, l = m % LL;
  int l2 = l + k - 1; l2 = (l2 + LL) % LL;    // circular pad
  Xg[idx] = (c < CC) ? x[(size_t)(b * LL + l2) * CC + c] : (u16)0;
}

// ---------------- bf16 MFMA GEMM: out = A[M,K] @ W[N,K]^T (+epilogue) ----------------
// R5 config (BM=128/BK=32 banking, 72 VGPR, verified locality sweet spot) with
// K-loop UNROLL-2: two BK=32 panels staged per barrier pair (16 -> 8 drains).
// Panel-local fragment addressing keeps the conflict-free BK=32 LDS banking.
// QKV: grid.y spans 3 concatenated weight sets (sel by n0>>9).
struct GemmW { const u16* W[3]; const u16* bias[3]; void* out[3]; };

template<int BM, int BN, int TAG, bool QKV, bool DIRECT>
__global__ __launch_bounds__(256)
void gemm_bt(const u16* __restrict__ A, int K, GemmW w,
             const u16* __restrict__ pe,     // if non-null: add pe[(m%100)*512+col]
             float* __restrict__ master,     // if non-null: (addm? +=) write fp32 master [M,512]
             int addm, int dogelu,
             int ldo, int nvalid,
             const int* __restrict__ dtf)    // DIRECT only: *dtf==1 -> fp32 store
{
  constexpr int BK = 32;                      // panel width (banking unit)
  constexpr int MI = BM / 32;                 // 16-row tiles per wave
  constexpr int CW = BN / 2, NT = CW / 16;    // cols per wave
  constexpr int SW = CW + 4;                  // epilogue slab stride (u16)
  constexpr int STAGE_U16 = (BM + BN) * BK * 2;   // two panels
  __shared__ alignas(16) u16 smem[STAGE_U16];
  u16* As = smem;                             // [2][BM][32]
  u16* Bs = smem + BM * BK * 2;               // [2][BN][32]

  const int tid = threadIdx.x;
  const int lane = tid & 63;
  const int wv = __builtin_amdgcn_readfirstlane(tid >> 6);
  const int wm = wv & 1, wn = wv >> 1;
  const int l15 = lane & 15, qd = lane >> 4;
  const int m0 = blockIdx.x * BM;
  int n0 = blockIdx.y * BN;
  int sel = 0, n0l = n0;
  if (QKV) { sel = n0 >> 9; n0l = n0 & 511; }
  const u16* W = w.W[sel];
  const u16* bias = w.bias[sel];
  void* outp = w.out[sel];

  const f32x4 zf = {0.f, 0.f, 0.f, 0.f};
  f32x4 acc[MI][NT];
#pragma unroll
  for (int i = 0; i < MI; i++)
#pragma unroll
    for (int j = 0; j < NT; j++) acc[i][j] = zf;

  for (int k0 = 0; k0 < K; k0 += 2 * BK) {
    __syncthreads();
#pragma unroll
    for (int p = 0; p < 2; p++) {
      u16* Asp = As + p * BM * BK;
      u16* Bsp = Bs + p * BN * BK;
      const int kp = k0 + p * BK;
#pragma unroll
      for (int i = 0; i < BM / 64; i++) {             // A panel: BMx32, 16B chunks
        int base = i * 256 + wv * 64;
        int idx = base + lane;
        int row = idx >> 2, c8 = (idx & 3) * 8;
        async_lds16(A + (size_t)(m0 + row) * K + kp + c8, Asp + base * 8);
      }
#pragma unroll
      for (int i = 0; i < BN / 64; i++) {             // B panel rows, clamped tail
        int base = i * 256 + wv * 64;
        int idx = base + lane;
        int row = idx >> 2, c8 = (idx & 3) * 8;
        int gr = n0l + row; if (gr >= nvalid) gr = nvalid - 1;
        async_lds16(W + (size_t)gr * K + kp + c8, Bsp + base * 8);
      }
    }
    __syncthreads();

#pragma unroll
    for (int p = 0; p < 2; p++) {
      const u16* Asp = As + p * BM * BK;
      const u16* Bsp = Bs + p * BN * BK;
      short8 af[MI], bfr[NT];
#pragma unroll
      for (int mi = 0; mi < MI; mi++)
        af[mi] = *(const short8*)&Asp[(wm * (BM / 2) + mi * 16 + l15) * BK + qd * 8];
#pragma unroll
      for (int ni = 0; ni < NT; ni++)
        bfr[ni] = *(const short8*)&Bsp[(wn * CW + ni * 16 + l15) * BK + qd * 8];
#pragma unroll
      for (int mi = 0; mi < MI; mi++)
#pragma unroll
        for (int ni = 0; ni < NT; ni++)
          acc[mi][ni] = __builtin_amdgcn_mfma_f32_16x16x32_bf16(af[mi], bfr[ni], acc[mi][ni], 0, 0, 0);
    }
  }

  // C/D layout: col=lane&15, row=(lane>>4)*4+reg [verified m89/m91]
  if (DIRECT) {
    const int sf = (dtf != nullptr) ? *dtf : 0;
#pragma unroll
    for (int mi = 0; mi < MI; mi++)
#pragma unroll
      for (int ni = 0; ni < NT; ni++) {
        int gcol = n0l + wn * CW + ni * 16 + l15;
        float bv = (bias && gcol < nvalid) ? bf2f(bias[gcol]) : 0.f;
#pragma unroll
        for (int r = 0; r < 4; r++) {
          int grow = m0 + wm * (BM / 2) + mi * 16 + qd * 4 + r;
          if (gcol < nvalid) {
            float v = acc[mi][ni][r] + bv;
            if (sf) ((float*)outp)[(size_t)grow * ldo + gcol] = v;
            else    ((u16*)outp)[(size_t)grow * ldo + gcol] = f2bf(v);
          }
        }
      }
    return;
  }

  __syncthreads();                                    // retire staging reads; reuse smem
  u16* slab = smem + wv * 16 * SW;                    // per-wave exclusive, 16 rows
#pragma unroll
  for (int mi = 0; mi < MI; mi++) {
    const int lr = wm * (BM / 2) + mi * 16 + qd * 4;  // local row base (frag layout)
    float v[NT][4];
    // batched master fp32 loads (quad-coalesced 64B segments)
    if (!QKV && master && addm) {
#pragma unroll
      for (int ni = 0; ni < NT; ni++) {
        int col = n0l + wn * CW + ni * 16 + l15;
#pragma unroll
        for (int r = 0; r < 4; r++)
          v[ni][r] = master[(size_t)(m0 + lr + r) * DD + col];
      }
    } else {
#pragma unroll
      for (int ni = 0; ni < NT; ni++)
#pragma unroll
        for (int r = 0; r < 4; r++) v[ni][r] = 0.f;
    }
#pragma unroll
    for (int ni = 0; ni < NT; ni++) {
      const int lc = wn * CW + ni * 16 + l15;
      float bv = bias ? bf2f(bias[n0l + lc]) : 0.f;
#pragma unroll
      for (int r = 0; r < 4; r++) {
        float x = v[ni][r] + acc[mi][ni][r] + bv;
        if (!QKV && pe) x += bf2f(pe[((m0 + lr + r) % LL) * DD + n0l + lc]);
        if (!QKV && master) master[(size_t)(m0 + lr + r) * DD + n0l + lc] = x;
        if (!QKV && dogelu) x = 0.5f * x * (1.f + erff(x * 0.70710678118654752f));
        v[ni][r] = x;
      }
    }
    // bf16 out via wave-local slab transpose -> full-line stores
#pragma unroll
    for (int ni = 0; ni < NT; ni++)
#pragma unroll
      for (int r = 0; r < 4; r++)
        slab[(qd * 4 + r) * SW + ni * 16 + l15] = f2bf(v[ni][r]);
    wave_lds_fence();
    if (BN == 128) {                                  // 4 lanes x 32B per row = 128B lines
      int r2 = lane >> 2, c2 = (lane & 3) * 16;
      int grow = m0 + wm * (BM / 2) + mi * 16 + r2;
      u16* op = (u16*)outp + (size_t)grow * ldo + n0l + wn * CW + c2;
      *(short8*)&op[0] = *(const short8*)&slab[r2 * SW + c2];
      *(short8*)&op[8] = *(const short8*)&slab[r2 * SW + c2 + 8];
    } else {                                          // BN=64: 2 lanes x 32B per row
      if (lane < 32) {
        int r2 = lane >> 1, c2 = (lane & 1) * 16;
        int grow = m0 + wm * (BM / 2) + mi * 16 + r2;
        u16* op = (u16*)outp + (size_t)grow * ldo + n0l + wn * CW + c2;
        *(short8*)&op[0] = *(const short8*)&slab[r2 * SW + c2];
        *(short8*)&op[8] = *(const short8*)&slab[r2 * SW + c2 + 8];
      }
    }
    wave_lds_fence();                                 // WAR guard before next mi
  }
}

// ---------------- fused attention: one block per (b,h) ----------------
__global__ __launch_bounds__(256)
void attn(const u16* __restrict__ qg, const u16* __restrict__ kg,
          const u16* __restrict__ vg, u16* __restrict__ og)
{
  constexpr int LP = 128;
  __shared__ alignas(16) u16 Ks[LP * DKK];   // 16 KB
  __shared__ alignas(16) u16 Vt[DKK * LP];   // 16 KB  V transposed [d][j]
  __shared__ alignas(16) u16 Ps[LP * LP];    // 32 KB  probs; reused for O staging

  const int bh = blockIdx.x;
  const int b = bh >> 3, h = bh & 7;
  const size_t base = (size_t)b * LL * DD + (size_t)h * DKK;
  const int tid = threadIdx.x, lane = tid & 63, wv = tid >> 6;
  const int l15 = lane & 15, qd = lane >> 4;
  const short8 z8 = {0, 0, 0, 0, 0, 0, 0, 0};

  for (int i = tid; i < LP * 8; i += 256) {            // K rows, zero-padded
    int row = i >> 3, e8 = (i & 7) * 8;
    short8 val = z8;
    if (row < LL) val = *(const short8*)(kg + base + (size_t)row * DD + e8);
    *(short8*)&Ks[row * DKK + e8] = val;
  }
  for (int i = tid; i < LP * 8; i += 256) {            // V transposed
    int j = i & 127, d0 = (i >> 7) * 8;
    short8 val = z8;
    if (j < LL) val = *(const short8*)(vg + base + (size_t)j * DD + d0);
#pragma unroll
    for (int u = 0; u < 8; u++) Vt[(d0 + u) * LP + j] = (u16)val[u];
  }
  __syncthreads();

  const f32x4 zf = {0.f, 0.f, 0.f, 0.f};
  f32x4 sc[2][8];
#pragma unroll
  for (int it = 0; it < 2; it++)
#pragma unroll
    for (int jt = 0; jt < 8; jt++) sc[it][jt] = zf;

  short8 af[2][2];
#pragma unroll
  for (int it = 0; it < 2; it++) {
    int row = (2 * wv + it) * 16 + l15;
#pragma unroll
    for (int ks = 0; ks < 2; ks++) {
      short8 val = z8;
      if (row < LL) val = *(const short8*)(qg + base + (size_t)row * DD + ks * 32 + qd * 8);
      af[it][ks] = val;
    }
  }
#pragma unroll
  for (int jt = 0; jt < 8; jt++) {
    short8 b0 = *(const short8*)&Ks[(jt * 16 + l15) * DKK + qd * 8];
    short8 b1 = *(const short8*)&Ks[(jt * 16 + l15) * DKK + 32 + qd * 8];
#pragma unroll
    for (int it = 0; it < 2; it++) {
      sc[it][jt] = __builtin_amdgcn_mfma_f32_16x16x32_bf16(af[it][0], b0, sc[it][jt], 0, 0, 0);
      sc[it][jt] = __builtin_amdgcn_mfma_f32_16x16x32_bf16(af[it][1], b1, sc[it][jt], 0, 0, 0);
    }
  }

  constexpr float scale = 0.125f;   // 1/sqrt(64)
#pragma unroll
  for (int it = 0; it < 2; it++) {
    int rb = (2 * wv + it) * 16 + qd * 4;
#pragma unroll
    for (int r = 0; r < 4; r++) {
      float vals[8];
      float mx = -1e30f;
#pragma unroll
      for (int jt = 0; jt < 8; jt++) {
        int col = jt * 16 + l15;
        float vv = sc[it][jt][r] * scale;
        if (col >= LL) vv = -1e30f;
        vals[jt] = vv;
        mx = fmaxf(mx, vv);
      }
#pragma unroll
      for (int off = 1; off < 16; off <<= 1) mx = fmaxf(mx, __shfl_xor(mx, off, 64));
      float s = 0.f;
#pragma unroll
      for (int jt = 0; jt < 8; jt++) { float p = __expf(vals[jt] - mx); vals[jt] = p; s += p; }
#pragma unroll
      for (int off = 1; off < 16; off <<= 1) s += __shfl_xor(s, off, 64);
      float inv = 1.f / s;
      int rowp = rb + r;
#pragma unroll
      for (int jt = 0; jt < 8; jt++) Ps[rowp * LP + jt * 16 + l15] = f2bf(vals[jt] * inv);
    }
  }
  __syncthreads();

  f32x4 oc[2][4];
#pragma unroll
  for (int it = 0; it < 2; it++)
#pragma unroll
    for (int dt = 0; dt < 4; dt++) oc[it][dt] = zf;
#pragma unroll
  for (int ks = 0; ks < 4; ks++) {
    short8 ap[2];
#pragma unroll
    for (int it = 0; it < 2; it++)
      ap[it] = *(const short8*)&Ps[((2 * wv + it) * 16 + l15) * LP + ks * 32 + qd * 8];
#pragma unroll
    for (int dt = 0; dt < 4; dt++) {
      short8 bv = *(const short8*)&Vt[(dt * 16 + l15) * LP + ks * 32 + qd * 8];
#pragma unroll
      for (int it = 0; it < 2; it++)
        oc[it][dt] = __builtin_amdgcn_mfma_f32_16x16x32_bf16(ap[it], bv, oc[it][dt], 0, 0, 0);
    }
  }

  // O staging -> vectorized store (reuse Ps as [128][64] bf16)
  __syncthreads();
  u16* Os = Ps;
#pragma unroll
  for (int it = 0; it < 2; it++) {
    int rb = (2 * wv + it) * 16 + qd * 4;
#pragma unroll
    for (int dt = 0; dt < 4; dt++)
#pragma unroll
      for (int r = 0; r < 4; r++)
        Os[(rb + r) * DKK + dt * 16 + l15] = f2bf(oc[it][dt][r]);
  }
  __syncthreads();
  {
    int row = tid >> 1, c0 = (tid & 1) * 32;
    if (row < LL) {
      u16* op = og + base + (size_t)row * DD + c0;
#pragma unroll
      for (int c = 0; c < 32; c += 8)
        *(short8*)&op[c] = *(const short8*)&Os[row * DKK + c0 + c];
    }
  }
}

// ---------------- launch ----------------
extern "C" void kernel_launch(void* const* d_in, const int* in_sizes, int n_in,
                              void* d_out, int out_size, void* d_ws, size_t ws_size,
                              hipStream_t stream)
{
  (void)in_sizes; (void)n_in; (void)out_size; (void)ws_size;

  char* ws = (char*)d_ws;
  size_t off = 0;
  auto alloc = [&](size_t bytes) { char* p = ws + off; off += (bytes + 255) & ~(size_t)255; return p; };
  int* dflag = (int*)alloc(256);
  static const int seg_sizes[NSEG] = {
    MM * CC, DD * CC * 3, LL * DD,
    3 * DD * DD, 3 * DD, 3 * DD * DD, 3 * DD, 3 * DD * DD, 3 * DD,
    3 * DD * DD, 3 * DD, 3 * 64 * DD, 3 * 64, 3 * DD * 64, 3 * DD,
    CC * DD, CC
  };
  static const int seg_input[NSEG] = {0, 1, 2, 3, 4, 5, 6, 7, 8, 11, 12, 13, 14, 15, 16, 17, 18};
  int total = 0, segoff[NSEG + 1];
  for (int i = 0; i < NSEG; i++) { segoff[i] = total; total += seg_sizes[i]; }
  segoff[NSEG] = total;
  u16* canon = (u16*)alloc((size_t)total * 2);

  float* h32 = (float*)alloc((size_t)MM * DD * 4);
  u16* hbf = (u16*)alloc((size_t)MM * DD * 2);
  u16* qb  = (u16*)alloc((size_t)MM * DD * 2);
  u16* kb  = (u16*)alloc((size_t)MM * DD * 2);
  u16* vb  = (u16*)alloc((size_t)MM * DD * 2);
  u16* ob  = (u16*)alloc((size_t)MM * DD * 2);
  u16* yb  = (u16*)alloc((size_t)MM * 64 * 2);
  u16* Wg  = (u16*)alloc((size_t)512 * KEMB * 2);
  u16* Xg  = qb;   // alias: Xg dead before qb first written (stream-serialized)

  const u16* xc  = canon + segoff[0];
  const u16* twc = canon + segoff[1];
  const u16* pec = canon + segoff[2];
  const u16* Wqc = canon + segoff[3];  const u16* bqc = canon + segoff[4];
  const u16* Wkc = canon + segoff[5];  const u16* bkc = canon + segoff[6];
  const u16* Wvc = canon + segoff[7];  const u16* bvc = canon + segoff[8];
  const u16* Woc = canon + segoff[9];  const u16* boc = canon + segoff[10];
  const u16* W1c = canon + segoff[11]; const u16* b1c = canon + segoff[12];
  const u16* W2c = canon + segoff[13]; const u16* b2c = canon + segoff[14];
  const u16* pwc = canon + segoff[15]; const u16* pbc = canon + segoff[16];

  Segs sg;
  for (int i = 0; i < NSEG; i++) { sg.src[i] = d_in[seg_input[i]]; sg.off[i] = segoff[i]; }
  sg.off[NSEG] = total;

  dim3 blk(256);
  detect_dtype<<<dim3(1), blk, 0, stream>>>((const u16*)d_in[0], dflag);
  convert_all<<<dim3((total + 255) / 256), blk, 0, stream>>>(sg, dflag, canon);
  repack_w<<<dim3((512 * KEMB + 255) / 256), blk, 0, stream>>>(twc, Wg);
  repack_x<<<dim3((MM * KEMB + 255) / 256), blk, 0, stream>>>(xc, Xg);

  auto W1of = [&](const u16* p) { GemmW g{}; g.W[0] = g.W[1] = g.W[2] = p; return g; };

  // embedding GEMM: h = Xg @ Wg^T + pe -> h32 (write), hbf   [TAG 0]
  { GemmW g = W1of(Wg); g.out[0] = hbf;
    gemm_bt<128, 128, 0, false, false><<<dim3(MM / 128, 4), blk, 0, stream>>>(Xg, KEMB, g, pec, h32, 0, 0, DD, DD, nullptr); }

  for (int l = 0; l < 3; l++) {
    const u16* Wq_l = Wqc + (size_t)l * DD * DD; const u16* bq_l = bqc + l * DD;
    const u16* Wk_l = Wkc + (size_t)l * DD * DD; const u16* bk_l = bkc + l * DD;
    const u16* Wv_l = Wvc + (size_t)l * DD * DD; const u16* bv_l = bvc + l * DD;
    const u16* Wo_l = Woc + (size_t)l * DD * DD; const u16* bo_l = boc + l * DD;
    const u16* W1_l = W1c + (size_t)l * 64 * DD; const u16* b1_l = b1c + l * 64;
    const u16* W2_l = W2c + (size_t)l * DD * 64; const u16* b2_l = b2c + l * DD;

    // fused QKV: BM=128, grid (200, 12), block-uniform sel by n0>>9   [TAG 1]
    { GemmW g{}; g.W[0] = Wq_l; g.W[1] = Wk_l; g.W[2] = Wv_l;
      g.bias[0] = bq_l; g.bias[1] = bk_l; g.bias[2] = bv_l;
      g.out[0] = qb; g.out[1] = kb; g.out[2] = vb;
      gemm_bt<128, 128, 1, true, false><<<dim3(MM / 128, 12), blk, 0, stream>>>(hbf, DD, g, nullptr, nullptr, 0, 0, DD, DD, nullptr); }

    attn<<<dim3(BB * HH), blk, 0, stream>>>(qb, kb, vb, ob);

    // h += o @ Wo^T + bo   [TAG 2]
    { GemmW g = W1of(Wo_l); g.bias[0] = g.bias[1] = g.bias[2] = bo_l; g.out[0] = g.out[1] = g.out[2] = hbf;
      gemm_bt<128, 128, 2, false, false><<<dim3(MM / 128, 4), blk, 0, stream>>>(ob, DD, g, nullptr, h32, 1, 0, DD, DD, nullptr); }
    // y = gelu(h @ W1^T + b1)   [TAG 3]
    { GemmW g = W1of(W1_l); g.bias[0] = b1_l; g.out[0] = yb;
      gemm_bt<64, 64, 3, false, false><<<dim3(MM / 64, 1), blk, 0, stream>>>(hbf, DD, g, nullptr, nullptr, 0, 1, 64, 64, nullptr); }
    // h += y @ W2^T + b2   [TAG 4]
    { GemmW g = W1of(W2_l); g.bias[0] = g.bias[1] = g.bias[2] = b2_l; g.out[0] = g.out[1] = g.out[2] = hbf;
      gemm_bt<128, 128, 4, false, false><<<dim3(MM / 128, 4), blk, 0, stream>>>(yb, 64, g, nullptr, h32, 1, 0, DD, DD, nullptr); }
  }
  // out = h @ proj_w^T + proj_b (N=55, direct masked stores; dtype per flag)   [TAG 5]
  { GemmW g = W1of(pwc); g.bias[0] = pbc; g.out[0] = d_out;
    gemm_bt<64, 64, 5, false, true><<<dim3(MM / 64, 1), blk, 0, stream>>>(hbf, DD, g, nullptr, nullptr, 0, 0, CC, CC, dflag); }
}

// Round 8
// 753.086 us; speedup vs baseline: 1.5667x; 1.0717x over previous
//
#include <hip/hip_runtime.h>
#include <stdint.h>

typedef unsigned short u16;
typedef __attribute__((ext_vector_type(8))) short short8;
typedef __attribute__((ext_vector_type(4))) float f32x4;

#define DEVI __device__ __forceinline__

// problem constants
#define BB   256
#define LL   100
#define CC   55
#define DD   512
#define HH   8
#define DKK  64
#define MM   (BB * LL)   // 25600 tokens
#define KEMB 192         // 3 * 64 (c padded 55->64)
#define NSEG 17

DEVI float bf2f(u16 s) { union { unsigned int u; float f; } x; x.u = ((unsigned int)s) << 16; return x.f; }
DEVI u16 f2bf(float f) {
  union { float f; unsigned int u; } x; x.f = f;
  unsigned int u = x.u;
  return (u16)((u + 0x7FFFu + ((u >> 16) & 1u)) >> 16);
}

DEVI void async_lds16(const u16* gp, u16* lp) {
  __builtin_amdgcn_global_load_lds((const __attribute__((address_space(1))) void*)gp,
                                   (__attribute__((address_space(3))) void*)lp, 16, 0, 0);
}

DEVI void wave_lds_fence() {   // wave-local LDS RAW/WAR fence (no cross-wave sync)
  asm volatile("s_waitcnt lgkmcnt(0)" ::: "memory");
  __builtin_amdgcn_wave_barrier();
}

// ---------------- dtype detect + canonicalize ----------------
__global__ void detect_dtype(const u16* __restrict__ x, int* __restrict__ flag) {
  __shared__ int cnt[256];
  int tid = threadIdx.x;
  u16 u = x[2 * tid];
  int e = (u >> 7) & 0xFF;
  cnt[tid] = (e >= 0x5F && e <= 0x90) ? 1 : 0;   // |v| in [2^-32, 2^17]
  __syncthreads();
  for (int s = 128; s > 0; s >>= 1) { if (tid < s) cnt[tid] += cnt[tid + s]; __syncthreads(); }
  if (tid == 0) *flag = (cnt[0] >= 160) ? 0 : 1;
}

struct Segs { const void* src[NSEG]; int off[NSEG + 1]; };

__global__ void convert_all(Segs s, const int* __restrict__ flag, u16* __restrict__ dst) {
  int i = blockIdx.x * 256 + threadIdx.x;
  if (i >= s.off[NSEG]) return;
  int sidx = 0;
#pragma unroll
  for (int k = 1; k < NSEG; k++) if (i >= s.off[k]) sidx = k;
  int j = i - s.off[sidx];
  u16 v;
  if (*flag) v = f2bf(((const float*)s.src[sidx])[j]);
  else       v = ((const u16*)s.src[sidx])[j];
  dst[i] = v;
}

// ---------------- repack kernels (embedding conv -> GEMM) ----------------
__global__ void repack_w(const u16* __restrict__ tokw, u16* __restrict__ Wg) {
  int idx = blockIdx.x * 256 + threadIdx.x;   // 512*192
  if (idx >= 512 * KEMB) return;
  int d = idx / KEMB, j = idx % KEMB, k = j >> 6, c = j & 63;
  Wg[idx] = (c < CC) ? tokw[d * (CC * 3) + c * 3 + k] : (u16)0;
}

__global__ void repack_x(const u16* __restrict__ x, u16* __restrict__ Xg) {
  int idx = blockIdx.x * 256 + threadIdx.x;   // 25600*192
  if (idx >= MM * KEMB) return;
  int m = idx / KEMB, j = idx % KEMB, k = j >> 6, c = j & 63;
  int b = m / LL, l = m % LL;
  int l2 = l + k - 1; l2 = (l2 + LL) % LL;    // circular pad
  Xg[idx] = (c < CC) ? x[(size_t)(b * LL + l2) * CC + c] : (u16)0;
}

// ---------------- bf16 MFMA GEMM: out = A[M,K] @ W[N,K]^T (+epilogue) ----------------
// BM=128/BK=32 banking, K-loop unroll-2 (R7). Grid is N-MAJOR: x = N-tiles,
// y = M-tiles, so consecutive blocks share the A row-block in L2 (A is the
// dominant read). Residual stream is bf16 (resid ptr), read in C-fragment
// layout; in-place resid==out is race-free (element read+store same wave).
// QKV: grid.x spans 3 concatenated weight sets (sel by n0>>9).
struct GemmW { const u16* W[3]; const u16* bias[3]; void* out[3]; };

template<int BM, int BN, int TAG, bool QKV, bool DIRECT>
__global__ __launch_bounds__(256)
void gemm_bt(const u16* __restrict__ A, int K, GemmW w,
             const u16* __restrict__ pe,     // if non-null: add pe[(m%100)*512+col]
             const u16* __restrict__ resid,  // if non-null: add resid[m*512+col] (bf16)
             int dogelu,
             int ldo, int nvalid,
             const int* __restrict__ dtf)    // DIRECT only: *dtf==1 -> fp32 store
{
  constexpr int BK = 32;                      // panel width (banking unit)
  constexpr int MI = BM / 32;                 // 16-row tiles per wave
  constexpr int CW = BN / 2, NT = CW / 16;    // cols per wave
  constexpr int SW = CW + 4;                  // epilogue slab stride (u16)
  constexpr int STAGE_U16 = (BM + BN) * BK * 2;   // two panels
  __shared__ alignas(16) u16 smem[STAGE_U16];
  u16* As = smem;                             // [2][BM][32]
  u16* Bs = smem + BM * BK * 2;               // [2][BN][32]

  const int tid = threadIdx.x;
  const int lane = tid & 63;
  const int wv = __builtin_amdgcn_readfirstlane(tid >> 6);
  const int wm = wv & 1, wn = wv >> 1;
  const int l15 = lane & 15, qd = lane >> 4;
  const int m0 = blockIdx.y * BM;             // N-major: y = M-tile
  int n0 = blockIdx.x * BN;                   //          x = N-tile
  int sel = 0, n0l = n0;
  if (QKV) { sel = n0 >> 9; n0l = n0 & 511; }
  const u16* W = w.W[sel];
  const u16* bias = w.bias[sel];
  void* outp = w.out[sel];

  const f32x4 zf = {0.f, 0.f, 0.f, 0.f};
  f32x4 acc[MI][NT];
#pragma unroll
  for (int i = 0; i < MI; i++)
#pragma unroll
    for (int j = 0; j < NT; j++) acc[i][j] = zf;

  for (int k0 = 0; k0 < K; k0 += 2 * BK) {
    __syncthreads();
#pragma unroll
    for (int p = 0; p < 2; p++) {
      u16* Asp = As + p * BM * BK;
      u16* Bsp = Bs + p * BN * BK;
      const int kp = k0 + p * BK;
#pragma unroll
      for (int i = 0; i < BM / 64; i++) {             // A panel: BMx32, 16B chunks
        int base = i * 256 + wv * 64;
        int idx = base + lane;
        int row = idx >> 2, c8 = (idx & 3) * 8;
        async_lds16(A + (size_t)(m0 + row) * K + kp + c8, Asp + base * 8);
      }
#pragma unroll
      for (int i = 0; i < BN / 64; i++) {             // B panel rows, clamped tail
        int base = i * 256 + wv * 64;
        int idx = base + lane;
        int row = idx >> 2, c8 = (idx & 3) * 8;
        int gr = n0l + row; if (gr >= nvalid) gr = nvalid - 1;
        async_lds16(W + (size_t)gr * K + kp + c8, Bsp + base * 8);
      }
    }
    __syncthreads();

#pragma unroll
    for (int p = 0; p < 2; p++) {
      const u16* Asp = As + p * BM * BK;
      const u16* Bsp = Bs + p * BN * BK;
      short8 af[MI], bfr[NT];
#pragma unroll
      for (int mi = 0; mi < MI; mi++)
        af[mi] = *(const short8*)&Asp[(wm * (BM / 2) + mi * 16 + l15) * BK + qd * 8];
#pragma unroll
      for (int ni = 0; ni < NT; ni++)
        bfr[ni] = *(const short8*)&Bsp[(wn * CW + ni * 16 + l15) * BK + qd * 8];
#pragma unroll
      for (int mi = 0; mi < MI; mi++)
#pragma unroll
        for (int ni = 0; ni < NT; ni++)
          acc[mi][ni] = __builtin_amdgcn_mfma_f32_16x16x32_bf16(af[mi], bfr[ni], acc[mi][ni], 0, 0, 0);
    }
  }

  // C/D layout: col=lane&15, row=(lane>>4)*4+reg [verified m89/m91]
  if (DIRECT) {
    const int sf = (dtf != nullptr) ? *dtf : 0;
#pragma unroll
    for (int mi = 0; mi < MI; mi++)
#pragma unroll
      for (int ni = 0; ni < NT; ni++) {
        int gcol = n0l + wn * CW + ni * 16 + l15;
        float bv = (bias && gcol < nvalid) ? bf2f(bias[gcol]) : 0.f;
#pragma unroll
        for (int r = 0; r < 4; r++) {
          int grow = m0 + wm * (BM / 2) + mi * 16 + qd * 4 + r;
          if (gcol < nvalid) {
            float v = acc[mi][ni][r] + bv;
            if (sf) ((float*)outp)[(size_t)grow * ldo + gcol] = v;
            else    ((u16*)outp)[(size_t)grow * ldo + gcol] = f2bf(v);
          }
        }
      }
    return;
  }

  __syncthreads();                                    // retire staging reads; reuse smem
  u16* slab = smem + wv * 16 * SW;                    // per-wave exclusive, 16 rows
#pragma unroll
  for (int mi = 0; mi < MI; mi++) {
    const int lr = wm * (BM / 2) + mi * 16 + qd * 4;  // local row base (frag layout)
    float v[NT][4];
    // batched bf16 residual loads (quad-coalesced 32B segments)
    if (!QKV && resid) {
#pragma unroll
      for (int ni = 0; ni < NT; ni++) {
        int col = n0l + wn * CW + ni * 16 + l15;
#pragma unroll
        for (int r = 0; r < 4; r++)
          v[ni][r] = bf2f(resid[(size_t)(m0 + lr + r) * DD + col]);
      }
    } else {
#pragma unroll
      for (int ni = 0; ni < NT; ni++)
#pragma unroll
        for (int r = 0; r < 4; r++) v[ni][r] = 0.f;
    }
#pragma unroll
    for (int ni = 0; ni < NT; ni++) {
      const int lc = wn * CW + ni * 16 + l15;
      float bv = bias ? bf2f(bias[n0l + lc]) : 0.f;
#pragma unroll
      for (int r = 0; r < 4; r++) {
        float x = v[ni][r] + acc[mi][ni][r] + bv;
        if (!QKV && pe) x += bf2f(pe[((m0 + lr + r) % LL) * DD + n0l + lc]);
        if (!QKV && dogelu) x = 0.5f * x * (1.f + erff(x * 0.70710678118654752f));
        v[ni][r] = x;
      }
    }
    // bf16 out via wave-local slab transpose -> full-line stores
#pragma unroll
    for (int ni = 0; ni < NT; ni++)
#pragma unroll
      for (int r = 0; r < 4; r++)
        slab[(qd * 4 + r) * SW + ni * 16 + l15] = f2bf(v[ni][r]);
    wave_lds_fence();
    if (BN == 128) {                                  // 4 lanes x 32B per row = 128B lines
      int r2 = lane >> 2, c2 = (lane & 3) * 16;
      int grow = m0 + wm * (BM / 2) + mi * 16 + r2;
      u16* op = (u16*)outp + (size_t)grow * ldo + n0l + wn * CW + c2;
      *(short8*)&op[0] = *(const short8*)&slab[r2 * SW + c2];
      *(short8*)&op[8] = *(const short8*)&slab[r2 * SW + c2 + 8];
    } else {                                          // BN=64: 2 lanes x 32B per row
      if (lane < 32) {
        int r2 = lane >> 1, c2 = (lane & 1) * 16;
        int grow = m0 + wm * (BM / 2) + mi * 16 + r2;
        u16* op = (u16*)outp + (size_t)grow * ldo + n0l + wn * CW + c2;
        *(short8*)&op[0] = *(const short8*)&slab[r2 * SW + c2];
        *(short8*)&op[8] = *(const short8*)&slab[r2 * SW + c2 + 8];
      }
    }
    wave_lds_fence();                                 // WAR guard before next mi
  }
}

// ---------------- fused attention: one block per (b,h) ----------------
__global__ __launch_bounds__(256)
void attn(const u16* __restrict__ qg, const u16* __restrict__ kg,
          const u16* __restrict__ vg, u16* __restrict__ og)
{
  constexpr int LP = 128;
  __shared__ alignas(16) u16 Ks[LP * DKK];   // 16 KB
  __shared__ alignas(16) u16 Vt[DKK * LP];   // 16 KB  V transposed [d][j]
  __shared__ alignas(16) u16 Ps[LP * LP];    // 32 KB  probs; reused for O staging

  const int bh = blockIdx.x;
  const int b = bh >> 3, h = bh & 7;
  const size_t base = (size_t)b * LL * DD + (size_t)h * DKK;
  const int tid = threadIdx.x, lane = tid & 63, wv = tid >> 6;
  const int l15 = lane & 15, qd = lane >> 4;
  const short8 z8 = {0, 0, 0, 0, 0, 0, 0, 0};

  for (int i = tid; i < LP * 8; i += 256) {            // K rows, zero-padded
    int row = i >> 3, e8 = (i & 7) * 8;
    short8 val = z8;
    if (row < LL) val = *(const short8*)(kg + base + (size_t)row * DD + e8);
    *(short8*)&Ks[row * DKK + e8] = val;
  }
  for (int i = tid; i < LP * 8; i += 256) {            // V transposed
    int j = i & 127, d0 = (i >> 7) * 8;
    short8 val = z8;
    if (j < LL) val = *(const short8*)(vg + base + (size_t)j * DD + d0);
#pragma unroll
    for (int u = 0; u < 8; u++) Vt[(d0 + u) * LP + j] = (u16)val[u];
  }
  __syncthreads();

  const f32x4 zf = {0.f, 0.f, 0.f, 0.f};
  f32x4 sc[2][8];
#pragma unroll
  for (int it = 0; it < 2; it++)
#pragma unroll
    for (int jt = 0; jt < 8; jt++) sc[it][jt] = zf;

  short8 af[2][2];
#pragma unroll
  for (int it = 0; it < 2; it++) {
    int row = (2 * wv + it) * 16 + l15;
#pragma unroll
    for (int ks = 0; ks < 2; ks++) {
      short8 val = z8;
      if (row < LL) val = *(const short8*)(qg + base + (size_t)row * DD + ks * 32 + qd * 8);
      af[it][ks] = val;
    }
  }
#pragma unroll
  for (int jt = 0; jt < 8; jt++) {
    short8 b0 = *(const short8*)&Ks[(jt * 16 + l15) * DKK + qd * 8];
    short8 b1 = *(const short8*)&Ks[(jt * 16 + l15) * DKK + 32 + qd * 8];
#pragma unroll
    for (int it = 0; it < 2; it++) {
      sc[it][jt] = __builtin_amdgcn_mfma_f32_16x16x32_bf16(af[it][0], b0, sc[it][jt], 0, 0, 0);
      sc[it][jt] = __builtin_amdgcn_mfma_f32_16x16x32_bf16(af[it][1], b1, sc[it][jt], 0, 0, 0);
    }
  }

  constexpr float scale = 0.125f;   // 1/sqrt(64)
#pragma unroll
  for (int it = 0; it < 2; it++) {
    int rb = (2 * wv + it) * 16 + qd * 4;
#pragma unroll
    for (int r = 0; r < 4; r++) {
      float vals[8];
      float mx = -1e30f;
#pragma unroll
      for (int jt = 0; jt < 8; jt++) {
        int col = jt * 16 + l15;
        float vv = sc[it][jt][r] * scale;
        if (col >= LL) vv = -1e30f;
        vals[jt] = vv;
        mx = fmaxf(mx, vv);
      }
#pragma unroll
      for (int off = 1; off < 16; off <<= 1) mx = fmaxf(mx, __shfl_xor(mx, off, 64));
      float s = 0.f;
#pragma unroll
      for (int jt = 0; jt < 8; jt++) { float p = __expf(vals[jt] - mx); vals[jt] = p; s += p; }
#pragma unroll
      for (int off = 1; off < 16; off <<= 1) s += __shfl_xor(s, off, 64);
      float inv = 1.f / s;
      int rowp = rb + r;
#pragma unroll
      for (int jt = 0; jt < 8; jt++) Ps[rowp * LP + jt * 16 + l15] = f2bf(vals[jt] * inv);
    }
  }
  __syncthreads();

  f32x4 oc[2][4];
#pragma unroll
  for (int it = 0; it < 2; it++)
#pragma unroll
    for (int dt = 0; dt < 4; dt++) oc[it][dt] = zf;
#pragma unroll
  for (int ks = 0; ks < 4; ks++) {
    short8 ap[2];
#pragma unroll
    for (int it = 0; it < 2; it++)
      ap[it] = *(const short8*)&Ps[((2 * wv + it) * 16 + l15) * LP + ks * 32 + qd * 8];
#pragma unroll
    for (int dt = 0; dt < 4; dt++) {
      short8 bv = *(const short8*)&Vt[(dt * 16 + l15) * LP + ks * 32 + qd * 8];
#pragma unroll
      for (int it = 0; it < 2; it++)
        oc[it][dt] = __builtin_amdgcn_mfma_f32_16x16x32_bf16(ap[it], bv, oc[it][dt], 0, 0, 0);
    }
  }

  // O staging -> vectorized store (reuse Ps as [128][64] bf16)
  __syncthreads();
  u16* Os = Ps;
#pragma unroll
  for (int it = 0; it < 2; it++) {
    int rb = (2 * wv + it) * 16 + qd * 4;
#pragma unroll
    for (int dt = 0; dt < 4; dt++)
#pragma unroll
      for (int r = 0; r < 4; r++)
        Os[(rb + r) * DKK + dt * 16 + l15] = f2bf(oc[it][dt][r]);
  }
  __syncthreads();
  {
    int row = tid >> 1, c0 = (tid & 1) * 32;
    if (row < LL) {
      u16* op = og + base + (size_t)row * DD + c0;
#pragma unroll
      for (int c = 0; c < 32; c += 8)
        *(short8*)&op[c] = *(const short8*)&Os[row * DKK + c0 + c];
    }
  }
}

// ---------------- launch ----------------
extern "C" void kernel_launch(void* const* d_in, const int* in_sizes, int n_in,
                              void* d_out, int out_size, void* d_ws, size_t ws_size,
                              hipStream_t stream)
{
  (void)in_sizes; (void)n_in; (void)out_size; (void)ws_size;

  char* ws = (char*)d_ws;
  size_t off = 0;
  auto alloc = [&](size_t bytes) { char* p = ws + off; off += (bytes + 255) & ~(size_t)255; return p; };
  int* dflag = (int*)alloc(256);
  static const int seg_sizes[NSEG] = {
    MM * CC, DD * CC * 3, LL * DD,
    3 * DD * DD, 3 * DD, 3 * DD * DD, 3 * DD, 3 * DD * DD, 3 * DD,
    3 * DD * DD, 3 * DD, 3 * 64 * DD, 3 * 64, 3 * DD * 64, 3 * DD,
    CC * DD, CC
  };
  static const int seg_input[NSEG] = {0, 1, 2, 3, 4, 5, 6, 7, 8, 11, 12, 13, 14, 15, 16, 17, 18};
  int total = 0, segoff[NSEG + 1];
  for (int i = 0; i < NSEG; i++) { segoff[i] = total; total += seg_sizes[i]; }
  segoff[NSEG] = total;
  u16* canon = (u16*)alloc((size_t)total * 2);

  u16* hbf = (u16*)alloc((size_t)MM * DD * 2);   // bf16 residual stream
  u16* qb  = (u16*)alloc((size_t)MM * DD * 2);
  u16* kb  = (u16*)alloc((size_t)MM * DD * 2);
  u16* vb  = (u16*)alloc((size_t)MM * DD * 2);
  u16* ob  = (u16*)alloc((size_t)MM * DD * 2);
  u16* yb  = (u16*)alloc((size_t)MM * 64 * 2);
  u16* Wg  = (u16*)alloc((size_t)512 * KEMB * 2);
  u16* Xg  = qb;   // alias: Xg dead before qb first written (stream-serialized)

  const u16* xc  = canon + segoff[0];
  const u16* twc = canon + segoff[1];
  const u16* pec = canon + segoff[2];
  const u16* Wqc = canon + segoff[3];  const u16* bqc = canon + segoff[4];
  const u16* Wkc = canon + segoff[5];  const u16* bkc = canon + segoff[6];
  const u16* Wvc = canon + segoff[7];  const u16* bvc = canon + segoff[8];
  const u16* Woc = canon + segoff[9];  const u16* boc = canon + segoff[10];
  const u16* W1c = canon + segoff[11]; const u16* b1c = canon + segoff[12];
  const u16* W2c = canon + segoff[13]; const u16* b2c = canon + segoff[14];
  const u16* pwc = canon + segoff[15]; const u16* pbc = canon + segoff[16];

  Segs sg;
  for (int i = 0; i < NSEG; i++) { sg.src[i] = d_in[seg_input[i]]; sg.off[i] = segoff[i]; }
  sg.off[NSEG] = total;

  dim3 blk(256);
  detect_dtype<<<dim3(1), blk, 0, stream>>>((const u16*)d_in[0], dflag);
  convert_all<<<dim3((total + 255) / 256), blk, 0, stream>>>(sg, dflag, canon);
  repack_w<<<dim3((512 * KEMB + 255) / 256), blk, 0, stream>>>(twc, Wg);
  repack_x<<<dim3((MM * KEMB + 255) / 256), blk, 0, stream>>>(xc, Xg);

  auto W1of = [&](const u16* p) { GemmW g{}; g.W[0] = g.W[1] = g.W[2] = p; return g; };

  // embedding GEMM: h = Xg @ Wg^T + pe -> hbf   [TAG 0]  (grid: x=N, y=M)
  { GemmW g = W1of(Wg); g.out[0] = hbf;
    gemm_bt<128, 128, 0, false, false><<<dim3(4, MM / 128), blk, 0, stream>>>(Xg, KEMB, g, pec, nullptr, 0, DD, DD, nullptr); }

  for (int l = 0; l < 3; l++) {
    const u16* Wq_l = Wqc + (size_t)l * DD * DD; const u16* bq_l = bqc + l * DD;
    const u16* Wk_l = Wkc + (size_t)l * DD * DD; const u16* bk_l = bkc + l * DD;
    const u16* Wv_l = Wvc + (size_t)l * DD * DD; const u16* bv_l = bvc + l * DD;
    const u16* Wo_l = Woc + (size_t)l * DD * DD; const u16* bo_l = boc + l * DD;
    const u16* W1_l = W1c + (size_t)l * 64 * DD; const u16* b1_l = b1c + l * 64;
    const u16* W2_l = W2c + (size_t)l * DD * 64; const u16* b2_l = b2c + l * DD;

    // fused QKV: grid (12, 200), block-uniform sel by n0>>9   [TAG 1]
    { GemmW g{}; g.W[0] = Wq_l; g.W[1] = Wk_l; g.W[2] = Wv_l;
      g.bias[0] = bq_l; g.bias[1] = bk_l; g.bias[2] = bv_l;
      g.out[0] = qb; g.out[1] = kb; g.out[2] = vb;
      gemm_bt<128, 128, 1, true, false><<<dim3(12, MM / 128), blk, 0, stream>>>(hbf, DD, g, nullptr, nullptr, 0, DD, DD, nullptr); }

    attn<<<dim3(BB * HH), blk, 0, stream>>>(qb, kb, vb, ob);

    // h = h + o @ Wo^T + bo  (bf16 resid, in-place hbf)   [TAG 2]
    { GemmW g = W1of(Wo_l); g.bias[0] = g.bias[1] = g.bias[2] = bo_l; g.out[0] = g.out[1] = g.out[2] = hbf;
      gemm_bt<128, 128, 2, false, false><<<dim3(4, MM / 128), blk, 0, stream>>>(ob, DD, g, nullptr, hbf, 0, DD, DD, nullptr); }
    // y = gelu(h @ W1^T + b1)   [TAG 3]
    { GemmW g = W1of(W1_l); g.bias[0] = b1_l; g.out[0] = yb;
      gemm_bt<64, 64, 3, false, false><<<dim3(1, MM / 64), blk, 0, stream>>>(hbf, DD, g, nullptr, nullptr, 1, 64, 64, nullptr); }
    // h = h + y @ W2^T + b2  (bf16 resid, in-place hbf)   [TAG 4]
    { GemmW g = W1of(W2_l); g.bias[0] = g.bias[1] = g.bias[2] = b2_l; g.out[0] = g.out[1] = g.out[2] = hbf;
      gemm_bt<128, 128, 4, false, false><<<dim3(4, MM / 128), blk, 0, stream>>>(yb, 64, g, nullptr, hbf, 0, DD, DD, nullptr); }
  }
  // out = h @ proj_w^T + proj_b (N=55, direct masked stores; dtype per flag)   [TAG 5]
  { GemmW g = W1of(pwc); g.bias[0] = pbc; g.out[0] = d_out;
    gemm_bt<64, 64, 5, false, true><<<dim3(1, MM / 64), blk, 0, stream>>>(hbf, DD, g, nullptr, nullptr, 0, CC, CC, dflag); }
}

// Round 9
// 732.286 us; speedup vs baseline: 1.6112x; 1.0284x over previous
//
#include <hip/hip_runtime.h>
#include <stdint.h>

typedef unsigned short u16;
typedef __attribute__((ext_vector_type(8))) short short8;
typedef __attribute__((ext_vector_type(4))) float f32x4;

#define DEVI __device__ __forceinline__

// problem constants
#define BB   256
#define LL   100
#define CC   55
#define DD   512
#define HH   8
#define DKK  64
#define MM   (BB * LL)   // 25600 tokens
#define KEMB 192         // 3 * 64 (c padded 55->64)
#define NSEG 17

DEVI float bf2f(u16 s) { union { unsigned int u; float f; } x; x.u = ((unsigned int)s) << 16; return x.f; }
DEVI u16 f2bf(float f) {
  union { float f; unsigned int u; } x; x.f = f;
  unsigned int u = x.u;
  return (u16)((u + 0x7FFFu + ((u >> 16) & 1u)) >> 16);
}

DEVI void async_lds16(const u16* gp, u16* lp) {
  __builtin_amdgcn_global_load_lds((const __attribute__((address_space(1))) void*)gp,
                                   (__attribute__((address_space(3))) void*)lp, 16, 0, 0);
}

DEVI void wave_lds_fence() {   // wave-local LDS RAW/WAR fence (no cross-wave sync)
  asm volatile("s_waitcnt lgkmcnt(0)" ::: "memory");
  __builtin_amdgcn_wave_barrier();
}

// ---------------- dtype detect + canonicalize ----------------
__global__ void detect_dtype(const u16* __restrict__ x, int* __restrict__ flag) {
  __shared__ int cnt[256];
  int tid = threadIdx.x;
  u16 u = x[2 * tid];
  int e = (u >> 7) & 0xFF;
  cnt[tid] = (e >= 0x5F && e <= 0x90) ? 1 : 0;   // |v| in [2^-32, 2^17]
  __syncthreads();
  for (int s = 128; s > 0; s >>= 1) { if (tid < s) cnt[tid] += cnt[tid + s]; __syncthreads(); }
  if (tid == 0) *flag = (cnt[0] >= 160) ? 0 : 1;
}

struct Segs { const void* src[NSEG]; int off[NSEG + 1]; };

__global__ void convert_all(Segs s, const int* __restrict__ flag, u16* __restrict__ dst) {
  int i = blockIdx.x * 256 + threadIdx.x;
  if (i >= s.off[NSEG]) return;
  int sidx = 0;
#pragma unroll
  for (int k = 1; k < NSEG; k++) if (i >= s.off[k]) sidx = k;
  int j = i - s.off[sidx];
  u16 v;
  if (*flag) v = f2bf(((const float*)s.src[sidx])[j]);
  else       v = ((const u16*)s.src[sidx])[j];
  dst[i] = v;
}

// ---------------- repack kernels (embedding conv -> GEMM) ----------------
__global__ void repack_w(const u16* __restrict__ tokw, u16* __restrict__ Wg) {
  int idx = blockIdx.x * 256 + threadIdx.x;   // 512*192
  if (idx >= 512 * KEMB) return;
  int d = idx / KEMB, j = idx % KEMB, k = j >> 6, c = j & 63;
  Wg[idx] = (c < CC) ? tokw[d * (CC * 3) + c * 3 + k] : (u16)0;
}

__global__ void repack_x(const u16* __restrict__ x, u16* __restrict__ Xg) {
  int idx = blockIdx.x * 256 + threadIdx.x;   // 25600*192
  if (idx >= MM * KEMB) return;
  int m = idx / KEMB, j = idx % KEMB, k = j >> 6, c = j & 63;
  int b = m / LL, l = m % LL;
  int l2 = l + k - 1; l2 = (l2 + LL) % LL;    // circular pad
  Xg[idx] = (c < CC) ? x[(size_t)(b * LL + l2) * CC + c] : (u16)0;
}

// ---------------- bf16 MFMA GEMM: out = A[M,K] @ W[N,K]^T (+epilogue) ----------------
// BM=128/BK=32 banking, K-loop unroll-2 (R7). 1-D grid with XCD-AWARE decode:
// xcd = id&7 (round-robin dispatch heuristic), each XCD owns a contiguous
// Mt/8 stripe of M-tiles and iterates all NTT N-tiles within it -> the A
// stripe (3.2 MB) stays resident in that XCD's 4 MB L2; A fetched once/XCD.
// Residual stream bf16 (resid), in-place hbf read/write race-free.
// QKV: NTT=12 spans 3 concatenated weight sets (sel by n0>>9).
struct GemmW { const u16* W[3]; const u16* bias[3]; void* out[3]; };

template<int BM, int BN, int NTT, int TAG, bool QKV, bool DIRECT>
__global__ __launch_bounds__(256)
void gemm_bt(const u16* __restrict__ A, int K, GemmW w,
             const u16* __restrict__ pe,     // if non-null: add pe[(m%100)*512+col]
             const u16* __restrict__ resid,  // if non-null: add resid[m*512+col] (bf16)
             int dogelu,
             int ldo, int nvalid,
             const int* __restrict__ dtf)    // DIRECT only: *dtf==1 -> fp32 store
{
  constexpr int BK = 32;                      // panel width (banking unit)
  constexpr int MI = BM / 32;                 // 16-row tiles per wave
  constexpr int CW = BN / 2, NT = CW / 16;    // cols per wave
  constexpr int SW = CW + 4;                  // epilogue slab stride (u16)
  constexpr int STAGE_U16 = (BM + BN) * BK * 2;   // two panels
  __shared__ alignas(16) u16 smem[STAGE_U16];
  u16* As = smem;                             // [2][BM][32]
  u16* Bs = smem + BM * BK * 2;               // [2][BN][32]

  const int tid = threadIdx.x;
  const int lane = tid & 63;
  const int wv = __builtin_amdgcn_readfirstlane(tid >> 6);
  const int wm = wv & 1, wn = wv >> 1;
  const int l15 = lane & 15, qd = lane >> 4;

  // XCD-aware (m,n) decode: id%8 = XCD (dispatch heuristic), contiguous M-stripe per XCD
  const int id = blockIdx.x;
  const int mpx = gridDim.x / (NTT * 8);      // m-tiles per XCD
  const int xcd = id & 7, slot = id >> 3;
  const int m_t = xcd * mpx + slot / NTT;     // NTT compile-time -> magic-mul
  const int n_t = slot % NTT;
  const int m0 = m_t * BM;
  int n0 = n_t * BN;
  int sel = 0, n0l = n0;
  if (QKV) { sel = n0 >> 9; n0l = n0 & 511; }
  const u16* W = w.W[sel];
  const u16* bias = w.bias[sel];
  void* outp = w.out[sel];

  const f32x4 zf = {0.f, 0.f, 0.f, 0.f};
  f32x4 acc[MI][NT];
#pragma unroll
  for (int i = 0; i < MI; i++)
#pragma unroll
    for (int j = 0; j < NT; j++) acc[i][j] = zf;

  for (int k0 = 0; k0 < K; k0 += 2 * BK) {
    __syncthreads();
#pragma unroll
    for (int p = 0; p < 2; p++) {
      u16* Asp = As + p * BM * BK;
      u16* Bsp = Bs + p * BN * BK;
      const int kp = k0 + p * BK;
#pragma unroll
      for (int i = 0; i < BM / 64; i++) {             // A panel: BMx32, 16B chunks
        int base = i * 256 + wv * 64;
        int idx = base + lane;
        int row = idx >> 2, c8 = (idx & 3) * 8;
        async_lds16(A + (size_t)(m0 + row) * K + kp + c8, Asp + base * 8);
      }
#pragma unroll
      for (int i = 0; i < BN / 64; i++) {             // B panel rows, clamped tail
        int base = i * 256 + wv * 64;
        int idx = base + lane;
        int row = idx >> 2, c8 = (idx & 3) * 8;
        int gr = n0l + row; if (gr >= nvalid) gr = nvalid - 1;
        async_lds16(W + (size_t)gr * K + kp + c8, Bsp + base * 8);
      }
    }
    __syncthreads();

#pragma unroll
    for (int p = 0; p < 2; p++) {
      const u16* Asp = As + p * BM * BK;
      const u16* Bsp = Bs + p * BN * BK;
      short8 af[MI], bfr[NT];
#pragma unroll
      for (int mi = 0; mi < MI; mi++)
        af[mi] = *(const short8*)&Asp[(wm * (BM / 2) + mi * 16 + l15) * BK + qd * 8];
#pragma unroll
      for (int ni = 0; ni < NT; ni++)
        bfr[ni] = *(const short8*)&Bsp[(wn * CW + ni * 16 + l15) * BK + qd * 8];
#pragma unroll
      for (int mi = 0; mi < MI; mi++)
#pragma unroll
        for (int ni = 0; ni < NT; ni++)
          acc[mi][ni] = __builtin_amdgcn_mfma_f32_16x16x32_bf16(af[mi], bfr[ni], acc[mi][ni], 0, 0, 0);
    }
  }

  // C/D layout: col=lane&15, row=(lane>>4)*4+reg [verified m89/m91]
  if (DIRECT) {
    const int sf = (dtf != nullptr) ? *dtf : 0;
#pragma unroll
    for (int mi = 0; mi < MI; mi++)
#pragma unroll
      for (int ni = 0; ni < NT; ni++) {
        int gcol = n0l + wn * CW + ni * 16 + l15;
        float bv = (bias && gcol < nvalid) ? bf2f(bias[gcol]) : 0.f;
#pragma unroll
        for (int r = 0; r < 4; r++) {
          int grow = m0 + wm * (BM / 2) + mi * 16 + qd * 4 + r;
          if (gcol < nvalid) {
            float v = acc[mi][ni][r] + bv;
            if (sf) ((float*)outp)[(size_t)grow * ldo + gcol] = v;
            else    ((u16*)outp)[(size_t)grow * ldo + gcol] = f2bf(v);
          }
        }
      }
    return;
  }

  __syncthreads();                                    // retire staging reads; reuse smem
  u16* slab = smem + wv * 16 * SW;                    // per-wave exclusive, 16 rows
#pragma unroll
  for (int mi = 0; mi < MI; mi++) {
    const int lr = wm * (BM / 2) + mi * 16 + qd * 4;  // local row base (frag layout)
    float v[NT][4];
    // batched bf16 residual loads (quad-coalesced 32B segments)
    if (!QKV && resid) {
#pragma unroll
      for (int ni = 0; ni < NT; ni++) {
        int col = n0l + wn * CW + ni * 16 + l15;
#pragma unroll
        for (int r = 0; r < 4; r++)
          v[ni][r] = bf2f(resid[(size_t)(m0 + lr + r) * DD + col]);
      }
    } else {
#pragma unroll
      for (int ni = 0; ni < NT; ni++)
#pragma unroll
        for (int r = 0; r < 4; r++) v[ni][r] = 0.f;
    }
#pragma unroll
    for (int ni = 0; ni < NT; ni++) {
      const int lc = wn * CW + ni * 16 + l15;
      float bv = bias ? bf2f(bias[n0l + lc]) : 0.f;
#pragma unroll
      for (int r = 0; r < 4; r++) {
        float x = v[ni][r] + acc[mi][ni][r] + bv;
        if (!QKV && pe) x += bf2f(pe[((m0 + lr + r) % LL) * DD + n0l + lc]);
        if (!QKV && dogelu) x = 0.5f * x * (1.f + erff(x * 0.70710678118654752f));
        v[ni][r] = x;
      }
    }
    // bf16 out via wave-local slab transpose -> full-line stores
#pragma unroll
    for (int ni = 0; ni < NT; ni++)
#pragma unroll
      for (int r = 0; r < 4; r++)
        slab[(qd * 4 + r) * SW + ni * 16 + l15] = f2bf(v[ni][r]);
    wave_lds_fence();
    if (BN == 128) {                                  // 4 lanes x 32B per row = 128B lines
      int r2 = lane >> 2, c2 = (lane & 3) * 16;
      int grow = m0 + wm * (BM / 2) + mi * 16 + r2;
      u16* op = (u16*)outp + (size_t)grow * ldo + n0l + wn * CW + c2;
      *(short8*)&op[0] = *(const short8*)&slab[r2 * SW + c2];
      *(short8*)&op[8] = *(const short8*)&slab[r2 * SW + c2 + 8];
    } else {                                          // BN=64: 2 lanes x 32B per row
      if (lane < 32) {
        int r2 = lane >> 1, c2 = (lane & 1) * 16;
        int grow = m0 + wm * (BM / 2) + mi * 16 + r2;
        u16* op = (u16*)outp + (size_t)grow * ldo + n0l + wn * CW + c2;
        *(short8*)&op[0] = *(const short8*)&slab[r2 * SW + c2];
        *(short8*)&op[8] = *(const short8*)&slab[r2 * SW + c2 + 8];
      }
    }
    wave_lds_fence();                                 // WAR guard before next mi
  }
}

// ---------------- fused attention: one block per (b,h) ----------------
__global__ __launch_bounds__(256)
void attn(const u16* __restrict__ qg, const u16* __restrict__ kg,
          const u16* __restrict__ vg, u16* __restrict__ og)
{
  constexpr int LP = 128;
  __shared__ alignas(16) u16 Ks[LP * DKK];   // 16 KB
  __shared__ alignas(16) u16 Vt[DKK * LP];   // 16 KB  V transposed [d][j]
  __shared__ alignas(16) u16 Ps[LP * LP];    // 32 KB  probs; reused for O staging

  const int bh = blockIdx.x;
  const int b = bh >> 3, h = bh & 7;
  const size_t base = (size_t)b * LL * DD + (size_t)h * DKK;
  const int tid = threadIdx.x, lane = tid & 63, wv = tid >> 6;
  const int l15 = lane & 15, qd = lane >> 4;
  const short8 z8 = {0, 0, 0, 0, 0, 0, 0, 0};

  for (int i = tid; i < LP * 8; i += 256) {            // K rows, zero-padded
    int row = i >> 3, e8 = (i & 7) * 8;
    short8 val = z8;
    if (row < LL) val = *(const short8*)(kg + base + (size_t)row * DD + e8);
    *(short8*)&Ks[row * DKK + e8] = val;
  }
  for (int i = tid; i < LP * 8; i += 256) {            // V transposed
    int j = i & 127, d0 = (i >> 7) * 8;
    short8 val = z8;
    if (j < LL) val = *(const short8*)(vg + base + (size_t)j * DD + d0);
#pragma unroll
    for (int u = 0; u < 8; u++) Vt[(d0 + u) * LP + j] = (u16)val[u];
  }
  __syncthreads();

  const f32x4 zf = {0.f, 0.f, 0.f, 0.f};
  f32x4 sc[2][8];
#pragma unroll
  for (int it = 0; it < 2; it++)
#pragma unroll
    for (int jt = 0; jt < 8; jt++) sc[it][jt] = zf;

  short8 af[2][2];
#pragma unroll
  for (int it = 0; it < 2; it++) {
    int row = (2 * wv + it) * 16 + l15;
#pragma unroll
    for (int ks = 0; ks < 2; ks++) {
      short8 val = z8;
      if (row < LL) val = *(const short8*)(qg + base + (size_t)row * DD + ks * 32 + qd * 8);
      af[it][ks] = val;
    }
  }
#pragma unroll
  for (int jt = 0; jt < 8; jt++) {
    short8 b0 = *(const short8*)&Ks[(jt * 16 + l15) * DKK + qd * 8];
    short8 b1 = *(const short8*)&Ks[(jt * 16 + l15) * DKK + 32 + qd * 8];
#pragma unroll
    for (int it = 0; it < 2; it++) {
      sc[it][jt] = __builtin_amdgcn_mfma_f32_16x16x32_bf16(af[it][0], b0, sc[it][jt], 0, 0, 0);
      sc[it][jt] = __builtin_amdgcn_mfma_f32_16x16x32_bf16(af[it][1], b1, sc[it][jt], 0, 0, 0);
    }
  }

  constexpr float scale = 0.125f;   // 1/sqrt(64)
#pragma unroll
  for (int it = 0; it < 2; it++) {
    int rb = (2 * wv + it) * 16 + qd * 4;
#pragma unroll
    for (int r = 0; r < 4; r++) {
      float vals[8];
      float mx = -1e30f;
#pragma unroll
      for (int jt = 0; jt < 8; jt++) {
        int col = jt * 16 + l15;
        float vv = sc[it][jt][r] * scale;
        if (col >= LL) vv = -1e30f;
        vals[jt] = vv;
        mx = fmaxf(mx, vv);
      }
#pragma unroll
      for (int off = 1; off < 16; off <<= 1) mx = fmaxf(mx, __shfl_xor(mx, off, 64));
      float s = 0.f;
#pragma unroll
      for (int jt = 0; jt < 8; jt++) { float p = __expf(vals[jt] - mx); vals[jt] = p; s += p; }
#pragma unroll
      for (int off = 1; off < 16; off <<= 1) s += __shfl_xor(s, off, 64);
      float inv = 1.f / s;
      int rowp = rb + r;
#pragma unroll
      for (int jt = 0; jt < 8; jt++) Ps[rowp * LP + jt * 16 + l15] = f2bf(vals[jt] * inv);
    }
  }
  __syncthreads();

  f32x4 oc[2][4];
#pragma unroll
  for (int it = 0; it < 2; it++)
#pragma unroll
    for (int dt = 0; dt < 4; dt++) oc[it][dt] = zf;
#pragma unroll
  for (int ks = 0; ks < 4; ks++) {
    short8 ap[2];
#pragma unroll
    for (int it = 0; it < 2; it++)
      ap[it] = *(const short8*)&Ps[((2 * wv + it) * 16 + l15) * LP + ks * 32 + qd * 8];
#pragma unroll
    for (int dt = 0; dt < 4; dt++) {
      short8 bv = *(const short8*)&Vt[(dt * 16 + l15) * LP + ks * 32 + qd * 8];
#pragma unroll
      for (int it = 0; it < 2; it++)
        oc[it][dt] = __builtin_amdgcn_mfma_f32_16x16x32_bf16(ap[it], bv, oc[it][dt], 0, 0, 0);
    }
  }

  // O staging -> vectorized store (reuse Ps as [128][64] bf16)
  __syncthreads();
  u16* Os = Ps;
#pragma unroll
  for (int it = 0; it < 2; it++) {
    int rb = (2 * wv + it) * 16 + qd * 4;
#pragma unroll
    for (int dt = 0; dt < 4; dt++)
#pragma unroll
      for (int r = 0; r < 4; r++)
        Os[(rb + r) * DKK + dt * 16 + l15] = f2bf(oc[it][dt][r]);
  }
  __syncthreads();
  {
    int row = tid >> 1, c0 = (tid & 1) * 32;
    if (row < LL) {
      u16* op = og + base + (size_t)row * DD + c0;
#pragma unroll
      for (int c = 0; c < 32; c += 8)
        *(short8*)&op[c] = *(const short8*)&Os[row * DKK + c0 + c];
    }
  }
}

// ---------------- launch ----------------
extern "C" void kernel_launch(void* const* d_in, const int* in_sizes, int n_in,
                              void* d_out, int out_size, void* d_ws, size_t ws_size,
                              hipStream_t stream)
{
  (void)in_sizes; (void)n_in; (void)out_size; (void)ws_size;

  char* ws = (char*)d_ws;
  size_t off = 0;
  auto alloc = [&](size_t bytes) { char* p = ws + off; off += (bytes + 255) & ~(size_t)255; return p; };
  int* dflag = (int*)alloc(256);
  static const int seg_sizes[NSEG] = {
    MM * CC, DD * CC * 3, LL * DD,
    3 * DD * DD, 3 * DD, 3 * DD * DD, 3 * DD, 3 * DD * DD, 3 * DD,
    3 * DD * DD, 3 * DD, 3 * 64 * DD, 3 * 64, 3 * DD * 64, 3 * DD,
    CC * DD, CC
  };
  static const int seg_input[NSEG] = {0, 1, 2, 3, 4, 5, 6, 7, 8, 11, 12, 13, 14, 15, 16, 17, 18};
  int total = 0, segoff[NSEG + 1];
  for (int i = 0; i < NSEG; i++) { segoff[i] = total; total += seg_sizes[i]; }
  segoff[NSEG] = total;
  u16* canon = (u16*)alloc((size_t)total * 2);

  u16* hbf = (u16*)alloc((size_t)MM * DD * 2);   // bf16 residual stream
  u16* qb  = (u16*)alloc((size_t)MM * DD * 2);
  u16* kb  = (u16*)alloc((size_t)MM * DD * 2);
  u16* vb  = (u16*)alloc((size_t)MM * DD * 2);
  u16* ob  = (u16*)alloc((size_t)MM * DD * 2);
  u16* yb  = (u16*)alloc((size_t)MM * 64 * 2);
  u16* Wg  = (u16*)alloc((size_t)512 * KEMB * 2);
  u16* Xg  = qb;   // alias: Xg dead before qb first written (stream-serialized)

  const u16* xc  = canon + segoff[0];
  const u16* twc = canon + segoff[1];
  const u16* pec = canon + segoff[2];
  const u16* Wqc = canon + segoff[3];  const u16* bqc = canon + segoff[4];
  const u16* Wkc = canon + segoff[5];  const u16* bkc = canon + segoff[6];
  const u16* Wvc = canon + segoff[7];  const u16* bvc = canon + segoff[8];
  const u16* Woc = canon + segoff[9];  const u16* boc = canon + segoff[10];
  const u16* W1c = canon + segoff[11]; const u16* b1c = canon + segoff[12];
  const u16* W2c = canon + segoff[13]; const u16* b2c = canon + segoff[14];
  const u16* pwc = canon + segoff[15]; const u16* pbc = canon + segoff[16];

  Segs sg;
  for (int i = 0; i < NSEG; i++) { sg.src[i] = d_in[seg_input[i]]; sg.off[i] = segoff[i]; }
  sg.off[NSEG] = total;

  dim3 blk(256);
  detect_dtype<<<dim3(1), blk, 0, stream>>>((const u16*)d_in[0], dflag);
  convert_all<<<dim3((total + 255) / 256), blk, 0, stream>>>(sg, dflag, canon);
  repack_w<<<dim3((512 * KEMB + 255) / 256), blk, 0, stream>>>(twc, Wg);
  repack_x<<<dim3((MM * KEMB + 255) / 256), blk, 0, stream>>>(xc, Xg);

  auto W1of = [&](const u16* p) { GemmW g{}; g.W[0] = g.W[1] = g.W[2] = p; return g; };

  // embedding GEMM: h = Xg @ Wg^T + pe -> hbf   [TAG 0]  grid 200*4, XCD-decoded
  { GemmW g = W1of(Wg); g.out[0] = hbf;
    gemm_bt<128, 128, 4, 0, false, false><<<dim3(800), blk, 0, stream>>>(Xg, KEMB, g, pec, nullptr, 0, DD, DD, nullptr); }

  for (int l = 0; l < 3; l++) {
    const u16* Wq_l = Wqc + (size_t)l * DD * DD; const u16* bq_l = bqc + l * DD;
    const u16* Wk_l = Wkc + (size_t)l * DD * DD; const u16* bk_l = bkc + l * DD;
    const u16* Wv_l = Wvc + (size_t)l * DD * DD; const u16* bv_l = bvc + l * DD;
    const u16* Wo_l = Woc + (size_t)l * DD * DD; const u16* bo_l = boc + l * DD;
    const u16* W1_l = W1c + (size_t)l * 64 * DD; const u16* b1_l = b1c + l * 64;
    const u16* W2_l = W2c + (size_t)l * DD * 64; const u16* b2_l = b2c + l * DD;

    // fused QKV: grid 200*12, NTT=12, XCD-decoded; sel by n0>>9   [TAG 1]
    { GemmW g{}; g.W[0] = Wq_l; g.W[1] = Wk_l; g.W[2] = Wv_l;
      g.bias[0] = bq_l; g.bias[1] = bk_l; g.bias[2] = bv_l;
      g.out[0] = qb; g.out[1] = kb; g.out[2] = vb;
      gemm_bt<128, 128, 12, 1, true, false><<<dim3(2400), blk, 0, stream>>>(hbf, DD, g, nullptr, nullptr, 0, DD, DD, nullptr); }

    attn<<<dim3(BB * HH), blk, 0, stream>>>(qb, kb, vb, ob);

    // h = h + o @ Wo^T + bo  (bf16 resid, in-place hbf)   [TAG 2]
    { GemmW g = W1of(Wo_l); g.bias[0] = g.bias[1] = g.bias[2] = bo_l; g.out[0] = g.out[1] = g.out[2] = hbf;
      gemm_bt<128, 128, 4, 2, false, false><<<dim3(800), blk, 0, stream>>>(ob, DD, g, nullptr, hbf, 0, DD, DD, nullptr); }
    // y = gelu(h @ W1^T + b1)   [TAG 3]  grid 400*1
    { GemmW g = W1of(W1_l); g.bias[0] = b1_l; g.out[0] = yb;
      gemm_bt<64, 64, 1, 3, false, false><<<dim3(400), blk, 0, stream>>>(hbf, DD, g, nullptr, nullptr, 1, 64, 64, nullptr); }
    // h = h + y @ W2^T + b2  (bf16 resid, in-place hbf)   [TAG 4]
    { GemmW g = W1of(W2_l); g.bias[0] = g.bias[1] = g.bias[2] = b2_l; g.out[0] = g.out[1] = g.out[2] = hbf;
      gemm_bt<128, 128, 4, 4, false, false><<<dim3(800), blk, 0, stream>>>(yb, 64, g, nullptr, hbf, 0, DD, DD, nullptr); }
  }
  // out = h @ proj_w^T + proj_b (N=55, direct masked stores; dtype per flag)   [TAG 5]
  { GemmW g = W1of(pwc); g.bias[0] = pbc; g.out[0] = d_out;
    gemm_bt<64, 64, 1, 5, false, true><<<dim3(400), blk, 0, stream>>>(hbf, DD, g, nullptr, nullptr, 0, CC, CC, dflag); }
}

// Round 10
// 719.237 us; speedup vs baseline: 1.6405x; 1.0181x over previous
//
#include <hip/hip_runtime.h>
#include <stdint.h>

typedef unsigned short u16;
typedef __attribute__((ext_vector_type(8))) short short8;
typedef __attribute__((ext_vector_type(4))) float f32x4;

#define DEVI __device__ __forceinline__

// problem constants
#define BB   256
#define LL   100
#define CC   55
#define DD   512
#define HH   8
#define DKK  64
#define MM   (BB * LL)   // 25600 tokens
#define KEMB 192         // 3 * 64 (c padded 55->64)
#define NSEG 17

DEVI float bf2f(u16 s) { union { unsigned int u; float f; } x; x.u = ((unsigned int)s) << 16; return x.f; }
DEVI u16 f2bf(float f) {
  union { float f; unsigned int u; } x; x.f = f;
  unsigned int u = x.u;
  return (u16)((u + 0x7FFFu + ((u >> 16) & 1u)) >> 16);
}

DEVI void async_lds16(const u16* gp, u16* lp) {
  __builtin_amdgcn_global_load_lds((const __attribute__((address_space(1))) void*)gp,
                                   (__attribute__((address_space(3))) void*)lp, 16, 0, 0);
}

DEVI void wave_lds_fence() {   // wave-local LDS RAW/WAR fence (no cross-wave sync)
  asm volatile("s_waitcnt lgkmcnt(0)" ::: "memory");
  __builtin_amdgcn_wave_barrier();
}

// ---------------- dtype detect + canonicalize ----------------
__global__ void detect_dtype(const u16* __restrict__ x, int* __restrict__ flag) {
  __shared__ int cnt[256];
  int tid = threadIdx.x;
  u16 u = x[2 * tid];
  int e = (u >> 7) & 0xFF;
  cnt[tid] = (e >= 0x5F && e <= 0x90) ? 1 : 0;   // |v| in [2^-32, 2^17]
  __syncthreads();
  for (int s = 128; s > 0; s >>= 1) { if (tid < s) cnt[tid] += cnt[tid + s]; __syncthreads(); }
  if (tid == 0) *flag = (cnt[0] >= 160) ? 0 : 1;
}

struct Segs { const void* src[NSEG]; int off[NSEG + 1]; };

__global__ void convert_all(Segs s, const int* __restrict__ flag, u16* __restrict__ dst) {
  int i = blockIdx.x * 256 + threadIdx.x;
  if (i >= s.off[NSEG]) return;
  int sidx = 0;
#pragma unroll
  for (int k = 1; k < NSEG; k++) if (i >= s.off[k]) sidx = k;
  int j = i - s.off[sidx];
  u16 v;
  if (*flag) v = f2bf(((const float*)s.src[sidx])[j]);
  else       v = ((const u16*)s.src[sidx])[j];
  dst[i] = v;
}

// ---------------- repack kernels (embedding conv -> GEMM) ----------------
__global__ void repack_w(const u16* __restrict__ tokw, u16* __restrict__ Wg) {
  int idx = blockIdx.x * 256 + threadIdx.x;   // 512*192
  if (idx >= 512 * KEMB) return;
  int d = idx / KEMB, j = idx % KEMB, k = j >> 6, c = j & 63;
  Wg[idx] = (c < CC) ? tokw[d * (CC * 3) + c * 3 + k] : (u16)0;
}

__global__ void repack_x(const u16* __restrict__ x, u16* __restrict__ Xg) {
  int idx = blockIdx.x * 256 + threadIdx.x;   // 25600*192
  if (idx >= MM * KEMB) return;
  int m = idx / KEMB, j = idx % KEMB, k = j >> 6, c = j & 63;
  int b = m / LL, l = m % LL;
  int l2 = l + k - 1; l2 = (l2 + LL) % LL;    // circular pad
  Xg[idx] = (c < CC) ? x[(size_t)(b * LL + l2) * CC + c] : (u16)0;
}

// ---------------- bf16 MFMA GEMM: out = A[M,K] @ W[N,K]^T (+epilogue) ----------------
// BM=128/BK=32 banking, XCD-aware 1-D grid decode (R9: A stripe resident per-XCD L2).
// K-loop: single-barrier DOUBLE-BUFFER over K=64 chunks — DMAs for chunk i+1 are
// issued right after the barrier and drained at the NEXT barrier, i.e. after the
// full compute of chunk i (issue->compute->drain, not issue->drain->compute).
// Residual stream bf16 (resid), in-place hbf read/write race-free.
// QKV: NTT=12 spans 3 concatenated weight sets (sel by n0>>9).
struct GemmW { const u16* W[3]; const u16* bias[3]; void* out[3]; };

template<int BM, int BN, int NTT, int TAG, bool QKV, bool DIRECT>
__global__ __launch_bounds__(256)
void gemm_bt(const u16* __restrict__ A, int K, GemmW w,
             const u16* __restrict__ pe,     // if non-null: add pe[(m%100)*512+col]
             const u16* __restrict__ resid,  // if non-null: add resid[m*512+col] (bf16)
             int dogelu,
             int ldo, int nvalid,
             const int* __restrict__ dtf)    // DIRECT only: *dtf==1 -> fp32 store
{
  constexpr int BK = 32;                      // panel width (banking unit)
  constexpr int MI = BM / 32;                 // 16-row tiles per wave
  constexpr int CW = BN / 2, NT = CW / 16;    // cols per wave
  constexpr int SW = CW + 4;                  // epilogue slab stride (u16)
  constexpr int BUF = (BM + BN) * 64;         // one buffer: two BK=32 sub-panels (u16)
  __shared__ alignas(16) u16 smem[BUF * 2];

  const int tid = threadIdx.x;
  const int lane = tid & 63;
  const int wv = __builtin_amdgcn_readfirstlane(tid >> 6);
  const int wm = wv & 1, wn = wv >> 1;
  const int l15 = lane & 15, qd = lane >> 4;

  // XCD-aware (m,n) decode: id%8 = XCD (dispatch heuristic), contiguous M-stripe per XCD
  const int id = blockIdx.x;
  const int mpx = gridDim.x / (NTT * 8);      // m-tiles per XCD
  const int xcd = id & 7, slot = id >> 3;
  const int m_t = xcd * mpx + slot / NTT;     // NTT compile-time -> magic-mul
  const int n_t = slot % NTT;
  const int m0 = m_t * BM;
  int n0 = n_t * BN;
  int sel = 0, n0l = n0;
  if (QKV) { sel = n0 >> 9; n0l = n0 & 511; }
  const u16* W = w.W[sel];
  const u16* bias = w.bias[sel];
  void* outp = w.out[sel];

  // stage one K=64 chunk (two BK=32 sub-panels) into buffer b
  auto stage = [&](int b, int kc) {
    u16* Ab = smem + b * BUF;
    u16* Bb = Ab + BM * 64;
    const int k64 = kc * 64;
#pragma unroll
    for (int p = 0; p < 2; p++) {
      u16* Asp = Ab + p * BM * BK;
      u16* Bsp = Bb + p * BN * BK;
      const int kp = k64 + p * BK;
#pragma unroll
      for (int i = 0; i < BM / 64; i++) {             // A panel: BMx32, 16B chunks
        int base = i * 256 + wv * 64;
        int idx = base + lane;
        int row = idx >> 2, c8 = (idx & 3) * 8;
        async_lds16(A + (size_t)(m0 + row) * K + kp + c8, Asp + base * 8);
      }
#pragma unroll
      for (int i = 0; i < BN / 64; i++) {             // B panel rows, clamped tail
        int base = i * 256 + wv * 64;
        int idx = base + lane;
        int row = idx >> 2, c8 = (idx & 3) * 8;
        int gr = n0l + row; if (gr >= nvalid) gr = nvalid - 1;
        async_lds16(W + (size_t)gr * K + kp + c8, Bsp + base * 8);
      }
    }
  };

  const f32x4 zf = {0.f, 0.f, 0.f, 0.f};
  f32x4 acc[MI][NT];
#pragma unroll
  for (int i = 0; i < MI; i++)
#pragma unroll
    for (int j = 0; j < NT; j++) acc[i][j] = zf;

  const int nit = K >> 6;                     // K=64 chunks (512->8, 192->3, 64->1)
  stage(0, 0);
  int cur = 0;
  for (int it = 0; it < nit; it++) {
    __syncthreads();                          // drains DMA for buf[cur]; protects buf[cur^1]
    if (it + 1 < nit) stage(cur ^ 1, it + 1); // issue next chunk (drained at NEXT barrier)
    const u16* Ab = smem + cur * BUF;
    const u16* Bb = Ab + BM * 64;
#pragma unroll
    for (int p = 0; p < 2; p++) {
      const u16* Asp = Ab + p * BM * BK;
      const u16* Bsp = Bb + p * BN * BK;
      short8 af[MI], bfr[NT];
#pragma unroll
      for (int mi = 0; mi < MI; mi++)
        af[mi] = *(const short8*)&Asp[(wm * (BM / 2) + mi * 16 + l15) * BK + qd * 8];
#pragma unroll
      for (int ni = 0; ni < NT; ni++)
        bfr[ni] = *(const short8*)&Bsp[(wn * CW + ni * 16 + l15) * BK + qd * 8];
#pragma unroll
      for (int mi = 0; mi < MI; mi++)
#pragma unroll
        for (int ni = 0; ni < NT; ni++)
          acc[mi][ni] = __builtin_amdgcn_mfma_f32_16x16x32_bf16(af[mi], bfr[ni], acc[mi][ni], 0, 0, 0);
    }
    cur ^= 1;
  }

  // C/D layout: col=lane&15, row=(lane>>4)*4+reg [verified m89/m91]
  if (DIRECT) {
    const int sf = (dtf != nullptr) ? *dtf : 0;
#pragma unroll
    for (int mi = 0; mi < MI; mi++)
#pragma unroll
      for (int ni = 0; ni < NT; ni++) {
        int gcol = n0l + wn * CW + ni * 16 + l15;
        float bv = (bias && gcol < nvalid) ? bf2f(bias[gcol]) : 0.f;
#pragma unroll
        for (int r = 0; r < 4; r++) {
          int grow = m0 + wm * (BM / 2) + mi * 16 + qd * 4 + r;
          if (gcol < nvalid) {
            float v = acc[mi][ni][r] + bv;
            if (sf) ((float*)outp)[(size_t)grow * ldo + gcol] = v;
            else    ((u16*)outp)[(size_t)grow * ldo + gcol] = f2bf(v);
          }
        }
      }
    return;
  }

  __syncthreads();                                    // retire staging reads; reuse smem
  u16* slab = smem + wv * 16 * SW;                    // per-wave exclusive, 16 rows
#pragma unroll
  for (int mi = 0; mi < MI; mi++) {
    const int lr = wm * (BM / 2) + mi * 16 + qd * 4;  // local row base (frag layout)
    float v[NT][4];
    // batched bf16 residual loads (quad-coalesced 32B segments)
    if (!QKV && resid) {
#pragma unroll
      for (int ni = 0; ni < NT; ni++) {
        int col = n0l + wn * CW + ni * 16 + l15;
#pragma unroll
        for (int r = 0; r < 4; r++)
          v[ni][r] = bf2f(resid[(size_t)(m0 + lr + r) * DD + col]);
      }
    } else {
#pragma unroll
      for (int ni = 0; ni < NT; ni++)
#pragma unroll
        for (int r = 0; r < 4; r++) v[ni][r] = 0.f;
    }
#pragma unroll
    for (int ni = 0; ni < NT; ni++) {
      const int lc = wn * CW + ni * 16 + l15;
      float bv = bias ? bf2f(bias[n0l + lc]) : 0.f;
#pragma unroll
      for (int r = 0; r < 4; r++) {
        float x = v[ni][r] + acc[mi][ni][r] + bv;
        if (!QKV && pe) x += bf2f(pe[((m0 + lr + r) % LL) * DD + n0l + lc]);
        if (!QKV && dogelu) x = 0.5f * x * (1.f + erff(x * 0.70710678118654752f));
        v[ni][r] = x;
      }
    }
    // bf16 out via wave-local slab transpose -> full-line stores
#pragma unroll
    for (int ni = 0; ni < NT; ni++)
#pragma unroll
      for (int r = 0; r < 4; r++)
        slab[(qd * 4 + r) * SW + ni * 16 + l15] = f2bf(v[ni][r]);
    wave_lds_fence();
    if (BN == 128) {                                  // 4 lanes x 32B per row = 128B lines
      int r2 = lane >> 2, c2 = (lane & 3) * 16;
      int grow = m0 + wm * (BM / 2) + mi * 16 + r2;
      u16* op = (u16*)outp + (size_t)grow * ldo + n0l + wn * CW + c2;
      *(short8*)&op[0] = *(const short8*)&slab[r2 * SW + c2];
      *(short8*)&op[8] = *(const short8*)&slab[r2 * SW + c2 + 8];
    } else {                                          // BN=64: 2 lanes x 32B per row
      if (lane < 32) {
        int r2 = lane >> 1, c2 = (lane & 1) * 16;
        int grow = m0 + wm * (BM / 2) + mi * 16 + r2;
        u16* op = (u16*)outp + (size_t)grow * ldo + n0l + wn * CW + c2;
        *(short8*)&op[0] = *(const short8*)&slab[r2 * SW + c2];
        *(short8*)&op[8] = *(const short8*)&slab[r2 * SW + c2 + 8];
      }
    }
    wave_lds_fence();                                 // WAR guard before next mi
  }
}

// ---------------- fused attention: one block per (b,h) ----------------
__global__ __launch_bounds__(256)
void attn(const u16* __restrict__ qg, const u16* __restrict__ kg,
          const u16* __restrict__ vg, u16* __restrict__ og)
{
  constexpr int LP = 128;
  __shared__ alignas(16) u16 Ks[LP * DKK];   // 16 KB
  __shared__ alignas(16) u16 Vt[DKK * LP];   // 16 KB  V transposed [d][j]
  __shared__ alignas(16) u16 Ps[LP * LP];    // 32 KB  probs; reused for O staging

  const int bh = blockIdx.x;
  const int b = bh >> 3, h = bh & 7;
  const size_t base = (size_t)b * LL * DD + (size_t)h * DKK;
  const int tid = threadIdx.x, lane = tid & 63, wv = tid >> 6;
  const int l15 = lane & 15, qd = lane >> 4;
  const short8 z8 = {0, 0, 0, 0, 0, 0, 0, 0};

  for (int i = tid; i < LP * 8; i += 256) {            // K rows, zero-padded
    int row = i >> 3, e8 = (i & 7) * 8;
    short8 val = z8;
    if (row < LL) val = *(const short8*)(kg + base + (size_t)row * DD + e8);
    *(short8*)&Ks[row * DKK + e8] = val;
  }
  for (int i = tid; i < LP * 8; i += 256) {            // V transposed
    int j = i & 127, d0 = (i >> 7) * 8;
    short8 val = z8;
    if (j < LL) val = *(const short8*)(vg + base + (size_t)j * DD + d0);
#pragma unroll
    for (int u = 0; u < 8; u++) Vt[(d0 + u) * LP + j] = (u16)val[u];
  }
  __syncthreads();

  const f32x4 zf = {0.f, 0.f, 0.f, 0.f};
  f32x4 sc[2][8];
#pragma unroll
  for (int it = 0; it < 2; it++)
#pragma unroll
    for (int jt = 0; jt < 8; jt++) sc[it][jt] = zf;

  short8 af[2][2];
#pragma unroll
  for (int it = 0; it < 2; it++) {
    int row = (2 * wv + it) * 16 + l15;
#pragma unroll
    for (int ks = 0; ks < 2; ks++) {
      short8 val = z8;
      if (row < LL) val = *(const short8*)(qg + base + (size_t)row * DD + ks * 32 + qd * 8);
      af[it][ks] = val;
    }
  }
#pragma unroll
  for (int jt = 0; jt < 8; jt++) {
    short8 b0 = *(const short8*)&Ks[(jt * 16 + l15) * DKK + qd * 8];
    short8 b1 = *(const short8*)&Ks[(jt * 16 + l15) * DKK + 32 + qd * 8];
#pragma unroll
    for (int it = 0; it < 2; it++) {
      sc[it][jt] = __builtin_amdgcn_mfma_f32_16x16x32_bf16(af[it][0], b0, sc[it][jt], 0, 0, 0);
      sc[it][jt] = __builtin_amdgcn_mfma_f32_16x16x32_bf16(af[it][1], b1, sc[it][jt], 0, 0, 0);
    }
  }

  constexpr float scale = 0.125f;   // 1/sqrt(64)
#pragma unroll
  for (int it = 0; it < 2; it++) {
    int rb = (2 * wv + it) * 16 + qd * 4;
#pragma unroll
    for (int r = 0; r < 4; r++) {
      float vals[8];
      float mx = -1e30f;
#pragma unroll
      for (int jt = 0; jt < 8; jt++) {
        int col = jt * 16 + l15;
        float vv = sc[it][jt][r] * scale;
        if (col >= LL) vv = -1e30f;
        vals[jt] = vv;
        mx = fmaxf(mx, vv);
      }
#pragma unroll
      for (int off = 1; off < 16; off <<= 1) mx = fmaxf(mx, __shfl_xor(mx, off, 64));
      float s = 0.f;
#pragma unroll
      for (int jt = 0; jt < 8; jt++) { float p = __expf(vals[jt] - mx); vals[jt] = p; s += p; }
#pragma unroll
      for (int off = 1; off < 16; off <<= 1) s += __shfl_xor(s, off, 64);
      float inv = 1.f / s;
      int rowp = rb + r;
#pragma unroll
      for (int jt = 0; jt < 8; jt++) Ps[rowp * LP + jt * 16 + l15] = f2bf(vals[jt] * inv);
    }
  }
  __syncthreads();

  f32x4 oc[2][4];
#pragma unroll
  for (int it = 0; it < 2; it++)
#pragma unroll
    for (int dt = 0; dt < 4; dt++) oc[it][dt] = zf;
#pragma unroll
  for (int ks = 0; ks < 4; ks++) {
    short8 ap[2];
#pragma unroll
    for (int it = 0; it < 2; it++)
      ap[it] = *(const short8*)&Ps[((2 * wv + it) * 16 + l15) * LP + ks * 32 + qd * 8];
#pragma unroll
    for (int dt = 0; dt < 4; dt++) {
      short8 bv = *(const short8*)&Vt[(dt * 16 + l15) * LP + ks * 32 + qd * 8];
#pragma unroll
      for (int it = 0; it < 2; it++)
        oc[it][dt] = __builtin_amdgcn_mfma_f32_16x16x32_bf16(ap[it], bv, oc[it][dt], 0, 0, 0);
    }
  }

  // O staging -> vectorized store (reuse Ps as [128][64] bf16)
  __syncthreads();
  u16* Os = Ps;
#pragma unroll
  for (int it = 0; it < 2; it++) {
    int rb = (2 * wv + it) * 16 + qd * 4;
#pragma unroll
    for (int dt = 0; dt < 4; dt++)
#pragma unroll
      for (int r = 0; r < 4; r++)
        Os[(rb + r) * DKK + dt * 16 + l15] = f2bf(oc[it][dt][r]);
  }
  __syncthreads();
  {
    int row = tid >> 1, c0 = (tid & 1) * 32;
    if (row < LL) {
      u16* op = og + base + (size_t)row * DD + c0;
#pragma unroll
      for (int c = 0; c < 32; c += 8)
        *(short8*)&op[c] = *(const short8*)&Os[row * DKK + c0 + c];
    }
  }
}

// ---------------- launch ----------------
extern "C" void kernel_launch(void* const* d_in, const int* in_sizes, int n_in,
                              void* d_out, int out_size, void* d_ws, size_t ws_size,
                              hipStream_t stream)
{
  (void)in_sizes; (void)n_in; (void)out_size; (void)ws_size;

  char* ws = (char*)d_ws;
  size_t off = 0;
  auto alloc = [&](size_t bytes) { char* p = ws + off; off += (bytes + 255) & ~(size_t)255; return p; };
  int* dflag = (int*)alloc(256);
  static const int seg_sizes[NSEG] = {
    MM * CC, DD * CC * 3, LL * DD,
    3 * DD * DD, 3 * DD, 3 * DD * DD, 3 * DD, 3 * DD * DD, 3 * DD,
    3 * DD * DD, 3 * DD, 3 * 64 * DD, 3 * 64, 3 * DD * 64, 3 * DD,
    CC * DD, CC
  };
  static const int seg_input[NSEG] = {0, 1, 2, 3, 4, 5, 6, 7, 8, 11, 12, 13, 14, 15, 16, 17, 18};
  int total = 0, segoff[NSEG + 1];
  for (int i = 0; i < NSEG; i++) { segoff[i] = total; total += seg_sizes[i]; }
  segoff[NSEG] = total;
  u16* canon = (u16*)alloc((size_t)total * 2);

  u16* hbf = (u16*)alloc((size_t)MM * DD * 2);   // bf16 residual stream
  u16* qb  = (u16*)alloc((size_t)MM * DD * 2);
  u16* kb  = (u16*)alloc((size_t)MM * DD * 2);
  u16* vb  = (u16*)alloc((size_t)MM * DD * 2);
  u16* ob  = (u16*)alloc((size_t)MM * DD * 2);
  u16* yb  = (u16*)alloc((size_t)MM * 64 * 2);
  u16* Wg  = (u16*)alloc((size_t)512 * KEMB * 2);
  u16* Xg  = qb;   // alias: Xg dead before qb first written (stream-serialized)

  const u16* xc  = canon + segoff[0];
  const u16* twc = canon + segoff[1];
  const u16* pec = canon + segoff[2];
  const u16* Wqc = canon + segoff[3];  const u16* bqc = canon + segoff[4];
  const u16* Wkc = canon + segoff[5];  const u16* bkc = canon + segoff[6];
  const u16* Wvc = canon + segoff[7];  const u16* bvc = canon + segoff[8];
  const u16* Woc = canon + segoff[9];  const u16* boc = canon + segoff[10];
  const u16* W1c = canon + segoff[11]; const u16* b1c = canon + segoff[12];
  const u16* W2c = canon + segoff[13]; const u16* b2c = canon + segoff[14];
  const u16* pwc = canon + segoff[15]; const u16* pbc = canon + segoff[16];

  Segs sg;
  for (int i = 0; i < NSEG; i++) { sg.src[i] = d_in[seg_input[i]]; sg.off[i] = segoff[i]; }
  sg.off[NSEG] = total;

  dim3 blk(256);
  detect_dtype<<<dim3(1), blk, 0, stream>>>((const u16*)d_in[0], dflag);
  convert_all<<<dim3((total + 255) / 256), blk, 0, stream>>>(sg, dflag, canon);
  repack_w<<<dim3((512 * KEMB + 255) / 256), blk, 0, stream>>>(twc, Wg);
  repack_x<<<dim3((MM * KEMB + 255) / 256), blk, 0, stream>>>(xc, Xg);

  auto W1of = [&](const u16* p) { GemmW g{}; g.W[0] = g.W[1] = g.W[2] = p; return g; };

  // embedding GEMM: h = Xg @ Wg^T + pe -> hbf   [TAG 0]  grid 200*4, XCD-decoded
  { GemmW g = W1of(Wg); g.out[0] = hbf;
    gemm_bt<128, 128, 4, 0, false, false><<<dim3(800), blk, 0, stream>>>(Xg, KEMB, g, pec, nullptr, 0, DD, DD, nullptr); }

  for (int l = 0; l < 3; l++) {
    const u16* Wq_l = Wqc + (size_t)l * DD * DD; const u16* bq_l = bqc + l * DD;
    const u16* Wk_l = Wkc + (size_t)l * DD * DD; const u16* bk_l = bkc + l * DD;
    const u16* Wv_l = Wvc + (size_t)l * DD * DD; const u16* bv_l = bvc + l * DD;
    const u16* Wo_l = Woc + (size_t)l * DD * DD; const u16* bo_l = boc + l * DD;
    const u16* W1_l = W1c + (size_t)l * 64 * DD; const u16* b1_l = b1c + l * 64;
    const u16* W2_l = W2c + (size_t)l * DD * 64; const u16* b2_l = b2c + l * DD;

    // fused QKV: grid 200*12, NTT=12, XCD-decoded; sel by n0>>9   [TAG 1]
    { GemmW g{}; g.W[0] = Wq_l; g.W[1] = Wk_l; g.W[2] = Wv_l;
      g.bias[0] = bq_l; g.bias[1] = bk_l; g.bias[2] = bv_l;
      g.out[0] = qb; g.out[1] = kb; g.out[2] = vb;
      gemm_bt<128, 128, 12, 1, true, false><<<dim3(2400), blk, 0, stream>>>(hbf, DD, g, nullptr, nullptr, 0, DD, DD, nullptr); }

    attn<<<dim3(BB * HH), blk, 0, stream>>>(qb, kb, vb, ob);

    // h = h + o @ Wo^T + bo  (bf16 resid, in-place hbf)   [TAG 2]
    { GemmW g = W1of(Wo_l); g.bias[0] = g.bias[1] = g.bias[2] = bo_l; g.out[0] = g.out[1] = g.out[2] = hbf;
      gemm_bt<128, 128, 4, 2, false, false><<<dim3(800), blk, 0, stream>>>(ob, DD, g, nullptr, hbf, 0, DD, DD, nullptr); }
    // y = gelu(h @ W1^T + b1)   [TAG 3]  grid 400*1
    { GemmW g = W1of(W1_l); g.bias[0] = b1_l; g.out[0] = yb;
      gemm_bt<64, 64, 1, 3, false, false><<<dim3(400), blk, 0, stream>>>(hbf, DD, g, nullptr, nullptr, 1, 64, 64, nullptr); }
    // h = h + y @ W2^T + b2  (bf16 resid, in-place hbf)   [TAG 4]
    { GemmW g = W1of(W2_l); g.bias[0] = g.bias[1] = g.bias[2] = b2_l; g.out[0] = g.out[1] = g.out[2] = hbf;
      gemm_bt<128, 128, 4, 4, false, false><<<dim3(800), blk, 0, stream>>>(yb, 64, g, nullptr, hbf, 0, DD, DD, nullptr); }
  }
  // out = h @ proj_w^T + proj_b (N=55, direct masked stores; dtype per flag)   [TAG 5]
  { GemmW g = W1of(pwc); g.bias[0] = pbc; g.out[0] = d_out;
    gemm_bt<64, 64, 1, 5, false, true><<<dim3(400), blk, 0, stream>>>(hbf, DD, g, nullptr, nullptr, 0, CC, CC, dflag); }
}

// Round 11
// 672.068 us; speedup vs baseline: 1.7556x; 1.0702x over previous
//
#include <hip/hip_runtime.h>
#include <stdint.h>

typedef unsigned short u16;
typedef __attribute__((ext_vector_type(8))) short short8;
typedef __attribute__((ext_vector_type(4))) float f32x4;

#define DEVI __device__ __forceinline__

// problem constants
#define BB   256
#define LL   100
#define CC   55
#define DD   512
#define HH   8
#define DKK  64
#define MM   (BB * LL)   // 25600 tokens
#define KEMB 192         // 3 * 64 (c padded 55->64)
#define NSEG 17

DEVI float bf2f(u16 s) { union { unsigned int u; float f; } x; x.u = ((unsigned int)s) << 16; return x.f; }
DEVI u16 f2bf(float f) {
  union { float f; unsigned int u; } x; x.f = f;
  unsigned int u = x.u;
  return (u16)((u + 0x7FFFu + ((u >> 16) & 1u)) >> 16);
}

DEVI void async_lds16(const u16* gp, u16* lp) {
  __builtin_amdgcn_global_load_lds((const __attribute__((address_space(1))) void*)gp,
                                   (__attribute__((address_space(3))) void*)lp, 16, 0, 0);
}

DEVI void wave_lds_fence() {   // wave-local LDS RAW/WAR fence (no cross-wave sync)
  asm volatile("s_waitcnt lgkmcnt(0)" ::: "memory");
  __builtin_amdgcn_wave_barrier();
}

// ---------------- dtype detect + canonicalize ----------------
__global__ void detect_dtype(const u16* __restrict__ x, int* __restrict__ flag) {
  __shared__ int cnt[256];
  int tid = threadIdx.x;
  u16 u = x[2 * tid];
  int e = (u >> 7) & 0xFF;
  cnt[tid] = (e >= 0x5F && e <= 0x90) ? 1 : 0;   // |v| in [2^-32, 2^17]
  __syncthreads();
  for (int s = 128; s > 0; s >>= 1) { if (tid < s) cnt[tid] += cnt[tid + s]; __syncthreads(); }
  if (tid == 0) *flag = (cnt[0] >= 160) ? 0 : 1;
}

struct Segs { const void* src[NSEG]; int off[NSEG + 1]; };

__global__ void convert_all(Segs s, const int* __restrict__ flag, u16* __restrict__ dst) {
  int i = blockIdx.x * 256 + threadIdx.x;
  if (i >= s.off[NSEG]) return;
  int sidx = 0;
#pragma unroll
  for (int k = 1; k < NSEG; k++) if (i >= s.off[k]) sidx = k;
  int j = i - s.off[sidx];
  u16 v;
  if (*flag) v = f2bf(((const float*)s.src[sidx])[j]);
  else       v = ((const u16*)s.src[sidx])[j];
  dst[i] = v;
}

// ---------------- repack kernels (embedding conv -> GEMM) ----------------
__global__ void repack_w(const u16* __restrict__ tokw, u16* __restrict__ Wg) {
  int idx = blockIdx.x * 256 + threadIdx.x;   // 512*192
  if (idx >= 512 * KEMB) return;
  int d = idx / KEMB, j = idx % KEMB, k = j >> 6, c = j & 63;
  Wg[idx] = (c < CC) ? tokw[d * (CC * 3) + c * 3 + k] : (u16)0;
}

__global__ void repack_x(const u16* __restrict__ x, u16* __restrict__ Xg) {
  int idx = blockIdx.x * 256 + threadIdx.x;   // 25600*192
  if (idx >= MM * KEMB) return;
  int m = idx / KEMB, j = idx % KEMB, k = j >> 6, c = j & 63;
  int b = m / LL, l = m % LL;
  int l2 = l + k - 1; l2 = (l2 + LL) % LL;    // circular pad
  Xg[idx] = (c < CC) ? x[(size_t)(b * LL + l2) * CC + c] : (u16)0;
}

// ---------------- bf16 MFMA GEMM: out = A[M,K] @ W[N,K]^T (+epilogue) ----------------
// R7 single-buffer K-loop (unroll-2, 2 barriers per K=64) + BN=64 for occupancy:
// acc 32 VGPR, LDS 24 KB -> ~6 blocks/CU co-resident (TLP covers DMA/barrier
// stalls per m114 implicit co-scheduling). XCD-aware 1-D grid decode (R9).
// Residual stream bf16 (resid), in-place hbf read/write race-free.
// QKV: NTT spans 3 concatenated weight sets (sel by n0>>9).
struct GemmW { const u16* W[3]; const u16* bias[3]; void* out[3]; };

template<int BM, int BN, int NTT, int TAG, bool QKV, bool DIRECT>
__global__ __launch_bounds__(256)
void gemm_bt(const u16* __restrict__ A, int K, GemmW w,
             const u16* __restrict__ pe,     // if non-null: add pe[(m%100)*512+col]
             const u16* __restrict__ resid,  // if non-null: add resid[m*512+col] (bf16)
             int dogelu,
             int ldo, int nvalid,
             const int* __restrict__ dtf)    // DIRECT only: *dtf==1 -> fp32 store
{
  constexpr int BK = 32;                      // panel width (banking unit)
  constexpr int MI = BM / 32;                 // 16-row tiles per wave
  constexpr int CW = BN / 2, NT = CW / 16;    // cols per wave
  constexpr int SW = CW + 4;                  // epilogue slab stride (u16)
  constexpr int STAGE_U16 = (BM + BN) * BK * 2;   // two BK=32 panels
  __shared__ alignas(16) u16 smem[STAGE_U16];
  u16* As = smem;                             // [2][BM][32]
  u16* Bs = smem + BM * BK * 2;               // [2][BN][32]

  const int tid = threadIdx.x;
  const int lane = tid & 63;
  const int wv = __builtin_amdgcn_readfirstlane(tid >> 6);
  const int wm = wv & 1, wn = wv >> 1;
  const int l15 = lane & 15, qd = lane >> 4;

  // XCD-aware (m,n) decode: id%8 = XCD (dispatch heuristic), contiguous M-stripe per XCD
  const int id = blockIdx.x;
  const int mpx = gridDim.x / (NTT * 8);      // m-tiles per XCD
  const int xcd = id & 7, slot = id >> 3;
  const int m_t = xcd * mpx + slot / NTT;     // NTT compile-time -> magic-mul
  const int n_t = slot % NTT;
  const int m0 = m_t * BM;
  int n0 = n_t * BN;
  int sel = 0, n0l = n0;
  if (QKV) { sel = n0 >> 9; n0l = n0 & 511; }
  const u16* W = w.W[sel];
  const u16* bias = w.bias[sel];
  void* outp = w.out[sel];

  const f32x4 zf = {0.f, 0.f, 0.f, 0.f};
  f32x4 acc[MI][NT];
#pragma unroll
  for (int i = 0; i < MI; i++)
#pragma unroll
    for (int j = 0; j < NT; j++) acc[i][j] = zf;

  for (int k0 = 0; k0 < K; k0 += 2 * BK) {
    __syncthreads();
#pragma unroll
    for (int p = 0; p < 2; p++) {
      u16* Asp = As + p * BM * BK;
      u16* Bsp = Bs + p * BN * BK;
      const int kp = k0 + p * BK;
#pragma unroll
      for (int i = 0; i < BM / 64; i++) {             // A panel: BMx32, 16B chunks
        int base = i * 256 + wv * 64;
        int idx = base + lane;
        int row = idx >> 2, c8 = (idx & 3) * 8;
        async_lds16(A + (size_t)(m0 + row) * K + kp + c8, Asp + base * 8);
      }
#pragma unroll
      for (int i = 0; i < BN / 64; i++) {             // B panel rows, clamped tail
        int base = i * 256 + wv * 64;
        int idx = base + lane;
        int row = idx >> 2, c8 = (idx & 3) * 8;
        int gr = n0l + row; if (gr >= nvalid) gr = nvalid - 1;
        async_lds16(W + (size_t)gr * K + kp + c8, Bsp + base * 8);
      }
    }
    __syncthreads();

#pragma unroll
    for (int p = 0; p < 2; p++) {
      const u16* Asp = As + p * BM * BK;
      const u16* Bsp = Bs + p * BN * BK;
      short8 af[MI], bfr[NT];
#pragma unroll
      for (int mi = 0; mi < MI; mi++)
        af[mi] = *(const short8*)&Asp[(wm * (BM / 2) + mi * 16 + l15) * BK + qd * 8];
#pragma unroll
      for (int ni = 0; ni < NT; ni++)
        bfr[ni] = *(const short8*)&Bsp[(wn * CW + ni * 16 + l15) * BK + qd * 8];
#pragma unroll
      for (int mi = 0; mi < MI; mi++)
#pragma unroll
        for (int ni = 0; ni < NT; ni++)
          acc[mi][ni] = __builtin_amdgcn_mfma_f32_16x16x32_bf16(af[mi], bfr[ni], acc[mi][ni], 0, 0, 0);
    }
  }

  // C/D layout: col=lane&15, row=(lane>>4)*4+reg [verified m89/m91]
  if (DIRECT) {
    const int sf = (dtf != nullptr) ? *dtf : 0;
#pragma unroll
    for (int mi = 0; mi < MI; mi++)
#pragma unroll
      for (int ni = 0; ni < NT; ni++) {
        int gcol = n0l + wn * CW + ni * 16 + l15;
        float bv = (bias && gcol < nvalid) ? bf2f(bias[gcol]) : 0.f;
#pragma unroll
        for (int r = 0; r < 4; r++) {
          int grow = m0 + wm * (BM / 2) + mi * 16 + qd * 4 + r;
          if (gcol < nvalid) {
            float v = acc[mi][ni][r] + bv;
            if (sf) ((float*)outp)[(size_t)grow * ldo + gcol] = v;
            else    ((u16*)outp)[(size_t)grow * ldo + gcol] = f2bf(v);
          }
        }
      }
    return;
  }

  __syncthreads();                                    // retire staging reads; reuse smem
  u16* slab = smem + wv * 16 * SW;                    // per-wave exclusive, 16 rows
#pragma unroll
  for (int mi = 0; mi < MI; mi++) {
    const int lr = wm * (BM / 2) + mi * 16 + qd * 4;  // local row base (frag layout)
    float v[NT][4];
    // batched bf16 residual loads (quad-coalesced 32B segments)
    if (!QKV && resid) {
#pragma unroll
      for (int ni = 0; ni < NT; ni++) {
        int col = n0l + wn * CW + ni * 16 + l15;
#pragma unroll
        for (int r = 0; r < 4; r++)
          v[ni][r] = bf2f(resid[(size_t)(m0 + lr + r) * DD + col]);
      }
    } else {
#pragma unroll
      for (int ni = 0; ni < NT; ni++)
#pragma unroll
        for (int r = 0; r < 4; r++) v[ni][r] = 0.f;
    }
#pragma unroll
    for (int ni = 0; ni < NT; ni++) {
      const int lc = wn * CW + ni * 16 + l15;
      float bv = bias ? bf2f(bias[n0l + lc]) : 0.f;
#pragma unroll
      for (int r = 0; r < 4; r++) {
        float x = v[ni][r] + acc[mi][ni][r] + bv;
        if (!QKV && pe) x += bf2f(pe[((m0 + lr + r) % LL) * DD + n0l + lc]);
        if (!QKV && dogelu) x = 0.5f * x * (1.f + erff(x * 0.70710678118654752f));
        v[ni][r] = x;
      }
    }
    // bf16 out via wave-local slab transpose -> full-line stores
#pragma unroll
    for (int ni = 0; ni < NT; ni++)
#pragma unroll
      for (int r = 0; r < 4; r++)
        slab[(qd * 4 + r) * SW + ni * 16 + l15] = f2bf(v[ni][r]);
    wave_lds_fence();
    if (BN == 128) {                                  // 4 lanes x 32B per row = 128B lines
      int r2 = lane >> 2, c2 = (lane & 3) * 16;
      int grow = m0 + wm * (BM / 2) + mi * 16 + r2;
      u16* op = (u16*)outp + (size_t)grow * ldo + n0l + wn * CW + c2;
      *(short8*)&op[0] = *(const short8*)&slab[r2 * SW + c2];
      *(short8*)&op[8] = *(const short8*)&slab[r2 * SW + c2 + 8];
    } else {                                          // BN=64: 2 lanes x 32B per row
      if (lane < 32) {
        int r2 = lane >> 1, c2 = (lane & 1) * 16;
        int grow = m0 + wm * (BM / 2) + mi * 16 + r2;
        u16* op = (u16*)outp + (size_t)grow * ldo + n0l + wn * CW + c2;
        *(short8*)&op[0] = *(const short8*)&slab[r2 * SW + c2];
        *(short8*)&op[8] = *(const short8*)&slab[r2 * SW + c2 + 8];
      }
    }
    wave_lds_fence();                                 // WAR guard before next mi
  }
}

// ---------------- fused attention: one block per (b,h) ----------------
__global__ __launch_bounds__(256)
void attn(const u16* __restrict__ qg, const u16* __restrict__ kg,
          const u16* __restrict__ vg, u16* __restrict__ og)
{
  constexpr int LP = 128;
  __shared__ alignas(16) u16 Ks[LP * DKK];   // 16 KB
  __shared__ alignas(16) u16 Vt[DKK * LP];   // 16 KB  V transposed [d][j]
  __shared__ alignas(16) u16 Ps[LP * LP];    // 32 KB  probs; reused for O staging

  const int bh = blockIdx.x;
  const int b = bh >> 3, h = bh & 7;
  const size_t base = (size_t)b * LL * DD + (size_t)h * DKK;
  const int tid = threadIdx.x, lane = tid & 63, wv = tid >> 6;
  const int l15 = lane & 15, qd = lane >> 4;
  const short8 z8 = {0, 0, 0, 0, 0, 0, 0, 0};

  for (int i = tid; i < LP * 8; i += 256) {            // K rows, zero-padded
    int row = i >> 3, e8 = (i & 7) * 8;
    short8 val = z8;
    if (row < LL) val = *(const short8*)(kg + base + (size_t)row * DD + e8);
    *(short8*)&Ks[row * DKK + e8] = val;
  }
  for (int i = tid; i < LP * 8; i += 256) {            // V transposed
    int j = i & 127, d0 = (i >> 7) * 8;
    short8 val = z8;
    if (j < LL) val = *(const short8*)(vg + base + (size_t)j * DD + d0);
#pragma unroll
    for (int u = 0; u < 8; u++) Vt[(d0 + u) * LP + j] = (u16)val[u];
  }
  __syncthreads();

  const f32x4 zf = {0.f, 0.f, 0.f, 0.f};
  f32x4 sc[2][8];
#pragma unroll
  for (int it = 0; it < 2; it++)
#pragma unroll
    for (int jt = 0; jt < 8; jt++) sc[it][jt] = zf;

  short8 af[2][2];
#pragma unroll
  for (int it = 0; it < 2; it++) {
    int row = (2 * wv + it) * 16 + l15;
#pragma unroll
    for (int ks = 0; ks < 2; ks++) {
      short8 val = z8;
      if (row < LL) val = *(const short8*)(qg + base + (size_t)row * DD + ks * 32 + qd * 8);
      af[it][ks] = val;
    }
  }
#pragma unroll
  for (int jt = 0; jt < 8; jt++) {
    short8 b0 = *(const short8*)&Ks[(jt * 16 + l15) * DKK + qd * 8];
    short8 b1 = *(const short8*)&Ks[(jt * 16 + l15) * DKK + 32 + qd * 8];
#pragma unroll
    for (int it = 0; it < 2; it++) {
      sc[it][jt] = __builtin_amdgcn_mfma_f32_16x16x32_bf16(af[it][0], b0, sc[it][jt], 0, 0, 0);
      sc[it][jt] = __builtin_amdgcn_mfma_f32_16x16x32_bf16(af[it][1], b1, sc[it][jt], 0, 0, 0);
    }
  }

  constexpr float scale = 0.125f;   // 1/sqrt(64)
#pragma unroll
  for (int it = 0; it < 2; it++) {
    int rb = (2 * wv + it) * 16 + qd * 4;
#pragma unroll
    for (int r = 0; r < 4; r++) {
      float vals[8];
      float mx = -1e30f;
#pragma unroll
      for (int jt = 0; jt < 8; jt++) {
        int col = jt * 16 + l15;
        float vv = sc[it][jt][r] * scale;
        if (col >= LL) vv = -1e30f;
        vals[jt] = vv;
        mx = fmaxf(mx, vv);
      }
#pragma unroll
      for (int off = 1; off < 16; off <<= 1) mx = fmaxf(mx, __shfl_xor(mx, off, 64));
      float s = 0.f;
#pragma unroll
      for (int jt = 0; jt < 8; jt++) { float p = __expf(vals[jt] - mx); vals[jt] = p; s += p; }
#pragma unroll
      for (int off = 1; off < 16; off <<= 1) s += __shfl_xor(s, off, 64);
      float inv = 1.f / s;
      int rowp = rb + r;
#pragma unroll
      for (int jt = 0; jt < 8; jt++) Ps[rowp * LP + jt * 16 + l15] = f2bf(vals[jt] * inv);
    }
  }
  __syncthreads();

  f32x4 oc[2][4];
#pragma unroll
  for (int it = 0; it < 2; it++)
#pragma unroll
    for (int dt = 0; dt < 4; dt++) oc[it][dt] = zf;
#pragma unroll
  for (int ks = 0; ks < 4; ks++) {
    short8 ap[2];
#pragma unroll
    for (int it = 0; it < 2; it++)
      ap[it] = *(const short8*)&Ps[((2 * wv + it) * 16 + l15) * LP + ks * 32 + qd * 8];
#pragma unroll
    for (int dt = 0; dt < 4; dt++) {
      short8 bv = *(const short8*)&Vt[(dt * 16 + l15) * LP + ks * 32 + qd * 8];
#pragma unroll
      for (int it = 0; it < 2; it++)
        oc[it][dt] = __builtin_amdgcn_mfma_f32_16x16x32_bf16(ap[it], bv, oc[it][dt], 0, 0, 0);
    }
  }

  // O staging -> vectorized store (reuse Ps as [128][64] bf16)
  __syncthreads();
  u16* Os = Ps;
#pragma unroll
  for (int it = 0; it < 2; it++) {
    int rb = (2 * wv + it) * 16 + qd * 4;
#pragma unroll
    for (int dt = 0; dt < 4; dt++)
#pragma unroll
      for (int r = 0; r < 4; r++)
        Os[(rb + r) * DKK + dt * 16 + l15] = f2bf(oc[it][dt][r]);
  }
  __syncthreads();
  {
    int row = tid >> 1, c0 = (tid & 1) * 32;
    if (row < LL) {
      u16* op = og + base + (size_t)row * DD + c0;
#pragma unroll
      for (int c = 0; c < 32; c += 8)
        *(short8*)&op[c] = *(const short8*)&Os[row * DKK + c0 + c];
    }
  }
}

// ---------------- launch ----------------
extern "C" void kernel_launch(void* const* d_in, const int* in_sizes, int n_in,
                              void* d_out, int out_size, void* d_ws, size_t ws_size,
                              hipStream_t stream)
{
  (void)in_sizes; (void)n_in; (void)out_size; (void)ws_size;

  char* ws = (char*)d_ws;
  size_t off = 0;
  auto alloc = [&](size_t bytes) { char* p = ws + off; off += (bytes + 255) & ~(size_t)255; return p; };
  int* dflag = (int*)alloc(256);
  static const int seg_sizes[NSEG] = {
    MM * CC, DD * CC * 3, LL * DD,
    3 * DD * DD, 3 * DD, 3 * DD * DD, 3 * DD, 3 * DD * DD, 3 * DD,
    3 * DD * DD, 3 * DD, 3 * 64 * DD, 3 * 64, 3 * DD * 64, 3 * DD,
    CC * DD, CC
  };
  static const int seg_input[NSEG] = {0, 1, 2, 3, 4, 5, 6, 7, 8, 11, 12, 13, 14, 15, 16, 17, 18};
  int total = 0, segoff[NSEG + 1];
  for (int i = 0; i < NSEG; i++) { segoff[i] = total; total += seg_sizes[i]; }
  segoff[NSEG] = total;
  u16* canon = (u16*)alloc((size_t)total * 2);

  u16* hbf = (u16*)alloc((size_t)MM * DD * 2);   // bf16 residual stream
  u16* qb  = (u16*)alloc((size_t)MM * DD * 2);
  u16* kb  = (u16*)alloc((size_t)MM * DD * 2);
  u16* vb  = (u16*)alloc((size_t)MM * DD * 2);
  u16* ob  = (u16*)alloc((size_t)MM * DD * 2);
  u16* yb  = (u16*)alloc((size_t)MM * 64 * 2);
  u16* Wg  = (u16*)alloc((size_t)512 * KEMB * 2);
  u16* Xg  = qb;   // alias: Xg dead before qb first written (stream-serialized)

  const u16* xc  = canon + segoff[0];
  const u16* twc = canon + segoff[1];
  const u16* pec = canon + segoff[2];
  const u16* Wqc = canon + segoff[3];  const u16* bqc = canon + segoff[4];
  const u16* Wkc = canon + segoff[5];  const u16* bkc = canon + segoff[6];
  const u16* Wvc = canon + segoff[7];  const u16* bvc = canon + segoff[8];
  const u16* Woc = canon + segoff[9];  const u16* boc = canon + segoff[10];
  const u16* W1c = canon + segoff[11]; const u16* b1c = canon + segoff[12];
  const u16* W2c = canon + segoff[13]; const u16* b2c = canon + segoff[14];
  const u16* pwc = canon + segoff[15]; const u16* pbc = canon + segoff[16];

  Segs sg;
  for (int i = 0; i < NSEG; i++) { sg.src[i] = d_in[seg_input[i]]; sg.off[i] = segoff[i]; }
  sg.off[NSEG] = total;

  dim3 blk(256);
  detect_dtype<<<dim3(1), blk, 0, stream>>>((const u16*)d_in[0], dflag);
  convert_all<<<dim3((total + 255) / 256), blk, 0, stream>>>(sg, dflag, canon);
  repack_w<<<dim3((512 * KEMB + 255) / 256), blk, 0, stream>>>(twc, Wg);
  repack_x<<<dim3((MM * KEMB + 255) / 256), blk, 0, stream>>>(xc, Xg);

  auto W1of = [&](const u16* p) { GemmW g{}; g.W[0] = g.W[1] = g.W[2] = p; return g; };

  // embedding GEMM: h = Xg @ Wg^T + pe -> hbf   [TAG 0]  grid 200*8, XCD-decoded
  { GemmW g = W1of(Wg); g.out[0] = hbf;
    gemm_bt<128, 64, 8, 0, false, false><<<dim3(1600), blk, 0, stream>>>(Xg, KEMB, g, pec, nullptr, 0, DD, DD, nullptr); }

  for (int l = 0; l < 3; l++) {
    const u16* Wq_l = Wqc + (size_t)l * DD * DD; const u16* bq_l = bqc + l * DD;
    const u16* Wk_l = Wkc + (size_t)l * DD * DD; const u16* bk_l = bkc + l * DD;
    const u16* Wv_l = Wvc + (size_t)l * DD * DD; const u16* bv_l = bvc + l * DD;
    const u16* Wo_l = Woc + (size_t)l * DD * DD; const u16* bo_l = boc + l * DD;
    const u16* W1_l = W1c + (size_t)l * 64 * DD; const u16* b1_l = b1c + l * 64;
    const u16* W2_l = W2c + (size_t)l * DD * 64; const u16* b2_l = b2c + l * DD;

    // fused QKV: grid 200*24, NTT=24, XCD-decoded; sel by n0>>9   [TAG 1]
    { GemmW g{}; g.W[0] = Wq_l; g.W[1] = Wk_l; g.W[2] = Wv_l;
      g.bias[0] = bq_l; g.bias[1] = bk_l; g.bias[2] = bv_l;
      g.out[0] = qb; g.out[1] = kb; g.out[2] = vb;
      gemm_bt<128, 64, 24, 1, true, false><<<dim3(4800), blk, 0, stream>>>(hbf, DD, g, nullptr, nullptr, 0, DD, DD, nullptr); }

    attn<<<dim3(BB * HH), blk, 0, stream>>>(qb, kb, vb, ob);

    // h = h + o @ Wo^T + bo  (bf16 resid, in-place hbf)   [TAG 2]
    { GemmW g = W1of(Wo_l); g.bias[0] = g.bias[1] = g.bias[2] = bo_l; g.out[0] = g.out[1] = g.out[2] = hbf;
      gemm_bt<128, 64, 8, 2, false, false><<<dim3(1600), blk, 0, stream>>>(ob, DD, g, nullptr, hbf, 0, DD, DD, nullptr); }
    // y = gelu(h @ W1^T + b1)   [TAG 3]  grid 400*1
    { GemmW g = W1of(W1_l); g.bias[0] = b1_l; g.out[0] = yb;
      gemm_bt<64, 64, 1, 3, false, false><<<dim3(400), blk, 0, stream>>>(hbf, DD, g, nullptr, nullptr, 1, 64, 64, nullptr); }
    // h = h + y @ W2^T + b2  (bf16 resid, in-place hbf)   [TAG 4]
    { GemmW g = W1of(W2_l); g.bias[0] = g.bias[1] = g.bias[2] = b2_l; g.out[0] = g.out[1] = g.out[2] = hbf;
      gemm_bt<128, 64, 8, 4, false, false><<<dim3(1600), blk, 0, stream>>>(yb, 64, g, nullptr, hbf, 0, DD, DD, nullptr); }
  }
  // out = h @ proj_w^T + proj_b (N=55, direct masked stores; dtype per flag)   [TAG 5]
  { GemmW g = W1of(pwc); g.bias[0] = pbc; g.out[0] = d_out;
    gemm_bt<64, 64, 1, 5, false, true><<<dim3(400), blk, 0, stream>>>(hbf, DD, g, nullptr, nullptr, 0, CC, CC, dflag); }
}

// Round 12
// 653.541 us; speedup vs baseline: 1.8054x; 1.0283x over previous
//
#include <hip/hip_runtime.h>
#include <stdint.h>

typedef unsigned short u16;
typedef __attribute__((ext_vector_type(8))) short short8;
typedef __attribute__((ext_vector_type(4))) float f32x4;

#define DEVI __device__ __forceinline__

// problem constants
#define BB   256
#define LL   100
#define CC   55
#define DD   512
#define HH   8
#define DKK  64
#define MM   (BB * LL)   // 25600 tokens
#define KEMB 192         // 3 * 64 (c padded 55->64)
#define NSEG 17

DEVI float bf2f(u16 s) { union { unsigned int u; float f; } x; x.u = ((unsigned int)s) << 16; return x.f; }
DEVI u16 f2bf(float f) {
  union { float f; unsigned int u; } x; x.f = f;
  unsigned int u = x.u;
  return (u16)((u + 0x7FFFu + ((u >> 16) & 1u)) >> 16);
}

DEVI void async_lds16(const u16* gp, u16* lp) {
  __builtin_amdgcn_global_load_lds((const __attribute__((address_space(1))) void*)gp,
                                   (__attribute__((address_space(3))) void*)lp, 16, 0, 0);
}

DEVI void wave_lds_fence() {   // wave-local LDS RAW/WAR fence (no cross-wave sync)
  asm volatile("s_waitcnt lgkmcnt(0)" ::: "memory");
  __builtin_amdgcn_wave_barrier();
}

// ---------------- dtype detect + canonicalize ----------------
__global__ void detect_dtype(const u16* __restrict__ x, int* __restrict__ flag) {
  __shared__ int cnt[256];
  int tid = threadIdx.x;
  u16 u = x[2 * tid];
  int e = (u >> 7) & 0xFF;
  cnt[tid] = (e >= 0x5F && e <= 0x90) ? 1 : 0;   // |v| in [2^-32, 2^17]
  __syncthreads();
  for (int s = 128; s > 0; s >>= 1) { if (tid < s) cnt[tid] += cnt[tid + s]; __syncthreads(); }
  if (tid == 0) *flag = (cnt[0] >= 160) ? 0 : 1;
}

struct Segs { const void* src[NSEG]; int off[NSEG + 1]; };

__global__ void convert_all(Segs s, const int* __restrict__ flag, u16* __restrict__ dst) {
  int i = blockIdx.x * 256 + threadIdx.x;
  if (i >= s.off[NSEG]) return;
  int sidx = 0;
#pragma unroll
  for (int k = 1; k < NSEG; k++) if (i >= s.off[k]) sidx = k;
  int j = i - s.off[sidx];
  u16 v;
  if (*flag) v = f2bf(((const float*)s.src[sidx])[j]);
  else       v = ((const u16*)s.src[sidx])[j];
  dst[i] = v;
}

// ---------------- repack kernels (embedding conv -> GEMM) ----------------
__global__ void repack_w(const u16* __restrict__ tokw, u16* __restrict__ Wg) {
  int idx = blockIdx.x * 256 + threadIdx.x;   // 512*192
  if (idx >= 512 * KEMB) return;
  int d = idx / KEMB, j = idx % KEMB, k = j >> 6, c = j & 63;
  Wg[idx] = (c < CC) ? tokw[d * (CC * 3) + c * 3 + k] : (u16)0;
}

__global__ void repack_x(const u16* __restrict__ x, u16* __restrict__ Xg) {
  int idx = blockIdx.x * 256 + threadIdx.x;   // 25600*192
  if (idx >= MM * KEMB) return;
  int m = idx / KEMB, j = idx % KEMB, k = j >> 6, c = j & 63;
  int b = m / LL, l = m % LL;
  int l2 = l + k - 1; l2 = (l2 + LL) % LL;    // circular pad
  Xg[idx] = (c < CC) ? x[(size_t)(b * LL + l2) * CC + c] : (u16)0;
}

// ---------------- bf16 MFMA GEMM: out = A[M,K] @ W[N,K]^T (+epilogue) ----------------
// R11 config: BN=64, single-buffer unroll-2 K-loop, XCD-aware 1-D grid decode.
struct GemmW { const u16* W[3]; const u16* bias[3]; void* out[3]; };

template<int BM, int BN, int NTT, int TAG, bool QKV, bool DIRECT>
__global__ __launch_bounds__(256)
void gemm_bt(const u16* __restrict__ A, int K, GemmW w,
             const u16* __restrict__ pe,     // if non-null: add pe[(m%100)*512+col]
             const u16* __restrict__ resid,  // if non-null: add resid[m*512+col] (bf16)
             int dogelu,
             int ldo, int nvalid,
             const int* __restrict__ dtf)    // DIRECT only: *dtf==1 -> fp32 store
{
  constexpr int BK = 32;
  constexpr int MI = BM / 32;
  constexpr int CW = BN / 2, NT = CW / 16;
  constexpr int SW = CW + 4;
  constexpr int STAGE_U16 = (BM + BN) * BK * 2;
  __shared__ alignas(16) u16 smem[STAGE_U16];
  u16* As = smem;
  u16* Bs = smem + BM * BK * 2;

  const int tid = threadIdx.x;
  const int lane = tid & 63;
  const int wv = __builtin_amdgcn_readfirstlane(tid >> 6);
  const int wm = wv & 1, wn = wv >> 1;
  const int l15 = lane & 15, qd = lane >> 4;

  const int id = blockIdx.x;
  const int mpx = gridDim.x / (NTT * 8);
  const int xcd = id & 7, slot = id >> 3;
  const int m_t = xcd * mpx + slot / NTT;
  const int n_t = slot % NTT;
  const int m0 = m_t * BM;
  int n0 = n_t * BN;
  int sel = 0, n0l = n0;
  if (QKV) { sel = n0 >> 9; n0l = n0 & 511; }
  const u16* W = w.W[sel];
  const u16* bias = w.bias[sel];
  void* outp = w.out[sel];

  const f32x4 zf = {0.f, 0.f, 0.f, 0.f};
  f32x4 acc[MI][NT];
#pragma unroll
  for (int i = 0; i < MI; i++)
#pragma unroll
    for (int j = 0; j < NT; j++) acc[i][j] = zf;

  for (int k0 = 0; k0 < K; k0 += 2 * BK) {
    __syncthreads();
#pragma unroll
    for (int p = 0; p < 2; p++) {
      u16* Asp = As + p * BM * BK;
      u16* Bsp = Bs + p * BN * BK;
      const int kp = k0 + p * BK;
#pragma unroll
      for (int i = 0; i < BM / 64; i++) {
        int base = i * 256 + wv * 64;
        int idx = base + lane;
        int row = idx >> 2, c8 = (idx & 3) * 8;
        async_lds16(A + (size_t)(m0 + row) * K + kp + c8, Asp + base * 8);
      }
#pragma unroll
      for (int i = 0; i < BN / 64; i++) {
        int base = i * 256 + wv * 64;
        int idx = base + lane;
        int row = idx >> 2, c8 = (idx & 3) * 8;
        int gr = n0l + row; if (gr >= nvalid) gr = nvalid - 1;
        async_lds16(W + (size_t)gr * K + kp + c8, Bsp + base * 8);
      }
    }
    __syncthreads();

#pragma unroll
    for (int p = 0; p < 2; p++) {
      const u16* Asp = As + p * BM * BK;
      const u16* Bsp = Bs + p * BN * BK;
      short8 af[MI], bfr[NT];
#pragma unroll
      for (int mi = 0; mi < MI; mi++)
        af[mi] = *(const short8*)&Asp[(wm * (BM / 2) + mi * 16 + l15) * BK + qd * 8];
#pragma unroll
      for (int ni = 0; ni < NT; ni++)
        bfr[ni] = *(const short8*)&Bsp[(wn * CW + ni * 16 + l15) * BK + qd * 8];
#pragma unroll
      for (int mi = 0; mi < MI; mi++)
#pragma unroll
        for (int ni = 0; ni < NT; ni++)
          acc[mi][ni] = __builtin_amdgcn_mfma_f32_16x16x32_bf16(af[mi], bfr[ni], acc[mi][ni], 0, 0, 0);
    }
  }

  // C/D layout: col=lane&15, row=(lane>>4)*4+reg [verified m89/m91]
  if (DIRECT) {
    const int sf = (dtf != nullptr) ? *dtf : 0;
#pragma unroll
    for (int mi = 0; mi < MI; mi++)
#pragma unroll
      for (int ni = 0; ni < NT; ni++) {
        int gcol = n0l + wn * CW + ni * 16 + l15;
        float bv = (bias && gcol < nvalid) ? bf2f(bias[gcol]) : 0.f;
#pragma unroll
        for (int r = 0; r < 4; r++) {
          int grow = m0 + wm * (BM / 2) + mi * 16 + qd * 4 + r;
          if (gcol < nvalid) {
            float v = acc[mi][ni][r] + bv;
            if (sf) ((float*)outp)[(size_t)grow * ldo + gcol] = v;
            else    ((u16*)outp)[(size_t)grow * ldo + gcol] = f2bf(v);
          }
        }
      }
    return;
  }

  __syncthreads();
  u16* slab = smem + wv * 16 * SW;
#pragma unroll
  for (int mi = 0; mi < MI; mi++) {
    const int lr = wm * (BM / 2) + mi * 16 + qd * 4;
    float v[NT][4];
    if (!QKV && resid) {
#pragma unroll
      for (int ni = 0; ni < NT; ni++) {
        int col = n0l + wn * CW + ni * 16 + l15;
#pragma unroll
        for (int r = 0; r < 4; r++)
          v[ni][r] = bf2f(resid[(size_t)(m0 + lr + r) * DD + col]);
      }
    } else {
#pragma unroll
      for (int ni = 0; ni < NT; ni++)
#pragma unroll
        for (int r = 0; r < 4; r++) v[ni][r] = 0.f;
    }
#pragma unroll
    for (int ni = 0; ni < NT; ni++) {
      const int lc = wn * CW + ni * 16 + l15;
      float bv = bias ? bf2f(bias[n0l + lc]) : 0.f;
#pragma unroll
      for (int r = 0; r < 4; r++) {
        float x = v[ni][r] + acc[mi][ni][r] + bv;
        if (!QKV && pe) x += bf2f(pe[((m0 + lr + r) % LL) * DD + n0l + lc]);
        if (!QKV && dogelu) x = 0.5f * x * (1.f + erff(x * 0.70710678118654752f));
        v[ni][r] = x;
      }
    }
#pragma unroll
    for (int ni = 0; ni < NT; ni++)
#pragma unroll
      for (int r = 0; r < 4; r++)
        slab[(qd * 4 + r) * SW + ni * 16 + l15] = f2bf(v[ni][r]);
    wave_lds_fence();
    if (BN == 128) {
      int r2 = lane >> 2, c2 = (lane & 3) * 16;
      int grow = m0 + wm * (BM / 2) + mi * 16 + r2;
      u16* op = (u16*)outp + (size_t)grow * ldo + n0l + wn * CW + c2;
      *(short8*)&op[0] = *(const short8*)&slab[r2 * SW + c2];
      *(short8*)&op[8] = *(const short8*)&slab[r2 * SW + c2 + 8];
    } else {
      if (lane < 32) {
        int r2 = lane >> 1, c2 = (lane & 1) * 16;
        int grow = m0 + wm * (BM / 2) + mi * 16 + r2;
        u16* op = (u16*)outp + (size_t)grow * ldo + n0l + wn * CW + c2;
        *(short8*)&op[0] = *(const short8*)&slab[r2 * SW + c2];
        *(short8*)&op[8] = *(const short8*)&slab[r2 * SW + c2 + 8];
      }
    }
    wave_lds_fence();
  }
}

// ---------------- fused FFN: h = h + gelu(h@W1^T + b1) @ W2^T + b2 ----------------
// One block per 64-row M-tile (grid 400, XCD-decoded). Phase 1: y[64x64] via
// K=512 loop (W1 as B); y parked in LDS in A-panel format (stride-32, conflict
// free). Phase 2: 8 chunks of 64 output cols; W2 chunk staged via dbuf DMA;
// resid read + slab store per chunk. In-place hbf is race-free: block owns all
// 512 cols of its rows.
__global__ __launch_bounds__(256)
void ffn_fused(const u16* __restrict__ h, const u16* __restrict__ W1,
               const u16* __restrict__ b1, const u16* __restrict__ W2,
               const u16* __restrict__ b2, u16* __restrict__ hout)
{
  constexpr int BM = 64, BK = 32, SW = 36;   // slab stride
  __shared__ alignas(16) u16 smem[4096 + 10496];
  u16* y      = smem;                        // [2][64][32] panels (A-format)
  u16* shared = smem + 4096;
  u16* As  = shared;                         // phase1 A panels [2][64][32]
  u16* Bs  = shared + 4096;                  // phase1 W1 panels [2][64][32]
  u16* Bs2 = shared;                         // phase2 W2 dbuf [2][2][64][32]
  u16* slabs = shared + 8192;                // 4 waves x 16 x 36

  const int tid = threadIdx.x;
  const int lane = tid & 63;
  const int wv = __builtin_amdgcn_readfirstlane(tid >> 6);
  const int wm = wv & 1, wn = wv >> 1;
  const int l15 = lane & 15, qd = lane >> 4;
  const int id = blockIdx.x;
  const int mpx = gridDim.x >> 3;            // m-tiles per XCD
  const int m0 = ((id & 7) * mpx + (id >> 3)) * BM;

  const int srow = tid >> 2, sc8 = (tid & 3) * 8;   // staging decode (1 chunk/thread)
  const f32x4 zf = {0.f, 0.f, 0.f, 0.f};

  // ---- phase 1: y = gelu(h @ W1^T + b1) ----
  f32x4 acc[2][2];
#pragma unroll
  for (int i = 0; i < 2; i++)
#pragma unroll
    for (int j = 0; j < 2; j++) acc[i][j] = zf;

  for (int k0 = 0; k0 < DD; k0 += 64) {
    __syncthreads();
#pragma unroll
    for (int p = 0; p < 2; p++) {
      const int kp = k0 + p * BK;
      async_lds16(h  + (size_t)(m0 + srow) * DD + kp + sc8, As + p * 2048 + tid * 8);
      async_lds16(W1 + (size_t)srow * DD + kp + sc8,        Bs + p * 2048 + tid * 8);
    }
    __syncthreads();
#pragma unroll
    for (int p = 0; p < 2; p++) {
      short8 af[2], bfr[2];
#pragma unroll
      for (int mi = 0; mi < 2; mi++)
        af[mi] = *(const short8*)&As[p * 2048 + (wm * 32 + mi * 16 + l15) * BK + qd * 8];
#pragma unroll
      for (int ni = 0; ni < 2; ni++)
        bfr[ni] = *(const short8*)&Bs[p * 2048 + (wn * 32 + ni * 16 + l15) * BK + qd * 8];
#pragma unroll
      for (int mi = 0; mi < 2; mi++)
#pragma unroll
        for (int ni = 0; ni < 2; ni++)
          acc[mi][ni] = __builtin_amdgcn_mfma_f32_16x16x32_bf16(af[mi], bfr[ni], acc[mi][ni], 0, 0, 0);
    }
  }
  // y panels: col = wn*32 + ni*16 + l15 -> panel wn, in-panel col ni*16+l15
#pragma unroll
  for (int mi = 0; mi < 2; mi++)
#pragma unroll
    for (int ni = 0; ni < 2; ni++) {
      float bv = bf2f(b1[wn * 32 + ni * 16 + l15]);
#pragma unroll
      for (int r = 0; r < 4; r++) {
        int row = wm * 32 + mi * 16 + qd * 4 + r;
        float x = acc[mi][ni][r] + bv;
        x = 0.5f * x * (1.f + erff(x * 0.70710678118654752f));
        y[wn * 2048 + row * BK + ni * 16 + l15] = f2bf(x);
      }
    }
  __syncthreads();   // y visible to all; phase-1 staging region free for Bs2

  // ---- phase 2: hout = h + y @ W2^T + b2, 8 chunks of 64 cols ----
  auto stage2 = [&](int buf, int nc) {
#pragma unroll
    for (int p = 0; p < 2; p++)
      async_lds16(W2 + (size_t)(nc * 64 + srow) * 64 + p * BK + sc8,
                  Bs2 + buf * 4096 + p * 2048 + tid * 8);
  };
  stage2(0, 0);
  int cur = 0;
  u16* slab = slabs + wv * 16 * SW;
  for (int nc = 0; nc < 8; nc++) {
    __syncthreads();                         // drain DMA for cur; protect cur^1
    if (nc + 1 < 8) stage2(cur ^ 1, nc + 1);
    f32x4 a2[2][2];
#pragma unroll
    for (int i = 0; i < 2; i++)
#pragma unroll
      for (int j = 0; j < 2; j++) a2[i][j] = zf;
#pragma unroll
    for (int p = 0; p < 2; p++) {
      short8 af[2], bfr[2];
#pragma unroll
      for (int mi = 0; mi < 2; mi++)
        af[mi] = *(const short8*)&y[p * 2048 + (wm * 32 + mi * 16 + l15) * BK + qd * 8];
#pragma unroll
      for (int ni = 0; ni < 2; ni++)
        bfr[ni] = *(const short8*)&Bs2[cur * 4096 + p * 2048 + (wn * 32 + ni * 16 + l15) * BK + qd * 8];
#pragma unroll
      for (int mi = 0; mi < 2; mi++)
#pragma unroll
        for (int ni = 0; ni < 2; ni++)
          a2[mi][ni] = __builtin_amdgcn_mfma_f32_16x16x32_bf16(af[mi], bfr[ni], a2[mi][ni], 0, 0, 0);
    }
    const int n0l = nc * 64;
#pragma unroll
    for (int mi = 0; mi < 2; mi++) {
      const int lr = wm * 32 + mi * 16 + qd * 4;
      float v[2][4];
#pragma unroll
      for (int ni = 0; ni < 2; ni++) {
        int col = n0l + wn * 32 + ni * 16 + l15;
        float bv = bf2f(b2[col]);
#pragma unroll
        for (int r = 0; r < 4; r++)
          v[ni][r] = bf2f(h[(size_t)(m0 + lr + r) * DD + col]) + a2[mi][ni][r] + bv;
      }
#pragma unroll
      for (int ni = 0; ni < 2; ni++)
#pragma unroll
        for (int r = 0; r < 4; r++)
          slab[(qd * 4 + r) * SW + ni * 16 + l15] = f2bf(v[ni][r]);
      wave_lds_fence();
      if (lane < 32) {
        int r2 = lane >> 1, c2 = (lane & 1) * 16;
        int grow = m0 + wm * 32 + mi * 16 + r2;
        u16* op = hout + (size_t)grow * DD + n0l + wn * 32 + c2;
        *(short8*)&op[0] = *(const short8*)&slab[r2 * SW + c2];
        *(short8*)&op[8] = *(const short8*)&slab[r2 * SW + c2 + 8];
      }
      wave_lds_fence();
    }
    cur ^= 1;
  }
}

// ---------------- fused attention: one block per (b,h) ----------------
__global__ __launch_bounds__(256)
void attn(const u16* __restrict__ qg, const u16* __restrict__ kg,
          const u16* __restrict__ vg, u16* __restrict__ og)
{
  constexpr int LP = 128;
  __shared__ alignas(16) u16 Ks[LP * DKK];
  __shared__ alignas(16) u16 Vt[DKK * LP];
  __shared__ alignas(16) u16 Ps[LP * LP];

  const int bh = blockIdx.x;
  const int b = bh >> 3, h = bh & 7;
  const size_t base = (size_t)b * LL * DD + (size_t)h * DKK;
  const int tid = threadIdx.x, lane = tid & 63, wv = tid >> 6;
  const int l15 = lane & 15, qd = lane >> 4;
  const short8 z8 = {0, 0, 0, 0, 0, 0, 0, 0};

  for (int i = tid; i < LP * 8; i += 256) {
    int row = i >> 3, e8 = (i & 7) * 8;
    short8 val = z8;
    if (row < LL) val = *(const short8*)(kg + base + (size_t)row * DD + e8);
    *(short8*)&Ks[row * DKK + e8] = val;
  }
  for (int i = tid; i < LP * 8; i += 256) {
    int j = i & 127, d0 = (i >> 7) * 8;
    short8 val = z8;
    if (j < LL) val = *(const short8*)(vg + base + (size_t)j * DD + d0);
#pragma unroll
    for (int u = 0; u < 8; u++) Vt[(d0 + u) * LP + j] = (u16)val[u];
  }
  __syncthreads();

  const f32x4 zf = {0.f, 0.f, 0.f, 0.f};
  f32x4 sc[2][8];
#pragma unroll
  for (int it = 0; it < 2; it++)
#pragma unroll
    for (int jt = 0; jt < 8; jt++) sc[it][jt] = zf;

  short8 af[2][2];
#pragma unroll
  for (int it = 0; it < 2; it++) {
    int row = (2 * wv + it) * 16 + l15;
#pragma unroll
    for (int ks = 0; ks < 2; ks++) {
      short8 val = z8;
      if (row < LL) val = *(const short8*)(qg + base + (size_t)row * DD + ks * 32 + qd * 8);
      af[it][ks] = val;
    }
  }
#pragma unroll
  for (int jt = 0; jt < 8; jt++) {
    short8 b0 = *(const short8*)&Ks[(jt * 16 + l15) * DKK + qd * 8];
    short8 b1 = *(const short8*)&Ks[(jt * 16 + l15) * DKK + 32 + qd * 8];
#pragma unroll
    for (int it = 0; it < 2; it++) {
      sc[it][jt] = __builtin_amdgcn_mfma_f32_16x16x32_bf16(af[it][0], b0, sc[it][jt], 0, 0, 0);
      sc[it][jt] = __builtin_amdgcn_mfma_f32_16x16x32_bf16(af[it][1], b1, sc[it][jt], 0, 0, 0);
    }
  }

  constexpr float scale = 0.125f;
#pragma unroll
  for (int it = 0; it < 2; it++) {
    int rb = (2 * wv + it) * 16 + qd * 4;
#pragma unroll
    for (int r = 0; r < 4; r++) {
      float vals[8];
      float mx = -1e30f;
#pragma unroll
      for (int jt = 0; jt < 8; jt++) {
        int col = jt * 16 + l15;
        float vv = sc[it][jt][r] * scale;
        if (col >= LL) vv = -1e30f;
        vals[jt] = vv;
        mx = fmaxf(mx, vv);
      }
#pragma unroll
      for (int off = 1; off < 16; off <<= 1) mx = fmaxf(mx, __shfl_xor(mx, off, 64));
      float s = 0.f;
#pragma unroll
      for (int jt = 0; jt < 8; jt++) { float p = __expf(vals[jt] - mx); vals[jt] = p; s += p; }
#pragma unroll
      for (int off = 1; off < 16; off <<= 1) s += __shfl_xor(s, off, 64);
      float inv = 1.f / s;
      int rowp = rb + r;
#pragma unroll
      for (int jt = 0; jt < 8; jt++) Ps[rowp * LP + jt * 16 + l15] = f2bf(vals[jt] * inv);
    }
  }
  __syncthreads();

  f32x4 oc[2][4];
#pragma unroll
  for (int it = 0; it < 2; it++)
#pragma unroll
    for (int dt = 0; dt < 4; dt++) oc[it][dt] = zf;
#pragma unroll
  for (int ks = 0; ks < 4; ks++) {
    short8 ap[2];
#pragma unroll
    for (int it = 0; it < 2; it++)
      ap[it] = *(const short8*)&Ps[((2 * wv + it) * 16 + l15) * LP + ks * 32 + qd * 8];
#pragma unroll
    for (int dt = 0; dt < 4; dt++) {
      short8 bv = *(const short8*)&Vt[(dt * 16 + l15) * LP + ks * 32 + qd * 8];
#pragma unroll
      for (int it = 0; it < 2; it++)
        oc[it][dt] = __builtin_amdgcn_mfma_f32_16x16x32_bf16(ap[it], bv, oc[it][dt], 0, 0, 0);
    }
  }

  __syncthreads();
  u16* Os = Ps;
#pragma unroll
  for (int it = 0; it < 2; it++) {
    int rb = (2 * wv + it) * 16 + qd * 4;
#pragma unroll
    for (int dt = 0; dt < 4; dt++)
#pragma unroll
      for (int r = 0; r < 4; r++)
        Os[(rb + r) * DKK + dt * 16 + l15] = f2bf(oc[it][dt][r]);
  }
  __syncthreads();
  {
    int row = tid >> 1, c0 = (tid & 1) * 32;
    if (row < LL) {
      u16* op = og + base + (size_t)row * DD + c0;
#pragma unroll
      for (int c = 0; c < 32; c += 8)
        *(short8*)&op[c] = *(const short8*)&Os[row * DKK + c0 + c];
    }
  }
}

// ---------------- launch ----------------
extern "C" void kernel_launch(void* const* d_in, const int* in_sizes, int n_in,
                              void* d_out, int out_size, void* d_ws, size_t ws_size,
                              hipStream_t stream)
{
  (void)in_sizes; (void)n_in; (void)out_size; (void)ws_size;

  char* ws = (char*)d_ws;
  size_t off = 0;
  auto alloc = [&](size_t bytes) { char* p = ws + off; off += (bytes + 255) & ~(size_t)255; return p; };
  int* dflag = (int*)alloc(256);
  static const int seg_sizes[NSEG] = {
    MM * CC, DD * CC * 3, LL * DD,
    3 * DD * DD, 3 * DD, 3 * DD * DD, 3 * DD, 3 * DD * DD, 3 * DD,
    3 * DD * DD, 3 * DD, 3 * 64 * DD, 3 * 64, 3 * DD * 64, 3 * DD,
    CC * DD, CC
  };
  static const int seg_input[NSEG] = {0, 1, 2, 3, 4, 5, 6, 7, 8, 11, 12, 13, 14, 15, 16, 17, 18};
  int total = 0, segoff[NSEG + 1];
  for (int i = 0; i < NSEG; i++) { segoff[i] = total; total += seg_sizes[i]; }
  segoff[NSEG] = total;
  u16* canon = (u16*)alloc((size_t)total * 2);

  u16* hbf = (u16*)alloc((size_t)MM * DD * 2);   // bf16 residual stream
  u16* qb  = (u16*)alloc((size_t)MM * DD * 2);
  u16* kb  = (u16*)alloc((size_t)MM * DD * 2);
  u16* vb  = (u16*)alloc((size_t)MM * DD * 2);
  u16* ob  = (u16*)alloc((size_t)MM * DD * 2);
  u16* Wg  = (u16*)alloc((size_t)512 * KEMB * 2);
  u16* Xg  = qb;   // alias: Xg dead before qb first written (stream-serialized)

  const u16* xc  = canon + segoff[0];
  const u16* twc = canon + segoff[1];
  const u16* pec = canon + segoff[2];
  const u16* Wqc = canon + segoff[3];  const u16* bqc = canon + segoff[4];
  const u16* Wkc = canon + segoff[5];  const u16* bkc = canon + segoff[6];
  const u16* Wvc = canon + segoff[7];  const u16* bvc = canon + segoff[8];
  const u16* Woc = canon + segoff[9];  const u16* boc = canon + segoff[10];
  const u16* W1c = canon + segoff[11]; const u16* b1c = canon + segoff[12];
  const u16* W2c = canon + segoff[13]; const u16* b2c = canon + segoff[14];
  const u16* pwc = canon + segoff[15]; const u16* pbc = canon + segoff[16];

  Segs sg;
  for (int i = 0; i < NSEG; i++) { sg.src[i] = d_in[seg_input[i]]; sg.off[i] = segoff[i]; }
  sg.off[NSEG] = total;

  dim3 blk(256);
  detect_dtype<<<dim3(1), blk, 0, stream>>>((const u16*)d_in[0], dflag);
  convert_all<<<dim3((total + 255) / 256), blk, 0, stream>>>(sg, dflag, canon);
  repack_w<<<dim3((512 * KEMB + 255) / 256), blk, 0, stream>>>(twc, Wg);
  repack_x<<<dim3((MM * KEMB + 255) / 256), blk, 0, stream>>>(xc, Xg);

  auto W1of = [&](const u16* p) { GemmW g{}; g.W[0] = g.W[1] = g.W[2] = p; return g; };

  // embedding GEMM: h = Xg @ Wg^T + pe -> hbf   [TAG 0]  grid 200*8, XCD-decoded
  { GemmW g = W1of(Wg); g.out[0] = hbf;
    gemm_bt<128, 64, 8, 0, false, false><<<dim3(1600), blk, 0, stream>>>(Xg, KEMB, g, pec, nullptr, 0, DD, DD, nullptr); }

  for (int l = 0; l < 3; l++) {
    const u16* Wq_l = Wqc + (size_t)l * DD * DD; const u16* bq_l = bqc + l * DD;
    const u16* Wk_l = Wkc + (size_t)l * DD * DD; const u16* bk_l = bkc + l * DD;
    const u16* Wv_l = Wvc + (size_t)l * DD * DD; const u16* bv_l = bvc + l * DD;
    const u16* Wo_l = Woc + (size_t)l * DD * DD; const u16* bo_l = boc + l * DD;
    const u16* W1_l = W1c + (size_t)l * 64 * DD; const u16* b1_l = b1c + l * 64;
    const u16* W2_l = W2c + (size_t)l * DD * 64; const u16* b2_l = b2c + l * DD;

    // fused QKV: grid 200*24, NTT=24, XCD-decoded; sel by n0>>9   [TAG 1]
    { GemmW g{}; g.W[0] = Wq_l; g.W[1] = Wk_l; g.W[2] = Wv_l;
      g.bias[0] = bq_l; g.bias[1] = bk_l; g.bias[2] = bv_l;
      g.out[0] = qb; g.out[1] = kb; g.out[2] = vb;
      gemm_bt<128, 64, 24, 1, true, false><<<dim3(4800), blk, 0, stream>>>(hbf, DD, g, nullptr, nullptr, 0, DD, DD, nullptr); }

    attn<<<dim3(BB * HH), blk, 0, stream>>>(qb, kb, vb, ob);

    // h = h + o @ Wo^T + bo  (bf16 resid, in-place hbf)   [TAG 2]
    { GemmW g = W1of(Wo_l); g.bias[0] = g.bias[1] = g.bias[2] = bo_l; g.out[0] = g.out[1] = g.out[2] = hbf;
      gemm_bt<128, 64, 8, 2, false, false><<<dim3(1600), blk, 0, stream>>>(ob, DD, g, nullptr, hbf, 0, DD, DD, nullptr); }

    // fused FFN: h = h + gelu(h@W1^T+b1)@W2^T + b2  (in-place hbf, block owns rows)
    ffn_fused<<<dim3(400), blk, 0, stream>>>(hbf, W1_l, b1_l, W2_l, b2_l, hbf);
  }
  // out = h @ proj_w^T + proj_b (N=55, direct masked stores; dtype per flag)   [TAG 5]
  { GemmW g = W1of(pwc); g.bias[0] = pbc; g.out[0] = d_out;
    gemm_bt<64, 64, 1, 5, false, true><<<dim3(400), blk, 0, stream>>>(hbf, DD, g, nullptr, nullptr, 0, CC, CC, dflag); }
}

// Round 14
// 651.921 us; speedup vs baseline: 1.8099x; 1.0025x over previous
//
#include <hip/hip_runtime.h>
#include <stdint.h>

typedef unsigned short u16;
typedef __attribute__((ext_vector_type(8))) short short8;
typedef __attribute__((ext_vector_type(4))) float f32x4;

#define DEVI __device__ __forceinline__

// problem constants
#define BB   256
#define LL   100
#define CC   55
#define DD   512
#define HH   8
#define DKK  64
#define MM   (BB * LL)   // 25600 tokens
#define KEMB 192         // 3 * 64 (c padded 55->64)
#define NSEG 17

DEVI float bf2f(u16 s) { union { unsigned int u; float f; } x; x.u = ((unsigned int)s) << 16; return x.f; }
DEVI u16 f2bf(float f) {
  union { float f; unsigned int u; } x; x.f = f;
  unsigned int u = x.u;
  return (u16)((u + 0x7FFFu + ((u >> 16) & 1u)) >> 16);
}

DEVI void async_lds16(const u16* gp, u16* lp) {
  __builtin_amdgcn_global_load_lds((const __attribute__((address_space(1))) void*)gp,
                                   (__attribute__((address_space(3))) void*)lp, 16, 0, 0);
}

DEVI void wave_lds_fence() {   // wave-local LDS RAW/WAR fence (no cross-wave sync)
  asm volatile("s_waitcnt lgkmcnt(0)" ::: "memory");
  __builtin_amdgcn_wave_barrier();
}

// bank-conflict XOR swizzle: chunk c of row r lives at slot c ^ sw(r),
// sw(r) = (r&3) ^ ((r>>2)&3). Self-inverse; spreads the 16 lanes of a
// fragment ds_read_b128 across all 8 bank-group starts -> 2-way (free, m136).
DEVI int swz_row(int r) { return (r & 3) ^ ((r >> 2) & 3); }

// ---------------- dtype detect + canonicalize ----------------
__global__ void detect_dtype(const u16* __restrict__ x, int* __restrict__ flag) {
  __shared__ int cnt[256];
  int tid = threadIdx.x;
  u16 u = x[2 * tid];
  int e = (u >> 7) & 0xFF;
  cnt[tid] = (e >= 0x5F && e <= 0x90) ? 1 : 0;   // |v| in [2^-32, 2^17]
  __syncthreads();
  for (int s = 128; s > 0; s >>= 1) { if (tid < s) cnt[tid] += cnt[tid + s]; __syncthreads(); }
  if (tid == 0) *flag = (cnt[0] >= 160) ? 0 : 1;
}

struct Segs { const void* src[NSEG]; int off[NSEG + 1]; };

__global__ void convert_all(Segs s, const int* __restrict__ flag, u16* __restrict__ dst) {
  int i = blockIdx.x * 256 + threadIdx.x;
  if (i >= s.off[NSEG]) return;
  int sidx = 0;
#pragma unroll
  for (int k = 1; k < NSEG; k++) if (i >= s.off[k]) sidx = k;
  int j = i - s.off[sidx];
  u16 v;
  if (*flag) v = f2bf(((const float*)s.src[sidx])[j]);
  else       v = ((const u16*)s.src[sidx])[j];
  dst[i] = v;
}

// ---------------- repack kernels (embedding conv -> GEMM) ----------------
__global__ void repack_w(const u16* __restrict__ tokw, u16* __restrict__ Wg) {
  int idx = blockIdx.x * 256 + threadIdx.x;   // 512*192
  if (idx >= 512 * KEMB) return;
  int d = idx / KEMB, j = idx % KEMB, k = j >> 6, c = j & 63;
  Wg[idx] = (c < CC) ? tokw[d * (CC * 3) + c * 3 + k] : (u16)0;
}

__global__ void repack_x(const u16* __restrict__ x, u16* __restrict__ Xg) {
  int idx = blockIdx.x * 256 + threadIdx.x;   // 25600*192
  if (idx >= MM * KEMB) return;
  int m = idx / KEMB, j = idx % KEMB, k = j >> 6, c = j & 63;
  int b = m / LL, l = m % LL;
  int l2 = l + k - 1; l2 = (l2 + LL) % LL;    // circular pad
  Xg[idx] = (c < CC) ? x[(size_t)(b * LL + l2) * CC + c] : (u16)0;
}

// ---------------- bf16 MFMA GEMM: out = A[M,K] @ W[N,K]^T (+epilogue) ----------------
// R11 config (BN=64, single-buffer unroll-2 K-loop, XCD-aware decode) + XOR-
// swizzled LDS panels (8-way fragment-read conflicts -> 2-way/free).
struct GemmW { const u16* W[3]; const u16* bias[3]; void* out[3]; };

template<int BM, int BN, int NTT, int TAG, bool QKV, bool DIRECT>
__global__ __launch_bounds__(256)
void gemm_bt(const u16* __restrict__ A, int K, GemmW w,
             const u16* __restrict__ pe,     // if non-null: add pe[(m%100)*512+col]
             const u16* __restrict__ resid,  // if non-null: add resid[m*512+col] (bf16)
             int dogelu,
             int ldo, int nvalid,
             const int* __restrict__ dtf)    // DIRECT only: *dtf==1 -> fp32 store
{
  constexpr int BK = 32;
  constexpr int MI = BM / 32;
  constexpr int CW = BN / 2, NT = CW / 16;
  constexpr int SW = CW + 4;
  constexpr int STAGE_U16 = (BM + BN) * BK * 2;
  __shared__ alignas(16) u16 smem[STAGE_U16];
  u16* As = smem;
  u16* Bs = smem + BM * BK * 2;

  const int tid = threadIdx.x;
  const int lane = tid & 63;
  const int wv = __builtin_amdgcn_readfirstlane(tid >> 6);
  const int wm = wv & 1, wn = wv >> 1;
  const int l15 = lane & 15, qd = lane >> 4;
  const int swz = swz_row(l15);               // fragment-read xor (lane-uniform cost)

  const int id = blockIdx.x;
  const int mpx = gridDim.x / (NTT * 8);
  const int xcd = id & 7, slot = id >> 3;
  const int m_t = xcd * mpx + slot / NTT;
  const int n_t = slot % NTT;
  const int m0 = m_t * BM;
  int n0 = n_t * BN;
  int sel = 0, n0l = n0;
  if (QKV) { sel = n0 >> 9; n0l = n0 & 511; }
  const u16* W = w.W[sel];
  const u16* bias = w.bias[sel];
  void* outp = w.out[sel];

  const f32x4 zf = {0.f, 0.f, 0.f, 0.f};
  f32x4 acc[MI][NT];
#pragma unroll
  for (int i = 0; i < MI; i++)
#pragma unroll
    for (int j = 0; j < NT; j++) acc[i][j] = zf;

  for (int k0 = 0; k0 < K; k0 += 2 * BK) {
    __syncthreads();
#pragma unroll
    for (int p = 0; p < 2; p++) {
      u16* Asp = As + p * BM * BK;
      u16* Bsp = Bs + p * BN * BK;
      const int kp = k0 + p * BK;
#pragma unroll
      for (int i = 0; i < BM / 64; i++) {
        int base = i * 256 + wv * 64;
        int idx = base + lane;
        int row = idx >> 2;
        int cs = ((idx & 3) ^ swz_row(row)) * 8;   // swizzled source chunk
        async_lds16(A + (size_t)(m0 + row) * K + kp + cs, Asp + base * 8);
      }
#pragma unroll
      for (int i = 0; i < BN / 64; i++) {
        int base = i * 256 + wv * 64;
        int idx = base + lane;
        int row = idx >> 2;
        int cs = ((idx & 3) ^ swz_row(row)) * 8;
        int gr = n0l + row; if (gr >= nvalid) gr = nvalid - 1;
        async_lds16(W + (size_t)gr * K + kp + cs, Bsp + base * 8);
      }
    }
    __syncthreads();

#pragma unroll
    for (int p = 0; p < 2; p++) {
      const u16* Asp = As + p * BM * BK;
      const u16* Bsp = Bs + p * BN * BK;
      short8 af[MI], bfr[NT];
#pragma unroll
      for (int mi = 0; mi < MI; mi++)
        af[mi] = *(const short8*)&Asp[(wm * (BM / 2) + mi * 16 + l15) * BK + ((qd ^ swz) * 8)];
#pragma unroll
      for (int ni = 0; ni < NT; ni++)
        bfr[ni] = *(const short8*)&Bsp[(wn * CW + ni * 16 + l15) * BK + ((qd ^ swz) * 8)];
#pragma unroll
      for (int mi = 0; mi < MI; mi++)
#pragma unroll
        for (int ni = 0; ni < NT; ni++)
          acc[mi][ni] = __builtin_amdgcn_mfma_f32_16x16x32_bf16(af[mi], bfr[ni], acc[mi][ni], 0, 0, 0);
    }
  }

  // C/D layout: col=lane&15, row=(lane>>4)*4+reg [verified m89/m91]
  if (DIRECT) {
    const int sf = (dtf != nullptr) ? *dtf : 0;
#pragma unroll
    for (int mi = 0; mi < MI; mi++)
#pragma unroll
      for (int ni = 0; ni < NT; ni++) {
        int gcol = n0l + wn * CW + ni * 16 + l15;
        float bv = (bias && gcol < nvalid) ? bf2f(bias[gcol]) : 0.f;
#pragma unroll
        for (int r = 0; r < 4; r++) {
          int grow = m0 + wm * (BM / 2) + mi * 16 + qd * 4 + r;
          if (gcol < nvalid) {
            float v = acc[mi][ni][r] + bv;
            if (sf) ((float*)outp)[(size_t)grow * ldo + gcol] = v;
            else    ((u16*)outp)[(size_t)grow * ldo + gcol] = f2bf(v);
          }
        }
      }
    return;
  }

  __syncthreads();
  u16* slab = smem + wv * 16 * SW;
#pragma unroll
  for (int mi = 0; mi < MI; mi++) {
    const int lr = wm * (BM / 2) + mi * 16 + qd * 4;
    float v[NT][4];
    if (!QKV && resid) {
#pragma unroll
      for (int ni = 0; ni < NT; ni++) {
        int col = n0l + wn * CW + ni * 16 + l15;
#pragma unroll
        for (int r = 0; r < 4; r++)
          v[ni][r] = bf2f(resid[(size_t)(m0 + lr + r) * DD + col]);
      }
    } else {
#pragma unroll
      for (int ni = 0; ni < NT; ni++)
#pragma unroll
        for (int r = 0; r < 4; r++) v[ni][r] = 0.f;
    }
#pragma unroll
    for (int ni = 0; ni < NT; ni++) {
      const int lc = wn * CW + ni * 16 + l15;
      float bv = bias ? bf2f(bias[n0l + lc]) : 0.f;
#pragma unroll
      for (int r = 0; r < 4; r++) {
        float x = v[ni][r] + acc[mi][ni][r] + bv;
        if (!QKV && pe) x += bf2f(pe[((m0 + lr + r) % LL) * DD + n0l + lc]);
        if (!QKV && dogelu) x = 0.5f * x * (1.f + erff(x * 0.70710678118654752f));
        v[ni][r] = x;
      }
    }
#pragma unroll
    for (int ni = 0; ni < NT; ni++)
#pragma unroll
      for (int r = 0; r < 4; r++)
        slab[(qd * 4 + r) * SW + ni * 16 + l15] = f2bf(v[ni][r]);
    wave_lds_fence();
    if (BN == 128) {
      int r2 = lane >> 2, c2 = (lane & 3) * 16;
      int grow = m0 + wm * (BM / 2) + mi * 16 + r2;
      u16* op = (u16*)outp + (size_t)grow * ldo + n0l + wn * CW + c2;
      *(short8*)&op[0] = *(const short8*)&slab[r2 * SW + c2];
      *(short8*)&op[8] = *(const short8*)&slab[r2 * SW + c2 + 8];
    } else {
      if (lane < 32) {
        int r2 = lane >> 1, c2 = (lane & 1) * 16;
        int grow = m0 + wm * (BM / 2) + mi * 16 + r2;
        u16* op = (u16*)outp + (size_t)grow * ldo + n0l + wn * CW + c2;
        *(short8*)&op[0] = *(const short8*)&slab[r2 * SW + c2];
        *(short8*)&op[8] = *(const short8*)&slab[r2 * SW + c2 + 8];
      }
    }
    wave_lds_fence();
  }
}

// ---------------- fused FFN: h = h + gelu(h@W1^T + b1) @ W2^T + b2 ----------------
// Same structure as R12 + XOR-swizzled panels (As/Bs/Bs2 staging, y park).
__global__ __launch_bounds__(256)
void ffn_fused(const u16* __restrict__ h, const u16* __restrict__ W1,
               const u16* __restrict__ b1, const u16* __restrict__ W2,
               const u16* __restrict__ b2, u16* __restrict__ hout)
{
  constexpr int BM = 64, BK = 32, SW = 36;
  __shared__ alignas(16) u16 smem[4096 + 10496];
  u16* y      = smem;                        // [2][64][32] panels (A-format, swizzled)
  u16* shared = smem + 4096;
  u16* As  = shared;
  u16* Bs  = shared + 4096;
  u16* Bs2 = shared;
  u16* slabs = shared + 8192;

  const int tid = threadIdx.x;
  const int lane = tid & 63;
  const int wv = __builtin_amdgcn_readfirstlane(tid >> 6);
  const int wm = wv & 1, wn = wv >> 1;
  const int l15 = lane & 15, qd = lane >> 4;
  const int swz = swz_row(l15);
  const int id = blockIdx.x;
  const int mpx = gridDim.x >> 3;
  const int m0 = ((id & 7) * mpx + (id >> 3)) * BM;

  const int srow = tid >> 2;
  const int scs = ((tid & 3) ^ swz_row(srow)) * 8;   // swizzled staging chunk
  const f32x4 zf = {0.f, 0.f, 0.f, 0.f};

  // ---- phase 1: y = gelu(h @ W1^T + b1) ----
  f32x4 acc[2][2];
#pragma unroll
  for (int i = 0; i < 2; i++)
#pragma unroll
    for (int j = 0; j < 2; j++) acc[i][j] = zf;

  for (int k0 = 0; k0 < DD; k0 += 64) {
    __syncthreads();
#pragma unroll
    for (int p = 0; p < 2; p++) {
      const int kp = k0 + p * BK;
      async_lds16(h  + (size_t)(m0 + srow) * DD + kp + scs, As + p * 2048 + tid * 8);
      async_lds16(W1 + (size_t)srow * DD + kp + scs,        Bs + p * 2048 + tid * 8);
    }
    __syncthreads();
#pragma unroll
    for (int p = 0; p < 2; p++) {
      short8 af[2], bfr[2];
#pragma unroll
      for (int mi = 0; mi < 2; mi++)
        af[mi] = *(const short8*)&As[p * 2048 + (wm * 32 + mi * 16 + l15) * BK + ((qd ^ swz) * 8)];
#pragma unroll
      for (int ni = 0; ni < 2; ni++)
        bfr[ni] = *(const short8*)&Bs[p * 2048 + (wn * 32 + ni * 16 + l15) * BK + ((qd ^ swz) * 8)];
#pragma unroll
      for (int mi = 0; mi < 2; mi++)
#pragma unroll
        for (int ni = 0; ni < 2; ni++)
          acc[mi][ni] = __builtin_amdgcn_mfma_f32_16x16x32_bf16(af[mi], bfr[ni], acc[mi][ni], 0, 0, 0);
    }
  }
  // y park (swizzled): element (row, kpos) -> slot (kpos>>3) ^ sw(row)
#pragma unroll
  for (int mi = 0; mi < 2; mi++)
#pragma unroll
    for (int ni = 0; ni < 2; ni++) {
      float bv = bf2f(b1[wn * 32 + ni * 16 + l15]);
#pragma unroll
      for (int r = 0; r < 4; r++) {
        int row = wm * 32 + mi * 16 + qd * 4 + r;
        int kpos = ni * 16 + l15;
        int slot = ((kpos >> 3) ^ swz_row(row)) & 3;
        float x = acc[mi][ni][r] + bv;
        x = 0.5f * x * (1.f + erff(x * 0.70710678118654752f));
        y[wn * 2048 + row * BK + slot * 8 + (kpos & 7)] = f2bf(x);
      }
    }
  __syncthreads();

  // ---- phase 2: hout = h + y @ W2^T + b2, 8 chunks of 64 cols ----
  auto stage2 = [&](int buf, int nc) {
#pragma unroll
    for (int p = 0; p < 2; p++)
      async_lds16(W2 + (size_t)(nc * 64 + srow) * 64 + p * BK + scs,
                  Bs2 + buf * 4096 + p * 2048 + tid * 8);
  };
  stage2(0, 0);
  int cur = 0;
  u16* slab = slabs + wv * 16 * SW;
  for (int nc = 0; nc < 8; nc++) {
    __syncthreads();
    if (nc + 1 < 8) stage2(cur ^ 1, nc + 1);
    f32x4 a2[2][2];
#pragma unroll
    for (int i = 0; i < 2; i++)
#pragma unroll
      for (int j = 0; j < 2; j++) a2[i][j] = zf;
#pragma unroll
    for (int p = 0; p < 2; p++) {
      short8 af[2], bfr[2];
#pragma unroll
      for (int mi = 0; mi < 2; mi++)
        af[mi] = *(const short8*)&y[p * 2048 + (wm * 32 + mi * 16 + l15) * BK + ((qd ^ swz) * 8)];
#pragma unroll
      for (int ni = 0; ni < 2; ni++)
        bfr[ni] = *(const short8*)&Bs2[cur * 4096 + p * 2048 + (wn * 32 + ni * 16 + l15) * BK + ((qd ^ swz) * 8)];
#pragma unroll
      for (int mi = 0; mi < 2; mi++)
#pragma unroll
        for (int ni = 0; ni < 2; ni++)
          a2[mi][ni] = __builtin_amdgcn_mfma_f32_16x16x32_bf16(af[mi], bfr[ni], a2[mi][ni], 0, 0, 0);
    }
    const int n0l = nc * 64;
#pragma unroll
    for (int mi = 0; mi < 2; mi++) {
      const int lr = wm * 32 + mi * 16 + qd * 4;
      float v[2][4];
#pragma unroll
      for (int ni = 0; ni < 2; ni++) {
        int col = n0l + wn * 32 + ni * 16 + l15;
        float bv = bf2f(b2[col]);
#pragma unroll
        for (int r = 0; r < 4; r++)
          v[ni][r] = bf2f(h[(size_t)(m0 + lr + r) * DD + col]) + a2[mi][ni][r] + bv;
      }
#pragma unroll
      for (int ni = 0; ni < 2; ni++)
#pragma unroll
        for (int r = 0; r < 4; r++)
          slab[(qd * 4 + r) * SW + ni * 16 + l15] = f2bf(v[ni][r]);
      wave_lds_fence();
      if (lane < 32) {
        int r2 = lane >> 1, c2 = (lane & 1) * 16;
        int grow = m0 + wm * 32 + mi * 16 + r2;
        u16* op = hout + (size_t)grow * DD + n0l + wn * 32 + c2;
        *(short8*)&op[0] = *(const short8*)&slab[r2 * SW + c2];
        *(short8*)&op[8] = *(const short8*)&slab[r2 * SW + c2 + 8];
      }
      wave_lds_fence();
    }
    cur ^= 1;
  }
}

// ---------------- fused attention: one block per (b,h) ----------------
__global__ __launch_bounds__(256)
void attn(const u16* __restrict__ qg, const u16* __restrict__ kg,
          const u16* __restrict__ vg, u16* __restrict__ og)
{
  constexpr int LP = 128;
  __shared__ alignas(16) u16 Ks[LP * DKK];
  __shared__ alignas(16) u16 Vt[DKK * LP];
  __shared__ alignas(16) u16 Ps[LP * LP];

  const int bh = blockIdx.x;
  const int b = bh >> 3, h = bh & 7;
  const size_t base = (size_t)b * LL * DD + (size_t)h * DKK;
  const int tid = threadIdx.x, lane = tid & 63, wv = tid >> 6;
  const int l15 = lane & 15, qd = lane >> 4;
  const short8 z8 = {0, 0, 0, 0, 0, 0, 0, 0};

  for (int i = tid; i < LP * 8; i += 256) {
    int row = i >> 3, e8 = (i & 7) * 8;
    short8 val = z8;
    if (row < LL) val = *(const short8*)(kg + base + (size_t)row * DD + e8);
    *(short8*)&Ks[row * DKK + e8] = val;
  }
  for (int i = tid; i < LP * 8; i += 256) {
    int j = i & 127, d0 = (i >> 7) * 8;
    short8 val = z8;
    if (j < LL) val = *(const short8*)(vg + base + (size_t)j * DD + d0);
#pragma unroll
    for (int u = 0; u < 8; u++) Vt[(d0 + u) * LP + j] = (u16)val[u];
  }
  __syncthreads();

  const f32x4 zf = {0.f, 0.f, 0.f, 0.f};
  f32x4 sc[2][8];
#pragma unroll
  for (int it = 0; it < 2; it++)
#pragma unroll
    for (int jt = 0; jt < 8; jt++) sc[it][jt] = zf;

  short8 af[2][2];
#pragma unroll
  for (int it = 0; it < 2; it++) {
    int row = (2 * wv + it) * 16 + l15;
#pragma unroll
    for (int ks = 0; ks < 2; ks++) {
      short8 val = z8;
      if (row < LL) val = *(const short8*)(qg + base + (size_t)row * DD + ks * 32 + qd * 8);
      af[it][ks] = val;
    }
  }
#pragma unroll
  for (int jt = 0; jt < 8; jt++) {
    short8 b0 = *(const short8*)&Ks[(jt * 16 + l15) * DKK + qd * 8];
    short8 b1 = *(const short8*)&Ks[(jt * 16 + l15) * DKK + 32 + qd * 8];
#pragma unroll
    for (int it = 0; it < 2; it++) {
      sc[it][jt] = __builtin_amdgcn_mfma_f32_16x16x32_bf16(af[it][0], b0, sc[it][jt], 0, 0, 0);
      sc[it][jt] = __builtin_amdgcn_mfma_f32_16x16x32_bf16(af[it][1], b1, sc[it][jt], 0, 0, 0);
    }
  }

  constexpr float scale = 0.125f;
#pragma unroll
  for (int it = 0; it < 2; it++) {
    int rb = (2 * wv + it) * 16 + qd * 4;
#pragma unroll
    for (int r = 0; r < 4; r++) {
      float vals[8];
      float mx = -1e30f;
#pragma unroll
      for (int jt = 0; jt < 8; jt++) {
        int col = jt * 16 + l15;
        float vv = sc[it][jt][r] * scale;
        if (col >= LL) vv = -1e30f;
        vals[jt] = vv;
        mx = fmaxf(mx, vv);
      }
#pragma unroll
      for (int off = 1; off < 16; off <<= 1) mx = fmaxf(mx, __shfl_xor(mx, off, 64));
      float s = 0.f;
#pragma unroll
      for (int jt = 0; jt < 8; jt++) { float p = __expf(vals[jt] - mx); vals[jt] = p; s += p; }
#pragma unroll
      for (int off = 1; off < 16; off <<= 1) s += __shfl_xor(s, off, 64);
      float inv = 1.f / s;
      int rowp = rb + r;
#pragma unroll
      for (int jt = 0; jt < 8; jt++) Ps[rowp * LP + jt * 16 + l15] = f2bf(vals[jt] * inv);
    }
  }
  __syncthreads();

  f32x4 oc[2][4];
#pragma unroll
  for (int it = 0; it < 2; it++)
#pragma unroll
    for (int dt = 0; dt < 4; dt++) oc[it][dt] = zf;
#pragma unroll
  for (int ks = 0; ks < 4; ks++) {
    short8 ap[2];
#pragma unroll
    for (int it = 0; it < 2; it++)
      ap[it] = *(const short8*)&Ps[((2 * wv + it) * 16 + l15) * LP + ks * 32 + qd * 8];
#pragma unroll
    for (int dt = 0; dt < 4; dt++) {
      short8 bv = *(const short8*)&Vt[(dt * 16 + l15) * LP + ks * 32 + qd * 8];
#pragma unroll
      for (int it = 0; it < 2; it++)
        oc[it][dt] = __builtin_amdgcn_mfma_f32_16x16x32_bf16(ap[it], bv, oc[it][dt], 0, 0, 0);
    }
  }

  __syncthreads();
  u16* Os = Ps;
#pragma unroll
  for (int it = 0; it < 2; it++) {
    int rb = (2 * wv + it) * 16 + qd * 4;
#pragma unroll
    for (int dt = 0; dt < 4; dt++)
#pragma unroll
      for (int r = 0; r < 4; r++)
        Os[(rb + r) * DKK + dt * 16 + l15] = f2bf(oc[it][dt][r]);
  }
  __syncthreads();
  {
    int row = tid >> 1, c0 = (tid & 1) * 32;
    if (row < LL) {
      u16* op = og + base + (size_t)row * DD + c0;
#pragma unroll
      for (int c = 0; c < 32; c += 8)
        *(short8*)&op[c] = *(const short8*)&Os[row * DKK + c0 + c];
    }
  }
}

// ---------------- launch ----------------
extern "C" void kernel_launch(void* const* d_in, const int* in_sizes, int n_in,
                              void* d_out, int out_size, void* d_ws, size_t ws_size,
                              hipStream_t stream)
{
  (void)in_sizes; (void)n_in; (void)out_size; (void)ws_size;

  char* ws = (char*)d_ws;
  size_t off = 0;
  auto alloc = [&](size_t bytes) { char* p = ws + off; off += (bytes + 255) & ~(size_t)255; return p; };
  int* dflag = (int*)alloc(256);
  static const int seg_sizes[NSEG] = {
    MM * CC, DD * CC * 3, LL * DD,
    3 * DD * DD, 3 * DD, 3 * DD * DD, 3 * DD, 3 * DD * DD, 3 * DD,
    3 * DD * DD, 3 * DD, 3 * 64 * DD, 3 * 64, 3 * DD * 64, 3 * DD,
    CC * DD, CC
  };
  static const int seg_input[NSEG] = {0, 1, 2, 3, 4, 5, 6, 7, 8, 11, 12, 13, 14, 15, 16, 17, 18};
  int total = 0, segoff[NSEG + 1];
  for (int i = 0; i < NSEG; i++) { segoff[i] = total; total += seg_sizes[i]; }
  segoff[NSEG] = total;
  u16* canon = (u16*)alloc((size_t)total * 2);

  u16* hbf = (u16*)alloc((size_t)MM * DD * 2);   // bf16 residual stream
  u16* qb  = (u16*)alloc((size_t)MM * DD * 2);
  u16* kb  = (u16*)alloc((size_t)MM * DD * 2);
  u16* vb  = (u16*)alloc((size_t)MM * DD * 2);
  u16* ob  = (u16*)alloc((size_t)MM * DD * 2);
  u16* Wg  = (u16*)alloc((size_t)512 * KEMB * 2);
  u16* Xg  = qb;   // alias: Xg dead before qb first written (stream-serialized)

  const u16* xc  = canon + segoff[0];
  const u16* twc = canon + segoff[1];
  const u16* pec = canon + segoff[2];
  const u16* Wqc = canon + segoff[3];  const u16* bqc = canon + segoff[4];
  const u16* Wkc = canon + segoff[5];  const u16* bkc = canon + segoff[6];
  const u16* Wvc = canon + segoff[7];  const u16* bvc = canon + segoff[8];
  const u16* Woc = canon + segoff[9];  const u16* boc = canon + segoff[10];
  const u16* W1c = canon + segoff[11]; const u16* b1c = canon + segoff[12];
  const u16* W2c = canon + segoff[13]; const u16* b2c = canon + segoff[14];
  const u16* pwc = canon + segoff[15]; const u16* pbc = canon + segoff[16];

  Segs sg;
  for (int i = 0; i < NSEG; i++) { sg.src[i] = d_in[seg_input[i]]; sg.off[i] = segoff[i]; }
  sg.off[NSEG] = total;

  dim3 blk(256);
  detect_dtype<<<dim3(1), blk, 0, stream>>>((const u16*)d_in[0], dflag);
  convert_all<<<dim3((total + 255) / 256), blk, 0, stream>>>(sg, dflag, canon);
  repack_w<<<dim3((512 * KEMB + 255) / 256), blk, 0, stream>>>(twc, Wg);
  repack_x<<<dim3((MM * KEMB + 255) / 256), blk, 0, stream>>>(xc, Xg);

  auto W1of = [&](const u16* p) { GemmW g{}; g.W[0] = g.W[1] = g.W[2] = p; return g; };

  // embedding GEMM: h = Xg @ Wg^T + pe -> hbf   [TAG 0]  grid 200*8, XCD-decoded
  { GemmW g = W1of(Wg); g.out[0] = hbf;
    gemm_bt<128, 64, 8, 0, false, false><<<dim3(1600), blk, 0, stream>>>(Xg, KEMB, g, pec, nullptr, 0, DD, DD, nullptr); }

  for (int l = 0; l < 3; l++) {
    const u16* Wq_l = Wqc + (size_t)l * DD * DD; const u16* bq_l = bqc + l * DD;
    const u16* Wk_l = Wkc + (size_t)l * DD * DD; const u16* bk_l = bkc + l * DD;
    const u16* Wv_l = Wvc + (size_t)l * DD * DD; const u16* bv_l = bvc + l * DD;
    const u16* Wo_l = Woc + (size_t)l * DD * DD; const u16* bo_l = boc + l * DD;
    const u16* W1_l = W1c + (size_t)l * 64 * DD; const u16* b1_l = b1c + l * 64;
    const u16* W2_l = W2c + (size_t)l * DD * 64; const u16* b2_l = b2c + l * DD;

    // fused QKV: grid 200*24, NTT=24, XCD-decoded; sel by n0>>9   [TAG 1]
    { GemmW g{}; g.W[0] = Wq_l; g.W[1] = Wk_l; g.W[2] = Wv_l;
      g.bias[0] = bq_l; g.bias[1] = bk_l; g.bias[2] = bv_l;
      g.out[0] = qb; g.out[1] = kb; g.out[2] = vb;
      gemm_bt<128, 64, 24, 1, true, false><<<dim3(4800), blk, 0, stream>>>(hbf, DD, g, nullptr, nullptr, 0, DD, DD, nullptr); }

    attn<<<dim3(BB * HH), blk, 0, stream>>>(qb, kb, vb, ob);

    // h = h + o @ Wo^T + bo  (bf16 resid, in-place hbf)   [TAG 2]
    { GemmW g = W1of(Wo_l); g.bias[0] = g.bias[1] = g.bias[2] = bo_l; g.out[0] = g.out[1] = g.out[2] = hbf;
      gemm_bt<128, 64, 8, 2, false, false><<<dim3(1600), blk, 0, stream>>>(ob, DD, g, nullptr, hbf, 0, DD, DD, nullptr); }

    // fused FFN: h = h + gelu(h@W1^T+b1)@W2^T + b2  (in-place hbf, block owns rows)
    ffn_fused<<<dim3(400), blk, 0, stream>>>(hbf, W1_l, b1_l, W2_l, b2_l, hbf);
  }
  // out = h @ proj_w^T + proj_b (N=55, direct masked stores; dtype per flag)   [TAG 5]
  { GemmW g = W1of(pwc); g.bias[0] = pbc; g.out[0] = d_out;
    gemm_bt<64, 64, 1, 5, false, true><<<dim3(400), blk, 0, stream>>>(hbf, DD, g, nullptr, nullptr, 0, CC, CC, dflag); }
}